// Round 1
// baseline (2598.958 us; speedup 1.0000x reference)
//
#include <hip/hip_runtime.h>
#include <math.h>

#define Bsz 4
#define Tt  1024
#define Cc  1024
#define Hh  16
#define HSs 64

__device__ __forceinline__ float sigf(float x) { return 1.f / (1.f + expf(-x)); }

// ---------------------------------------------------------------------------
// Simple fp32 tiled GEMM: out[M,N] = f( A[M,K] @ W[K,N] + bias )
// Optional prologue: A row r, col c -> x + (shift(x)-x)*mix[c]  (token-shift mix)
// epi: 0=none, 1=tanh, 2=sigmoid, 3=decay exp(-exp(-0.5)*sigmoid(v))
// BM=BN=64, BK=16, 256 threads, 4x4 microtile per thread.
// ---------------------------------------------------------------------------
__global__ __launch_bounds__(256) void gemm_f32(
    const float* __restrict__ A, const float* __restrict__ W,
    float* __restrict__ out, const float* __restrict__ mix,
    const float* __restrict__ bias, int M, int N, int K, int epi)
{
    __shared__ float As[16][65];
    __shared__ float Bs[16][65];
    const int row0 = blockIdx.y * 64;
    const int col0 = blockIdx.x * 64;
    const int tid = threadIdx.x;
    const int tr = tid >> 4, tc = tid & 15;

    float acc[4][4];
#pragma unroll
    for (int i = 0; i < 4; ++i)
#pragma unroll
        for (int j = 0; j < 4; ++j) acc[i][j] = 0.f;

    for (int k0 = 0; k0 < K; k0 += 16) {
        // A tile: 64 rows x 16 k. thread i -> rr = i/16, kk = i%16 (coalesced over kk)
#pragma unroll
        for (int s = 0; s < 4; ++s) {
            int i = tid + s * 256;
            int rr = i >> 4, kk = i & 15;
            int r = row0 + rr;
            int c = k0 + kk;
            float xv = A[r * K + c];
            float val;
            if (mix) {
                int t = r & (Tt - 1);
                float xp = (t > 0) ? A[(r - 1) * K + c] : 0.f;
                val = xv + (xp - xv) * mix[c];
            } else val = xv;
            As[kk][rr] = val;
        }
        // B tile: 16 k x 64 cols. thread i -> kk = i/64, cc = i%64 (coalesced over cc)
#pragma unroll
        for (int s = 0; s < 4; ++s) {
            int i = tid + s * 256;
            int kk = i >> 6, cc = i & 63;
            Bs[kk][cc] = W[(k0 + kk) * N + col0 + cc];
        }
        __syncthreads();
#pragma unroll
        for (int kk = 0; kk < 16; ++kk) {
            float a[4], b[4];
#pragma unroll
            for (int u = 0; u < 4; ++u) a[u] = As[kk][tr * 4 + u];
#pragma unroll
            for (int u = 0; u < 4; ++u) b[u] = Bs[kk][tc * 4 + u];
#pragma unroll
            for (int i = 0; i < 4; ++i)
#pragma unroll
                for (int j = 0; j < 4; ++j) acc[i][j] += a[i] * b[j];
        }
        __syncthreads();
    }

#pragma unroll
    for (int i = 0; i < 4; ++i) {
        int r = row0 + tr * 4 + i;
#pragma unroll
        for (int j = 0; j < 4; ++j) {
            int c = col0 + tc * 4 + j;
            float v = acc[i][j];
            if (bias) v += bias[c];
            if (epi == 1) v = tanhf(v);
            else if (epi == 2) v = sigf(v);
            else if (epi == 3) v = expf(-0.60653065971263342f * sigf(v));
            out[(size_t)r * N + c] = v;
        }
    }
}

// ---------------------------------------------------------------------------
// prep_k: kk = normalize_perhead(kraw*k_k); aa=-kk; bb=kk*a; k=kraw*(1+(a-1)*k_a)
// one block per token row; thread -> 4 consecutive channels; 16-lane head reduce
// ---------------------------------------------------------------------------
__global__ __launch_bounds__(256) void prep_k_kernel(
    const float* kraw, const float* __restrict__ a,
    const float* __restrict__ k_k, const float* __restrict__ k_a,
    float* kout, float* __restrict__ aaout, float* __restrict__ bbout)
{
    const int row = blockIdx.x;
    const int tid = threadIdx.x;
    const int c0 = tid * 4;
    const size_t o = (size_t)row * Cc;

    float4 kr = *(const float4*)(kraw + o + c0);
    float4 kkw = *(const float4*)(k_k + c0);
    float4 av = *(const float4*)(a + o + c0);
    float4 kaw = *(const float4*)(k_a + c0);

    float kk[4] = { kr.x * kkw.x, kr.y * kkw.y, kr.z * kkw.z, kr.w * kkw.w };
    float ssq = kk[0]*kk[0] + kk[1]*kk[1] + kk[2]*kk[2] + kk[3]*kk[3];
    ssq += __shfl_xor(ssq, 1);
    ssq += __shfl_xor(ssq, 2);
    ssq += __shfl_xor(ssq, 4);
    ssq += __shfl_xor(ssq, 8);
    float inv = 1.f / fmaxf(sqrtf(ssq), 1e-12f);

    float krr[4] = { kr.x, kr.y, kr.z, kr.w };
    float av4[4] = { av.x, av.y, av.z, av.w };
    float ka4[4] = { kaw.x, kaw.y, kaw.z, kaw.w };
    float4 aa4, bb4, kf4;
    float* aap = (float*)&aa4; float* bbp = (float*)&bb4; float* kfp = (float*)&kf4;
#pragma unroll
    for (int j = 0; j < 4; ++j) {
        float kkn = kk[j] * inv;
        aap[j] = -kkn;
        bbp[j] = kkn * av4[j];
        kfp[j] = krr[j] * (1.f + (av4[j] - 1.f) * ka4[j]);
    }
    *(float4*)(aaout + o + c0) = aa4;
    *(float4*)(bbout + o + c0) = bb4;
    *(float4*)(kout + o + c0) = kf4;
}

// ---------------------------------------------------------------------------
// WKV recurrence. One block per (b,h). 256 threads: thread = (row i, col-chunk jc)
// i = tid>>2 (0..63), jc = tid&3 -> cols jc*16..+15. State in registers.
// ---------------------------------------------------------------------------
__global__ __launch_bounds__(256) void wkv_kernel(
    const float* __restrict__ rb, const float* __restrict__ wdb,
    const float* __restrict__ kb, const float* __restrict__ vb,
    const float* __restrict__ aab, const float* __restrict__ bbb,
    float* __restrict__ yb)
{
    const int bh = blockIdx.x;
    const int b = bh >> 4, h = bh & 15;
    const int tid = threadIdx.x;
    const int i = tid >> 2, jc = tid & 3, j0 = jc << 4;
    const size_t base = (size_t)b * Tt * Cc + h * HSs;

    float S[16];
#pragma unroll
    for (int u = 0; u < 16; ++u) S[u] = 0.f;

    for (int t = 0; t < Tt; ++t) {
        const size_t o = base + (size_t)t * Cc;
        float a_[16], w_[16], b_[16], k_[16], r_[16];
#pragma unroll
        for (int q = 0; q < 4; ++q) {
            float4 t0 = *(const float4*)(aab + o + j0 + q * 4);
            a_[q*4+0]=t0.x; a_[q*4+1]=t0.y; a_[q*4+2]=t0.z; a_[q*4+3]=t0.w;
            float4 t1 = *(const float4*)(wdb + o + j0 + q * 4);
            w_[q*4+0]=t1.x; w_[q*4+1]=t1.y; w_[q*4+2]=t1.z; w_[q*4+3]=t1.w;
            float4 t2 = *(const float4*)(bbb + o + j0 + q * 4);
            b_[q*4+0]=t2.x; b_[q*4+1]=t2.y; b_[q*4+2]=t2.z; b_[q*4+3]=t2.w;
            float4 t3 = *(const float4*)(kb + o + j0 + q * 4);
            k_[q*4+0]=t3.x; k_[q*4+1]=t3.y; k_[q*4+2]=t3.z; k_[q*4+3]=t3.w;
            float4 t4 = *(const float4*)(rb + o + j0 + q * 4);
            r_[q*4+0]=t4.x; r_[q*4+1]=t4.y; r_[q*4+2]=t4.z; r_[q*4+3]=t4.w;
        }
        float vi = vb[o + i];

        float sa = 0.f;
#pragma unroll
        for (int u = 0; u < 16; ++u) sa += S[u] * a_[u];
        sa += __shfl_xor(sa, 1);
        sa += __shfl_xor(sa, 2);

        float yp = 0.f;
#pragma unroll
        for (int u = 0; u < 16; ++u) {
            S[u] = S[u] * w_[u] + sa * b_[u] + vi * k_[u];
            yp += S[u] * r_[u];
        }
        yp += __shfl_xor(yp, 1);
        yp += __shfl_xor(yp, 2);
        if (jc == 0) yb[o + i] = yp;
    }
}

// ---------------------------------------------------------------------------
// GroupNorm over heads + r*k*r_k bonus + multiply by g -> z
// ---------------------------------------------------------------------------
__global__ __launch_bounds__(256) void gn_rt_kernel(
    const float* __restrict__ yb, const float* __restrict__ rb,
    const float* __restrict__ kb, const float* __restrict__ vb,
    const float* __restrict__ gb, const float* __restrict__ r_k,
    const float* __restrict__ ln_w, const float* __restrict__ ln_b,
    float* __restrict__ zb)
{
    const int row = blockIdx.x;
    const int tid = threadIdx.x;
    const int c0 = tid * 4;
    const int hd = tid >> 4;
    const int n0 = c0 & 63;
    const size_t o = (size_t)row * Cc;

    float4 y4 = *(const float4*)(yb + o + c0);
    float4 r4 = *(const float4*)(rb + o + c0);
    float4 k4 = *(const float4*)(kb + o + c0);
    float4 v4 = *(const float4*)(vb + o + c0);
    float4 g4 = *(const float4*)(gb + o + c0);
    float4 rk4 = *(const float4*)(r_k + hd * 64 + n0);

    float yv[4] = { y4.x, y4.y, y4.z, y4.w };
    float rv[4] = { r4.x, r4.y, r4.z, r4.w };
    float kv[4] = { k4.x, k4.y, k4.z, k4.w };
    float vv[4] = { v4.x, v4.y, v4.z, v4.w };
    float gv[4] = { g4.x, g4.y, g4.z, g4.w };
    float rkv[4] = { rk4.x, rk4.y, rk4.z, rk4.w };

    float sum = 0.f, ssq = 0.f, dot = 0.f;
#pragma unroll
    for (int j = 0; j < 4; ++j) {
        sum += yv[j];
        ssq += yv[j] * yv[j];
        dot += rv[j] * kv[j] * rkv[j];
    }
#pragma unroll
    for (int m = 1; m <= 8; m <<= 1) {
        sum += __shfl_xor(sum, m);
        ssq += __shfl_xor(ssq, m);
        dot += __shfl_xor(dot, m);
    }
    const float mu = sum * (1.f / 64.f);
    const float var = ssq * (1.f / 64.f) - mu * mu;
    const float inv = rsqrtf(var + 0.00064f);

    float4 z4;
    float* zp = (float*)&z4;
#pragma unroll
    for (int j = 0; j < 4; ++j) {
        int c = c0 + j;
        float yg = (yv[j] - mu) * inv * ln_w[c] + ln_b[c];
        yg += dot * vv[j];
        zp[j] = yg * gv[j];
    }
    *(float4*)(zb + o + c0) = z4;
}

// ---------------------------------------------------------------------------

extern "C" void kernel_launch(void* const* d_in, const int* in_sizes, int n_in,
                              void* d_out, int out_size, void* d_ws, size_t ws_size,
                              hipStream_t stream)
{
    const float* x   = (const float*)d_in[0];
    const float* x_r = (const float*)d_in[1];
    const float* x_w = (const float*)d_in[2];
    const float* x_k = (const float*)d_in[3];
    const float* x_v = (const float*)d_in[4];
    const float* x_a = (const float*)d_in[5];
    const float* x_g = (const float*)d_in[6];
    const float* w0  = (const float*)d_in[7];
    const float* w1  = (const float*)d_in[8];
    const float* w2  = (const float*)d_in[9];
    const float* a0  = (const float*)d_in[10];
    const float* a1  = (const float*)d_in[11];
    const float* a2  = (const float*)d_in[12];
    // d_in[13..15] = v0,v1,v2 : forward no-op (v_first == v on first layer)
    const float* g1  = (const float*)d_in[16];
    const float* g2  = (const float*)d_in[17];
    const float* k_k = (const float*)d_in[18];
    const float* k_a = (const float*)d_in[19];
    const float* r_k = (const float*)d_in[20];
    const float* Wr  = (const float*)d_in[21];
    const float* Wk  = (const float*)d_in[22];
    const float* Wv  = (const float*)d_in[23];
    const float* Wo  = (const float*)d_in[24];
    const float* ln_w = (const float*)d_in[25];
    const float* ln_b = (const float*)d_in[26];

    float* ws = (float*)d_ws;
    const size_t S = (size_t)Bsz * Tt * Cc;  // 4,194,304
    float* rb  = ws + 0 * S;
    float* wdb = ws + 1 * S;
    float* kb  = ws + 2 * S;
    float* vb  = ws + 3 * S;
    float* aab = ws + 4 * S;
    float* bbb = ws + 5 * S;
    float* yb  = ws + 6 * S;
    float* ab  = ws + 7 * S;
    float* gb  = ws + 8 * S;
    float* hw  = ws + 9 * S;             // 4096*64
    float* ha  = hw + 4096 * 64;         // 4096*64
    float* hg  = ha + 4096 * 64;         // 4096*128
    float* zb  = aab;                    // aa dead after wkv; reuse for z

    const int M = Bsz * Tt;              // 4096
    dim3 blk(256);

    // low-rank hidden projections (token-shift mix fused into A load)
    gemm_f32<<<dim3(1, M / 64), blk, 0, stream>>>(x, w1, hw, x_w, nullptr, M, 64, Cc, 1);   // tanh
    gemm_f32<<<dim3(1, M / 64), blk, 0, stream>>>(x, a1, ha, x_a, nullptr, M, 64, Cc, 0);
    gemm_f32<<<dim3(2, M / 64), blk, 0, stream>>>(x, g1, hg, x_g, nullptr, M, 128, Cc, 2);  // sigmoid

    // big projections
    gemm_f32<<<dim3(16, M / 64), blk, 0, stream>>>(x, Wr, rb, x_r, nullptr, M, Cc, Cc, 0);
    gemm_f32<<<dim3(16, M / 64), blk, 0, stream>>>(x, Wk, kb, x_k, nullptr, M, Cc, Cc, 0);
    gemm_f32<<<dim3(16, M / 64), blk, 0, stream>>>(x, Wv, vb, x_v, nullptr, M, Cc, Cc, 0);

    // second-stage low-rank
    gemm_f32<<<dim3(16, M / 64), blk, 0, stream>>>(hw, w2, wdb, nullptr, w0, M, Cc, 64, 3); // decay
    gemm_f32<<<dim3(16, M / 64), blk, 0, stream>>>(ha, a2, ab, nullptr, a0, M, Cc, 64, 2);  // sigmoid
    gemm_f32<<<dim3(16, M / 64), blk, 0, stream>>>(hg, g2, gb, nullptr, nullptr, M, Cc, 128, 0);

    // k / kk / aa / bb
    prep_k_kernel<<<dim3(M), blk, 0, stream>>>(kb, ab, k_k, k_a, kb, aab, bbb);

    // sequential recurrence
    wkv_kernel<<<dim3(Bsz * Hh), blk, 0, stream>>>(rb, wdb, kb, vb, aab, bbb, yb);

    // groupnorm + bonus + gate
    gn_rt_kernel<<<dim3(M), blk, 0, stream>>>(yb, rb, kb, vb, gb, r_k, ln_w, ln_b, zb);

    // output projection
    gemm_f32<<<dim3(16, M / 64), blk, 0, stream>>>(zb, Wo, (float*)d_out, nullptr, nullptr, M, Cc, Cc, 0);
}

// Round 3
// 1699.118 us; speedup vs baseline: 1.5296x; 1.5296x over previous
//
#include <hip/hip_runtime.h>
#include <math.h>

#define Bsz 4
#define Tt  1024
#define Cc  1024
#define Hh  16
#define HSs 64

typedef __attribute__((ext_vector_type(8))) short bf16x8;
typedef __attribute__((ext_vector_type(4))) float f32x4;

__device__ __forceinline__ float sigf(float x) { return 1.f / (1.f + expf(-x)); }

__device__ __forceinline__ unsigned short f2bf(float f) {
    unsigned int u = __float_as_uint(f);
    u = u + 0x7fffu + ((u >> 16) & 1u);   // RNE
    return (unsigned short)(u >> 16);
}

// ---------------------------------------------------------------------------
// fp32 tiled GEMM (small / low-rank paths): out[M,N] = f( A[M,K] @ W[K,N] + bias )
// Optional token-shift mix fused into A load. epi: 0=none 1=tanh 2=sigmoid 3=decay
// ---------------------------------------------------------------------------
__global__ __launch_bounds__(256) void gemm_f32(
    const float* __restrict__ A, const float* __restrict__ W,
    float* __restrict__ out, const float* __restrict__ mix,
    const float* __restrict__ bias, int M, int N, int K, int epi)
{
    __shared__ float As[16][65];
    __shared__ float Bs[16][65];
    const int row0 = blockIdx.y * 64;
    const int col0 = blockIdx.x * 64;
    const int tid = threadIdx.x;
    const int tr = tid >> 4, tc = tid & 15;

    float acc[4][4];
#pragma unroll
    for (int i = 0; i < 4; ++i)
#pragma unroll
        for (int j = 0; j < 4; ++j) acc[i][j] = 0.f;

    for (int k0 = 0; k0 < K; k0 += 16) {
#pragma unroll
        for (int s = 0; s < 4; ++s) {
            int i = tid + s * 256;
            int rr = i >> 4, kk = i & 15;
            int r = row0 + rr;
            int c = k0 + kk;
            float xv = A[r * K + c];
            float val;
            if (mix) {
                int t = r & (Tt - 1);
                float xp = (t > 0) ? A[(r - 1) * K + c] : 0.f;
                val = xv + (xp - xv) * mix[c];
            } else val = xv;
            As[kk][rr] = val;
        }
#pragma unroll
        for (int s = 0; s < 4; ++s) {
            int i = tid + s * 256;
            int kk = i >> 6, cc = i & 63;
            Bs[kk][cc] = W[(k0 + kk) * N + col0 + cc];
        }
        __syncthreads();
#pragma unroll
        for (int kk = 0; kk < 16; ++kk) {
            float a[4], b[4];
#pragma unroll
            for (int u = 0; u < 4; ++u) a[u] = As[kk][tr * 4 + u];
#pragma unroll
            for (int u = 0; u < 4; ++u) b[u] = Bs[kk][tc * 4 + u];
#pragma unroll
            for (int i = 0; i < 4; ++i)
#pragma unroll
                for (int j = 0; j < 4; ++j) acc[i][j] += a[i] * b[j];
        }
        __syncthreads();
    }

#pragma unroll
    for (int i = 0; i < 4; ++i) {
        int r = row0 + tr * 4 + i;
#pragma unroll
        for (int j = 0; j < 4; ++j) {
            int c = col0 + tc * 4 + j;
            float v = acc[i][j];
            if (bias) v += bias[c];
            if (epi == 1) v = tanhf(v);
            else if (epi == 2) v = sigf(v);
            else if (epi == 3) v = expf(-0.60653065971263342f * sigf(v));
            out[(size_t)r * N + c] = v;
        }
    }
}

// ---------------------------------------------------------------------------
// mixcast: xr/xk/xv = bf16( x + (shift(x)-x)*mix )   one block per token row
// ---------------------------------------------------------------------------
__global__ __launch_bounds__(256) void mixcast_kernel(
    const float* __restrict__ x, const float* __restrict__ x_r,
    const float* __restrict__ x_k, const float* __restrict__ x_v,
    unsigned short* __restrict__ xr, unsigned short* __restrict__ xk,
    unsigned short* __restrict__ xv)
{
    const int row = blockIdx.x;
    const int c0 = threadIdx.x * 4;
    const size_t o = (size_t)row * Cc;
    float4 xc = *(const float4*)(x + o + c0);
    float4 xp;
    if (row & (Tt - 1)) xp = *(const float4*)(x + o - Cc + c0);
    else { xp.x = xp.y = xp.z = xp.w = 0.f; }
    float4 mr = *(const float4*)(x_r + c0);
    float4 mk = *(const float4*)(x_k + c0);
    float4 mv = *(const float4*)(x_v + c0);
    const float* xcf = (const float*)&xc; const float* xpf = (const float*)&xp;
    const float* mrf = (const float*)&mr; const float* mkf = (const float*)&mk;
    const float* mvf = (const float*)&mv;
    ushort4 r4, k4, v4;
    unsigned short* rp = (unsigned short*)&r4;
    unsigned short* kp = (unsigned short*)&k4;
    unsigned short* vp = (unsigned short*)&v4;
#pragma unroll
    for (int j = 0; j < 4; ++j) {
        float xx = xpf[j] - xcf[j];
        rp[j] = f2bf(xcf[j] + xx * mrf[j]);
        kp[j] = f2bf(xcf[j] + xx * mkf[j]);
        vp[j] = f2bf(xcf[j] + xx * mvf[j]);
    }
    *(ushort4*)(xr + o + c0) = r4;
    *(ushort4*)(xk + o + c0) = k4;
    *(ushort4*)(xv + o + c0) = v4;
}

// ---------------------------------------------------------------------------
// transpose+cast: WT[n][k] = bf16(W[k][n]),  W is 1024x1024 fp32
// ---------------------------------------------------------------------------
__global__ __launch_bounds__(256) void transpose_cast(
    const float* __restrict__ W, unsigned short* __restrict__ WT)
{
    __shared__ unsigned short tile[64][68];
    const int n0 = blockIdx.x * 64, k0 = blockIdx.y * 64;
    const int tid = threadIdx.x;
    const int tr = tid >> 4, tc4 = (tid & 15) * 4;
#pragma unroll
    for (int s = 0; s < 4; ++s) {
        int kk = tr + s * 16;
        float4 w4 = *(const float4*)(W + (size_t)(k0 + kk) * Cc + n0 + tc4);
        tile[kk][tc4 + 0] = f2bf(w4.x);
        tile[kk][tc4 + 1] = f2bf(w4.y);
        tile[kk][tc4 + 2] = f2bf(w4.z);
        tile[kk][tc4 + 3] = f2bf(w4.w);
    }
    __syncthreads();
#pragma unroll
    for (int s = 0; s < 4; ++s) {
        int nn = tr + s * 16;
        ushort4 o4;
        o4.x = tile[tc4 + 0][nn];
        o4.y = tile[tc4 + 1][nn];
        o4.z = tile[tc4 + 2][nn];
        o4.w = tile[tc4 + 3][nn];
        *(ushort4*)(WT + (size_t)(n0 + nn) * Cc + k0 + tc4) = o4;
    }
}

// ---------------------------------------------------------------------------
// bf16 MFMA GEMM: out[M,N] (fp32) = A[M,K](bf16) @ W[K,N], W given as WT[N][K] bf16
// 128x128 tile, BK=32, 4 waves (2x2), 16x16x32 MFMA, padded LDS (stride 40)
// Staging: 256 threads cover 128 rows x 32 ushorts = 512 uint4 chunks -> 2/thread/buf
// ---------------------------------------------------------------------------
__global__ __launch_bounds__(256) void gemm_bf16(
    const unsigned short* __restrict__ A, const unsigned short* __restrict__ WT,
    float* __restrict__ out, int M, int N, int K)
{
    __shared__ __attribute__((aligned(16))) unsigned short As[128][40];
    __shared__ __attribute__((aligned(16))) unsigned short Bs[128][40];
    const int row0 = blockIdx.y * 128;
    const int col0 = blockIdx.x * 128;
    const int tid = threadIdx.x;
    const int wave = tid >> 6, lane = tid & 63;
    const int wr = wave >> 1, wc = wave & 1;
    const int lr = lane & 15, lk = lane >> 4;

    f32x4 acc[4][4];
#pragma unroll
    for (int m = 0; m < 4; ++m)
#pragma unroll
        for (int n = 0; n < 4; ++n)
#pragma unroll
            for (int r = 0; r < 4; ++r) acc[m][n][r] = 0.f;

    const int sr = tid >> 2;           // 0..63
    const int sc = (tid & 3) * 8;      // 0,8,16,24 (ushort offset; 16B chunks)

    for (int k0 = 0; k0 < K; k0 += 32) {
        uint4 a0v = *(const uint4*)(A  + (size_t)(row0 + sr) * K + k0 + sc);
        uint4 a1v = *(const uint4*)(A  + (size_t)(row0 + 64 + sr) * K + k0 + sc);
        uint4 b0v = *(const uint4*)(WT + (size_t)(col0 + sr) * K + k0 + sc);
        uint4 b1v = *(const uint4*)(WT + (size_t)(col0 + 64 + sr) * K + k0 + sc);
        *(uint4*)&As[sr][sc]      = a0v;
        *(uint4*)&As[64 + sr][sc] = a1v;
        *(uint4*)&Bs[sr][sc]      = b0v;
        *(uint4*)&Bs[64 + sr][sc] = b1v;
        __syncthreads();
        bf16x8 af[4], bff[4];
#pragma unroll
        for (int m = 0; m < 4; ++m)
            af[m] = *(const bf16x8*)&As[wr * 64 + m * 16 + lr][lk * 8];
#pragma unroll
        for (int n = 0; n < 4; ++n)
            bff[n] = *(const bf16x8*)&Bs[wc * 64 + n * 16 + lr][lk * 8];
#pragma unroll
        for (int m = 0; m < 4; ++m)
#pragma unroll
            for (int n = 0; n < 4; ++n)
                acc[m][n] = __builtin_amdgcn_mfma_f32_16x16x32_bf16(af[m], bff[n], acc[m][n], 0, 0, 0);
        __syncthreads();
    }

#pragma unroll
    for (int m = 0; m < 4; ++m)
#pragma unroll
        for (int n = 0; n < 4; ++n) {
            int col = col0 + wc * 64 + n * 16 + lr;
#pragma unroll
            for (int r = 0; r < 4; ++r) {
                int row = row0 + wr * 64 + m * 16 + lk * 4 + r;
                out[(size_t)row * N + col] = acc[m][n][r];
            }
        }
}

// ---------------------------------------------------------------------------
// prep_k: kk = normalize_perhead(kraw*k_k); aa=-kk; bb=kk*a; k=kraw*(1+(a-1)*k_a)
// ---------------------------------------------------------------------------
__global__ __launch_bounds__(256) void prep_k_kernel(
    const float* kraw, const float* __restrict__ a,
    const float* __restrict__ k_k, const float* __restrict__ k_a,
    float* kout, float* __restrict__ aaout, float* __restrict__ bbout)
{
    const int row = blockIdx.x;
    const int tid = threadIdx.x;
    const int c0 = tid * 4;
    const size_t o = (size_t)row * Cc;

    float4 kr = *(const float4*)(kraw + o + c0);
    float4 kkw = *(const float4*)(k_k + c0);
    float4 av = *(const float4*)(a + o + c0);
    float4 kaw = *(const float4*)(k_a + c0);

    float kk[4] = { kr.x * kkw.x, kr.y * kkw.y, kr.z * kkw.z, kr.w * kkw.w };
    float ssq = kk[0]*kk[0] + kk[1]*kk[1] + kk[2]*kk[2] + kk[3]*kk[3];
    ssq += __shfl_xor(ssq, 1);
    ssq += __shfl_xor(ssq, 2);
    ssq += __shfl_xor(ssq, 4);
    ssq += __shfl_xor(ssq, 8);
    float inv = 1.f / fmaxf(sqrtf(ssq), 1e-12f);

    float krr[4] = { kr.x, kr.y, kr.z, kr.w };
    float av4[4] = { av.x, av.y, av.z, av.w };
    float ka4[4] = { kaw.x, kaw.y, kaw.z, kaw.w };
    float4 aa4, bb4, kf4;
    float* aap = (float*)&aa4; float* bbp = (float*)&bb4; float* kfp = (float*)&kf4;
#pragma unroll
    for (int j = 0; j < 4; ++j) {
        float kkn = kk[j] * inv;
        aap[j] = -kkn;
        bbp[j] = kkn * av4[j];
        kfp[j] = krr[j] * (1.f + (av4[j] - 1.f) * ka4[j]);
    }
    *(float4*)(aaout + o + c0) = aa4;
    *(float4*)(bbout + o + c0) = bb4;
    *(float4*)(kout + o + c0) = kf4;
}

// ---------------------------------------------------------------------------
// WKV recurrence, register-double-buffered prefetch.
// One block per (b,h). 256 threads: i = tid>>2 (row), jc = tid&3 (16-col chunk).
// ---------------------------------------------------------------------------
#define WKV_LOAD(P, t) do { \
    const size_t o_ = base + (size_t)(t) * Cc + j0; \
    _Pragma("unroll") \
    for (int q = 0; q < 4; ++q) { \
        P##_a[q] = *(const float4*)(aab + o_ + q * 4); \
        P##_w[q] = *(const float4*)(wdb + o_ + q * 4); \
        P##_b[q] = *(const float4*)(bbb + o_ + q * 4); \
        P##_k[q] = *(const float4*)(kb + o_ + q * 4); \
        P##_r[q] = *(const float4*)(rb + o_ + q * 4); \
    } \
    P##_v = vb[base + (size_t)(t) * Cc + i]; \
} while (0)

#define WKV_STEP(P, t) do { \
    float sa0 = 0.f, sa1 = 0.f, sa2 = 0.f, sa3 = 0.f; \
    _Pragma("unroll") \
    for (int q = 0; q < 4; ++q) { \
        const float* ap_ = (const float*)&P##_a[q]; \
        float* sq_ = (q == 0 ? &sa0 : q == 1 ? &sa1 : q == 2 ? &sa2 : &sa3); \
        _Pragma("unroll") \
        for (int e = 0; e < 4; ++e) *sq_ += S[q * 4 + e] * ap_[e]; \
    } \
    float sa = (sa0 + sa1) + (sa2 + sa3); \
    sa += __shfl_xor(sa, 1); \
    sa += __shfl_xor(sa, 2); \
    float y0 = 0.f, y1 = 0.f, y2 = 0.f, y3 = 0.f; \
    _Pragma("unroll") \
    for (int q = 0; q < 4; ++q) { \
        const float* wp_ = (const float*)&P##_w[q]; \
        const float* bp_ = (const float*)&P##_b[q]; \
        const float* kp_ = (const float*)&P##_k[q]; \
        const float* rp_ = (const float*)&P##_r[q]; \
        float* yq_ = (q == 0 ? &y0 : q == 1 ? &y1 : q == 2 ? &y2 : &y3); \
        _Pragma("unroll") \
        for (int e = 0; e < 4; ++e) { \
            int u = q * 4 + e; \
            float tmp = sa * bp_[e]; \
            tmp = fmaf(P##_v, kp_[e], tmp); \
            S[u] = fmaf(S[u], wp_[e], tmp); \
            *yq_ += S[u] * rp_[e]; \
        } \
    } \
    float yp = (y0 + y1) + (y2 + y3); \
    yp += __shfl_xor(yp, 1); \
    yp += __shfl_xor(yp, 2); \
    if (jc == 0) yb[base + (size_t)(t) * Cc + i] = yp; \
} while (0)

__global__ __launch_bounds__(256, 1) void wkv_kernel(
    const float* __restrict__ rb, const float* __restrict__ wdb,
    const float* __restrict__ kb, const float* __restrict__ vb,
    const float* __restrict__ aab, const float* __restrict__ bbb,
    float* __restrict__ yb)
{
    const int bh = blockIdx.x;
    const int b = bh >> 4, h = bh & 15;
    const int tid = threadIdx.x;
    const int i = tid >> 2, jc = tid & 3, j0 = jc << 4;
    const size_t base = (size_t)b * Tt * Cc + h * HSs;

    float S[16];
#pragma unroll
    for (int u = 0; u < 16; ++u) S[u] = 0.f;

    float4 A_a[4], A_w[4], A_b[4], A_k[4], A_r[4]; float A_v;
    float4 B_a[4], B_w[4], B_b[4], B_k[4], B_r[4]; float B_v;

    WKV_LOAD(A, 0);
    for (int t = 0; t < Tt; t += 2) {
        WKV_LOAD(B, t + 1);
        WKV_STEP(A, t);
        if (t + 2 < Tt) WKV_LOAD(A, t + 2);
        WKV_STEP(B, t + 1);
    }
}

// ---------------------------------------------------------------------------
// GroupNorm + r*k*r_k bonus + gate; writes z as bf16 for the Wo MFMA GEMM
// ---------------------------------------------------------------------------
__global__ __launch_bounds__(256) void gn_rt_kernel(
    const float* __restrict__ yb, const float* __restrict__ rb,
    const float* __restrict__ kb, const float* __restrict__ vb,
    const float* __restrict__ gb, const float* __restrict__ r_k,
    const float* __restrict__ ln_w, const float* __restrict__ ln_b,
    unsigned short* __restrict__ zb)
{
    const int row = blockIdx.x;
    const int tid = threadIdx.x;
    const int c0 = tid * 4;
    const int hd = tid >> 4;
    const int n0 = c0 & 63;
    const size_t o = (size_t)row * Cc;

    float4 y4 = *(const float4*)(yb + o + c0);
    float4 r4 = *(const float4*)(rb + o + c0);
    float4 k4 = *(const float4*)(kb + o + c0);
    float4 v4 = *(const float4*)(vb + o + c0);
    float4 g4 = *(const float4*)(gb + o + c0);
    float4 rk4 = *(const float4*)(r_k + hd * 64 + n0);

    float yv[4] = { y4.x, y4.y, y4.z, y4.w };
    float rv[4] = { r4.x, r4.y, r4.z, r4.w };
    float kv[4] = { k4.x, k4.y, k4.z, k4.w };
    float vv[4] = { v4.x, v4.y, v4.z, v4.w };
    float gv[4] = { g4.x, g4.y, g4.z, g4.w };
    float rkv[4] = { rk4.x, rk4.y, rk4.z, rk4.w };

    float sum = 0.f, ssq = 0.f, dot = 0.f;
#pragma unroll
    for (int j = 0; j < 4; ++j) {
        sum += yv[j];
        ssq += yv[j] * yv[j];
        dot += rv[j] * kv[j] * rkv[j];
    }
#pragma unroll
    for (int m = 1; m <= 8; m <<= 1) {
        sum += __shfl_xor(sum, m);
        ssq += __shfl_xor(ssq, m);
        dot += __shfl_xor(dot, m);
    }
    const float mu = sum * (1.f / 64.f);
    const float var = ssq * (1.f / 64.f) - mu * mu;
    const float inv = rsqrtf(var + 0.00064f);

    ushort4 z4;
    unsigned short* zp = (unsigned short*)&z4;
#pragma unroll
    for (int j = 0; j < 4; ++j) {
        int c = c0 + j;
        float yg = (yv[j] - mu) * inv * ln_w[c] + ln_b[c];
        yg += dot * vv[j];
        zp[j] = f2bf(yg * gv[j]);
    }
    *(ushort4*)(zb + o + c0) = z4;
}

// ---------------------------------------------------------------------------

extern "C" void kernel_launch(void* const* d_in, const int* in_sizes, int n_in,
                              void* d_out, int out_size, void* d_ws, size_t ws_size,
                              hipStream_t stream)
{
    const float* x   = (const float*)d_in[0];
    const float* x_r = (const float*)d_in[1];
    const float* x_w = (const float*)d_in[2];
    const float* x_k = (const float*)d_in[3];
    const float* x_v = (const float*)d_in[4];
    const float* x_a = (const float*)d_in[5];
    const float* x_g = (const float*)d_in[6];
    const float* w0  = (const float*)d_in[7];
    const float* w1  = (const float*)d_in[8];
    const float* w2  = (const float*)d_in[9];
    const float* a0  = (const float*)d_in[10];
    const float* a1  = (const float*)d_in[11];
    const float* a2  = (const float*)d_in[12];
    // v0,v1,v2 (13..15): forward no-op on first-layer call
    const float* g1  = (const float*)d_in[16];
    const float* g2  = (const float*)d_in[17];
    const float* k_k = (const float*)d_in[18];
    const float* k_a = (const float*)d_in[19];
    const float* r_k = (const float*)d_in[20];
    const float* Wr  = (const float*)d_in[21];
    const float* Wk  = (const float*)d_in[22];
    const float* Wv  = (const float*)d_in[23];
    const float* Wo  = (const float*)d_in[24];
    const float* ln_w = (const float*)d_in[25];
    const float* ln_b = (const float*)d_in[26];

    float* ws = (float*)d_ws;
    const size_t S = (size_t)Bsz * Tt * Cc;       // 4,194,304 floats
    const int M = Bsz * Tt;                        // 4096

    float* rb  = ws + 0 * S;
    float* wdb = ws + 1 * S;
    unsigned short* WoT = (unsigned short*)(ws + 1 * S);   // after wkv
    float* kb  = ws + 2 * S;
    float* vb  = ws + 3 * S;
    float* aab = ws + 4 * S;
    unsigned short* zb = (unsigned short*)(ws + 4 * S);    // after wkv
    float* bbb = ws + 5 * S;
    float* yb  = ws + 6 * S;
    float* hw  = yb;                    // 4096*64   (dead before wkv writes yb)
    float* ha  = yb + 262144;           // 4096*64
    float* hg  = yb + 524288;           // 4096*128
    unsigned short* xr = (unsigned short*)(ws + 7 * S);    // 8 MB
    unsigned short* xk = xr + S;                           // 8 MB
    float* ab  = ws + 7 * S;            // after xr/xk consumed
    unsigned short* xv = (unsigned short*)(ws + 8 * S);    // 8 MB
    unsigned short* WrT = xv + S;                          // 2 MB
    unsigned short* WkT = WrT + 1048576;
    unsigned short* WvT = WkT + 1048576;
    float* gb  = ws + 8 * S;            // after xv/W*T consumed

    dim3 blk(256);

    // mixed bf16 inputs + transposed bf16 weights
    mixcast_kernel<<<dim3(M), blk, 0, stream>>>(x, x_r, x_k, x_v, xr, xk, xv);
    transpose_cast<<<dim3(16, 16), blk, 0, stream>>>(Wr, WrT);
    transpose_cast<<<dim3(16, 16), blk, 0, stream>>>(Wk, WkT);
    transpose_cast<<<dim3(16, 16), blk, 0, stream>>>(Wv, WvT);

    // low-rank hidden projections (fp32, token-shift fused)
    gemm_f32<<<dim3(1, M / 64), blk, 0, stream>>>(x, w1, hw, x_w, nullptr, M, 64, Cc, 1);   // tanh
    gemm_f32<<<dim3(1, M / 64), blk, 0, stream>>>(x, a1, ha, x_a, nullptr, M, 64, Cc, 0);
    gemm_f32<<<dim3(2, M / 64), blk, 0, stream>>>(x, g1, hg, x_g, nullptr, M, 128, Cc, 2);  // sigmoid

    // big projections: bf16 MFMA
    gemm_bf16<<<dim3(8, 32), blk, 0, stream>>>(xr, WrT, rb, M, Cc, Cc);
    gemm_bf16<<<dim3(8, 32), blk, 0, stream>>>(xk, WkT, kb, M, Cc, Cc);
    gemm_bf16<<<dim3(8, 32), blk, 0, stream>>>(xv, WvT, vb, M, Cc, Cc);

    // second-stage low-rank (fp32) — xr/xk/xv and W*T are dead now
    gemm_f32<<<dim3(16, M / 64), blk, 0, stream>>>(hw, w2, wdb, nullptr, w0, M, Cc, 64, 3); // decay
    gemm_f32<<<dim3(16, M / 64), blk, 0, stream>>>(ha, a2, ab, nullptr, a0, M, Cc, 64, 2);  // sigmoid
    gemm_f32<<<dim3(16, M / 64), blk, 0, stream>>>(hg, g2, gb, nullptr, nullptr, M, Cc, 128, 0);

    // k / kk / aa / bb
    prep_k_kernel<<<dim3(M), blk, 0, stream>>>(kb, ab, k_k, k_a, kb, aab, bbb);

    // sequential recurrence (register-prefetch double-buffered)
    wkv_kernel<<<dim3(Bsz * Hh), blk, 0, stream>>>(rb, wdb, kb, vb, aab, bbb, yb);

    // Wo transpose (into dead wdb slot), groupnorm+bonus+gate -> z (bf16)
    transpose_cast<<<dim3(16, 16), blk, 0, stream>>>(Wo, WoT);
    gn_rt_kernel<<<dim3(M), blk, 0, stream>>>(yb, rb, kb, vb, gb, r_k, ln_w, ln_b, zb);

    // output projection: bf16 MFMA
    gemm_bf16<<<dim3(8, 32), blk, 0, stream>>>(zb, WoT, (float*)d_out, M, Cc, Cc);
}

// Round 4
// 1036.125 us; speedup vs baseline: 2.5083x; 1.6399x over previous
//
#include <hip/hip_runtime.h>
#include <math.h>

#define Bsz 4
#define Tt  1024
#define Cc  1024
#define Hh  16
#define HSs 64
#define WCHUNK 16

typedef __attribute__((ext_vector_type(8))) short bf16x8;
typedef __attribute__((ext_vector_type(4))) float f32x4;

__device__ __forceinline__ float sigf(float x) { return 1.f / (1.f + expf(-x)); }

__device__ __forceinline__ unsigned short f2bf(float f) {
    unsigned int u = __float_as_uint(f);
    u = u + 0x7fffu + ((u >> 16) & 1u);   // RNE
    return (unsigned short)(u >> 16);
}

// ---------------------------------------------------------------------------
// fp32 tiled GEMM (small / low-rank paths): out[M,N] = f( A[M,K] @ W[K,N] + bias )
// Optional token-shift mix fused into A load. epi: 0=none 1=tanh 2=sigmoid 3=decay
// ---------------------------------------------------------------------------
__global__ __launch_bounds__(256) void gemm_f32(
    const float* __restrict__ A, const float* __restrict__ W,
    float* __restrict__ out, const float* __restrict__ mix,
    const float* __restrict__ bias, int M, int N, int K, int epi)
{
    __shared__ float As[16][65];
    __shared__ float Bs[16][65];
    const int row0 = blockIdx.y * 64;
    const int col0 = blockIdx.x * 64;
    const int tid = threadIdx.x;
    const int tr = tid >> 4, tc = tid & 15;

    float acc[4][4];
#pragma unroll
    for (int i = 0; i < 4; ++i)
#pragma unroll
        for (int j = 0; j < 4; ++j) acc[i][j] = 0.f;

    for (int k0 = 0; k0 < K; k0 += 16) {
#pragma unroll
        for (int s = 0; s < 4; ++s) {
            int i = tid + s * 256;
            int rr = i >> 4, kk = i & 15;
            int r = row0 + rr;
            int c = k0 + kk;
            float xv = A[r * K + c];
            float val;
            if (mix) {
                int t = r & (Tt - 1);
                float xp = (t > 0) ? A[(r - 1) * K + c] : 0.f;
                val = xv + (xp - xv) * mix[c];
            } else val = xv;
            As[kk][rr] = val;
        }
#pragma unroll
        for (int s = 0; s < 4; ++s) {
            int i = tid + s * 256;
            int kk = i >> 6, cc = i & 63;
            Bs[kk][cc] = W[(k0 + kk) * N + col0 + cc];
        }
        __syncthreads();
#pragma unroll
        for (int kk = 0; kk < 16; ++kk) {
            float a[4], b[4];
#pragma unroll
            for (int u = 0; u < 4; ++u) a[u] = As[kk][tr * 4 + u];
#pragma unroll
            for (int u = 0; u < 4; ++u) b[u] = Bs[kk][tc * 4 + u];
#pragma unroll
            for (int i = 0; i < 4; ++i)
#pragma unroll
                for (int j = 0; j < 4; ++j) acc[i][j] += a[i] * b[j];
        }
        __syncthreads();
    }

#pragma unroll
    for (int i = 0; i < 4; ++i) {
        int r = row0 + tr * 4 + i;
#pragma unroll
        for (int j = 0; j < 4; ++j) {
            int c = col0 + tc * 4 + j;
            float v = acc[i][j];
            if (bias) v += bias[c];
            if (epi == 1) v = tanhf(v);
            else if (epi == 2) v = sigf(v);
            else if (epi == 3) v = expf(-0.60653065971263342f * sigf(v));
            out[(size_t)r * N + c] = v;
        }
    }
}

// ---------------------------------------------------------------------------
// mixcast: xr/xk/xv = bf16( x + (shift(x)-x)*mix )   one block per token row
// ---------------------------------------------------------------------------
__global__ __launch_bounds__(256) void mixcast_kernel(
    const float* __restrict__ x, const float* __restrict__ x_r,
    const float* __restrict__ x_k, const float* __restrict__ x_v,
    unsigned short* __restrict__ xr, unsigned short* __restrict__ xk,
    unsigned short* __restrict__ xv)
{
    const int row = blockIdx.x;
    const int c0 = threadIdx.x * 4;
    const size_t o = (size_t)row * Cc;
    float4 xc = *(const float4*)(x + o + c0);
    float4 xp;
    if (row & (Tt - 1)) xp = *(const float4*)(x + o - Cc + c0);
    else { xp.x = xp.y = xp.z = xp.w = 0.f; }
    float4 mr = *(const float4*)(x_r + c0);
    float4 mk = *(const float4*)(x_k + c0);
    float4 mv = *(const float4*)(x_v + c0);
    const float* xcf = (const float*)&xc; const float* xpf = (const float*)&xp;
    const float* mrf = (const float*)&mr; const float* mkf = (const float*)&mk;
    const float* mvf = (const float*)&mv;
    ushort4 r4, k4, v4;
    unsigned short* rp = (unsigned short*)&r4;
    unsigned short* kp = (unsigned short*)&k4;
    unsigned short* vp = (unsigned short*)&v4;
#pragma unroll
    for (int j = 0; j < 4; ++j) {
        float xx = xpf[j] - xcf[j];
        rp[j] = f2bf(xcf[j] + xx * mrf[j]);
        kp[j] = f2bf(xcf[j] + xx * mkf[j]);
        vp[j] = f2bf(xcf[j] + xx * mvf[j]);
    }
    *(ushort4*)(xr + o + c0) = r4;
    *(ushort4*)(xk + o + c0) = k4;
    *(ushort4*)(xv + o + c0) = v4;
}

// ---------------------------------------------------------------------------
// transpose+cast: WT[n][k] = bf16(W[k][n]),  W is 1024x1024 fp32
// ---------------------------------------------------------------------------
__global__ __launch_bounds__(256) void transpose_cast(
    const float* __restrict__ W, unsigned short* __restrict__ WT)
{
    __shared__ unsigned short tile[64][68];
    const int n0 = blockIdx.x * 64, k0 = blockIdx.y * 64;
    const int tid = threadIdx.x;
    const int tr = tid >> 4, tc4 = (tid & 15) * 4;
#pragma unroll
    for (int s = 0; s < 4; ++s) {
        int kk = tr + s * 16;
        float4 w4 = *(const float4*)(W + (size_t)(k0 + kk) * Cc + n0 + tc4);
        tile[kk][tc4 + 0] = f2bf(w4.x);
        tile[kk][tc4 + 1] = f2bf(w4.y);
        tile[kk][tc4 + 2] = f2bf(w4.z);
        tile[kk][tc4 + 3] = f2bf(w4.w);
    }
    __syncthreads();
#pragma unroll
    for (int s = 0; s < 4; ++s) {
        int nn = tr + s * 16;
        ushort4 o4;
        o4.x = tile[tc4 + 0][nn];
        o4.y = tile[tc4 + 1][nn];
        o4.z = tile[tc4 + 2][nn];
        o4.w = tile[tc4 + 3][nn];
        *(ushort4*)(WT + (size_t)(n0 + nn) * Cc + k0 + tc4) = o4;
    }
}

// ---------------------------------------------------------------------------
// bf16 MFMA GEMM: out[M,N] (fp32) = A[M,K](bf16) @ W[K,N], W given as WT[N][K] bf16
// 128x128 tile, BK=32, 4 waves (2x2), 16x16x32 MFMA, padded LDS (stride 40)
// ---------------------------------------------------------------------------
__global__ __launch_bounds__(256) void gemm_bf16(
    const unsigned short* __restrict__ A, const unsigned short* __restrict__ WT,
    float* __restrict__ out, int M, int N, int K)
{
    __shared__ __attribute__((aligned(16))) unsigned short As[128][40];
    __shared__ __attribute__((aligned(16))) unsigned short Bs[128][40];
    const int row0 = blockIdx.y * 128;
    const int col0 = blockIdx.x * 128;
    const int tid = threadIdx.x;
    const int wave = tid >> 6, lane = tid & 63;
    const int wr = wave >> 1, wc = wave & 1;
    const int lr = lane & 15, lk = lane >> 4;

    f32x4 acc[4][4];
#pragma unroll
    for (int m = 0; m < 4; ++m)
#pragma unroll
        for (int n = 0; n < 4; ++n)
#pragma unroll
            for (int r = 0; r < 4; ++r) acc[m][n][r] = 0.f;

    const int sr = tid >> 2;           // 0..63
    const int sc = (tid & 3) * 8;      // 0,8,16,24 (ushort offset; 16B chunks)

    for (int k0 = 0; k0 < K; k0 += 32) {
        uint4 a0v = *(const uint4*)(A  + (size_t)(row0 + sr) * K + k0 + sc);
        uint4 a1v = *(const uint4*)(A  + (size_t)(row0 + 64 + sr) * K + k0 + sc);
        uint4 b0v = *(const uint4*)(WT + (size_t)(col0 + sr) * K + k0 + sc);
        uint4 b1v = *(const uint4*)(WT + (size_t)(col0 + 64 + sr) * K + k0 + sc);
        *(uint4*)&As[sr][sc]      = a0v;
        *(uint4*)&As[64 + sr][sc] = a1v;
        *(uint4*)&Bs[sr][sc]      = b0v;
        *(uint4*)&Bs[64 + sr][sc] = b1v;
        __syncthreads();
        bf16x8 af[4], bff[4];
#pragma unroll
        for (int m = 0; m < 4; ++m)
            af[m] = *(const bf16x8*)&As[wr * 64 + m * 16 + lr][lk * 8];
#pragma unroll
        for (int n = 0; n < 4; ++n)
            bff[n] = *(const bf16x8*)&Bs[wc * 64 + n * 16 + lr][lk * 8];
#pragma unroll
        for (int m = 0; m < 4; ++m)
#pragma unroll
            for (int n = 0; n < 4; ++n)
                acc[m][n] = __builtin_amdgcn_mfma_f32_16x16x32_bf16(af[m], bff[n], acc[m][n], 0, 0, 0);
        __syncthreads();
    }

#pragma unroll
    for (int m = 0; m < 4; ++m)
#pragma unroll
        for (int n = 0; n < 4; ++n) {
            int col = col0 + wc * 64 + n * 16 + lr;
#pragma unroll
            for (int r = 0; r < 4; ++r) {
                int row = row0 + wr * 64 + m * 16 + lk * 4 + r;
                out[(size_t)row * N + col] = acc[m][n][r];
            }
        }
}

// ---------------------------------------------------------------------------
// prep_k: kk = normalize_perhead(kraw*k_k); aa=-kk; bb=kk*a; k=kraw*(1+(a-1)*k_a)
// ---------------------------------------------------------------------------
__global__ __launch_bounds__(256) void prep_k_kernel(
    const float* kraw, const float* __restrict__ a,
    const float* __restrict__ k_k, const float* __restrict__ k_a,
    float* kout, float* __restrict__ aaout, float* __restrict__ bbout)
{
    const int row = blockIdx.x;
    const int tid = threadIdx.x;
    const int c0 = tid * 4;
    const size_t o = (size_t)row * Cc;

    float4 kr = *(const float4*)(kraw + o + c0);
    float4 kkw = *(const float4*)(k_k + c0);
    float4 av = *(const float4*)(a + o + c0);
    float4 kaw = *(const float4*)(k_a + c0);

    float kk[4] = { kr.x * kkw.x, kr.y * kkw.y, kr.z * kkw.z, kr.w * kkw.w };
    float ssq = kk[0]*kk[0] + kk[1]*kk[1] + kk[2]*kk[2] + kk[3]*kk[3];
    ssq += __shfl_xor(ssq, 1);
    ssq += __shfl_xor(ssq, 2);
    ssq += __shfl_xor(ssq, 4);
    ssq += __shfl_xor(ssq, 8);
    float inv = 1.f / fmaxf(sqrtf(ssq), 1e-12f);

    float krr[4] = { kr.x, kr.y, kr.z, kr.w };
    float av4[4] = { av.x, av.y, av.z, av.w };
    float ka4[4] = { kaw.x, kaw.y, kaw.z, kaw.w };
    float4 aa4, bb4, kf4;
    float* aap = (float*)&aa4; float* bbp = (float*)&bb4; float* kfp = (float*)&kf4;
#pragma unroll
    for (int j = 0; j < 4; ++j) {
        float kkn = kk[j] * inv;
        aap[j] = -kkn;
        bbp[j] = kkn * av4[j];
        kfp[j] = krr[j] * (1.f + (av4[j] - 1.f) * ka4[j]);
    }
    *(float4*)(aaout + o + c0) = aa4;
    *(float4*)(bbout + o + c0) = bb4;
    *(float4*)(kout + o + c0) = kf4;
}

// ---------------------------------------------------------------------------
// WKV recurrence, producer/consumer LDS pipeline.
// One block of 512 threads per (b,h): waves 0-3 compute (thread = (row i, 16-col
// chunk jc)), waves 4-7 stage WCHUNK steps of {a,w,b,k,r,v} into a double-buffered
// LDS ring. Wave-uniform role branch; one __syncthreads per phase.
// LDS layout per step s: [s*384 + arr*64 + j], arr: 0=a 1=w 2=b 3=k 4=r 5=v.
// ---------------------------------------------------------------------------
__global__ __launch_bounds__(512, 1) void wkv_kernel(
    const float* __restrict__ rb, const float* __restrict__ wdb,
    const float* __restrict__ kb, const float* __restrict__ vb,
    const float* __restrict__ aab, const float* __restrict__ bbb,
    float* __restrict__ yb)
{
    __shared__ float lds[2][WCHUNK * 6 * 64];
    const int bh = blockIdx.x;
    const int b = bh >> 4, h = bh & 15;
    const int tid = threadIdx.x;
    const size_t base = (size_t)b * Tt * Cc + h * HSs;
    const int nph = Tt / WCHUNK;   // 64

    if (tid >= 256) {
        // ---- producer role: 256 threads, 1 float4 per array per phase ----
        const int st = tid - 256;
        const int s_ = st >> 4;           // step within chunk 0..15
        const int l16 = (st & 15) * 4;    // float offset within 64-col slice
        {
            float* dstp = lds[0] + s_ * 384 + l16;
            const size_t go = base + (size_t)s_ * Cc + l16;
            *(float4*)(dstp + 0 * 64) = *(const float4*)(aab + go);
            *(float4*)(dstp + 1 * 64) = *(const float4*)(wdb + go);
            *(float4*)(dstp + 2 * 64) = *(const float4*)(bbb + go);
            *(float4*)(dstp + 3 * 64) = *(const float4*)(kb + go);
            *(float4*)(dstp + 4 * 64) = *(const float4*)(rb + go);
            *(float4*)(dstp + 5 * 64) = *(const float4*)(vb + go);
        }
        __syncthreads();
        for (int p = 0; p < nph; ++p) {
            if (p + 1 < nph) {
                float* dstp = lds[(p + 1) & 1] + s_ * 384 + l16;
                const size_t go = base + (size_t)((p + 1) * WCHUNK + s_) * Cc + l16;
                *(float4*)(dstp + 0 * 64) = *(const float4*)(aab + go);
                *(float4*)(dstp + 1 * 64) = *(const float4*)(wdb + go);
                *(float4*)(dstp + 2 * 64) = *(const float4*)(bbb + go);
                *(float4*)(dstp + 3 * 64) = *(const float4*)(kb + go);
                *(float4*)(dstp + 4 * 64) = *(const float4*)(rb + go);
                *(float4*)(dstp + 5 * 64) = *(const float4*)(vb + go);
            }
            __syncthreads();
        }
    } else {
        // ---- consumer role: 256 threads, i = row, jc = 16-col chunk ----
        const int i = tid >> 2, jc = tid & 3, j0 = jc << 4;
        float S[16];
#pragma unroll
        for (int u = 0; u < 16; ++u) S[u] = 0.f;

        __syncthreads();
        for (int p = 0; p < nph; ++p) {
            const float* bufp = lds[p & 1];
            const int t0 = p * WCHUNK;
#pragma unroll 4
            for (int s = 0; s < WCHUNK; ++s) {
                const float* sp = bufp + s * 384;
                float sa = 0.f;
#pragma unroll
                for (int q = 0; q < 4; ++q) {
                    float4 aq = *(const float4*)(sp + 0 * 64 + j0 + q * 4);
                    sa += S[q*4+0] * aq.x + S[q*4+1] * aq.y + S[q*4+2] * aq.z + S[q*4+3] * aq.w;
                }
                sa += __shfl_xor(sa, 1);
                sa += __shfl_xor(sa, 2);
                float vi = sp[5 * 64 + i];
                float yp = 0.f;
#pragma unroll
                for (int q = 0; q < 4; ++q) {
                    float4 wq = *(const float4*)(sp + 1 * 64 + j0 + q * 4);
                    float4 bq = *(const float4*)(sp + 2 * 64 + j0 + q * 4);
                    float4 kq = *(const float4*)(sp + 3 * 64 + j0 + q * 4);
                    float4 rq = *(const float4*)(sp + 4 * 64 + j0 + q * 4);
                    S[q*4+0] = fmaf(S[q*4+0], wq.x, fmaf(vi, kq.x, sa * bq.x)); yp += S[q*4+0] * rq.x;
                    S[q*4+1] = fmaf(S[q*4+1], wq.y, fmaf(vi, kq.y, sa * bq.y)); yp += S[q*4+1] * rq.y;
                    S[q*4+2] = fmaf(S[q*4+2], wq.z, fmaf(vi, kq.z, sa * bq.z)); yp += S[q*4+2] * rq.z;
                    S[q*4+3] = fmaf(S[q*4+3], wq.w, fmaf(vi, kq.w, sa * bq.w)); yp += S[q*4+3] * rq.w;
                }
                yp += __shfl_xor(yp, 1);
                yp += __shfl_xor(yp, 2);
                if (jc == 0) yb[base + (size_t)(t0 + s) * Cc + i] = yp;
            }
            __syncthreads();
        }
    }
}

// ---------------------------------------------------------------------------
// GroupNorm + r*k*r_k bonus + gate; writes z as bf16 for the Wo MFMA GEMM
// ---------------------------------------------------------------------------
__global__ __launch_bounds__(256) void gn_rt_kernel(
    const float* __restrict__ yb, const float* __restrict__ rb,
    const float* __restrict__ kb, const float* __restrict__ vb,
    const float* __restrict__ gb, const float* __restrict__ r_k,
    const float* __restrict__ ln_w, const float* __restrict__ ln_b,
    unsigned short* __restrict__ zb)
{
    const int row = blockIdx.x;
    const int tid = threadIdx.x;
    const int c0 = tid * 4;
    const int hd = tid >> 4;
    const int n0 = c0 & 63;
    const size_t o = (size_t)row * Cc;

    float4 y4 = *(const float4*)(yb + o + c0);
    float4 r4 = *(const float4*)(rb + o + c0);
    float4 k4 = *(const float4*)(kb + o + c0);
    float4 v4 = *(const float4*)(vb + o + c0);
    float4 g4 = *(const float4*)(gb + o + c0);
    float4 rk4 = *(const float4*)(r_k + hd * 64 + n0);

    float yv[4] = { y4.x, y4.y, y4.z, y4.w };
    float rv[4] = { r4.x, r4.y, r4.z, r4.w };
    float kv[4] = { k4.x, k4.y, k4.z, k4.w };
    float vv[4] = { v4.x, v4.y, v4.z, v4.w };
    float gv[4] = { g4.x, g4.y, g4.z, g4.w };
    float rkv[4] = { rk4.x, rk4.y, rk4.z, rk4.w };

    float sum = 0.f, ssq = 0.f, dot = 0.f;
#pragma unroll
    for (int j = 0; j < 4; ++j) {
        sum += yv[j];
        ssq += yv[j] * yv[j];
        dot += rv[j] * kv[j] * rkv[j];
    }
#pragma unroll
    for (int m = 1; m <= 8; m <<= 1) {
        sum += __shfl_xor(sum, m);
        ssq += __shfl_xor(ssq, m);
        dot += __shfl_xor(dot, m);
    }
    const float mu = sum * (1.f / 64.f);
    const float var = ssq * (1.f / 64.f) - mu * mu;
    const float inv = rsqrtf(var + 0.00064f);

    ushort4 z4;
    unsigned short* zp = (unsigned short*)&z4;
#pragma unroll
    for (int j = 0; j < 4; ++j) {
        int c = c0 + j;
        float yg = (yv[j] - mu) * inv * ln_w[c] + ln_b[c];
        yg += dot * vv[j];
        zp[j] = f2bf(yg * gv[j]);
    }
    *(ushort4*)(zb + o + c0) = z4;
}

// ---------------------------------------------------------------------------

extern "C" void kernel_launch(void* const* d_in, const int* in_sizes, int n_in,
                              void* d_out, int out_size, void* d_ws, size_t ws_size,
                              hipStream_t stream)
{
    const float* x   = (const float*)d_in[0];
    const float* x_r = (const float*)d_in[1];
    const float* x_w = (const float*)d_in[2];
    const float* x_k = (const float*)d_in[3];
    const float* x_v = (const float*)d_in[4];
    const float* x_a = (const float*)d_in[5];
    const float* x_g = (const float*)d_in[6];
    const float* w0  = (const float*)d_in[7];
    const float* w1  = (const float*)d_in[8];
    const float* w2  = (const float*)d_in[9];
    const float* a0  = (const float*)d_in[10];
    const float* a1  = (const float*)d_in[11];
    const float* a2  = (const float*)d_in[12];
    // v0,v1,v2 (13..15): forward no-op on first-layer call
    const float* g1  = (const float*)d_in[16];
    const float* g2  = (const float*)d_in[17];
    const float* k_k = (const float*)d_in[18];
    const float* k_a = (const float*)d_in[19];
    const float* r_k = (const float*)d_in[20];
    const float* Wr  = (const float*)d_in[21];
    const float* Wk  = (const float*)d_in[22];
    const float* Wv  = (const float*)d_in[23];
    const float* Wo  = (const float*)d_in[24];
    const float* ln_w = (const float*)d_in[25];
    const float* ln_b = (const float*)d_in[26];

    float* ws = (float*)d_ws;
    const size_t S = (size_t)Bsz * Tt * Cc;       // 4,194,304 floats
    const int M = Bsz * Tt;                        // 4096

    float* rb  = ws + 0 * S;
    float* wdb = ws + 1 * S;
    unsigned short* WoT = (unsigned short*)(ws + 1 * S);   // after wkv
    float* kb  = ws + 2 * S;
    float* vb  = ws + 3 * S;
    float* aab = ws + 4 * S;
    unsigned short* zb = (unsigned short*)(ws + 4 * S);    // after wkv
    float* bbb = ws + 5 * S;
    float* yb  = ws + 6 * S;
    float* hw  = yb;                    // 4096*64   (dead before wkv writes yb)
    float* ha  = yb + 262144;           // 4096*64
    float* hg  = yb + 524288;           // 4096*128
    unsigned short* xr = (unsigned short*)(ws + 7 * S);    // 8 MB
    unsigned short* xk = xr + S;                           // 8 MB
    float* ab  = ws + 7 * S;            // after xr/xk consumed
    unsigned short* xv = (unsigned short*)(ws + 8 * S);    // 8 MB
    unsigned short* WrT = xv + S;                          // 2 MB
    unsigned short* WkT = WrT + 1048576;
    unsigned short* WvT = WkT + 1048576;
    float* gb  = ws + 8 * S;            // after xv/W*T consumed

    dim3 blk(256);

    // mixed bf16 inputs + transposed bf16 weights
    mixcast_kernel<<<dim3(M), blk, 0, stream>>>(x, x_r, x_k, x_v, xr, xk, xv);
    transpose_cast<<<dim3(16, 16), blk, 0, stream>>>(Wr, WrT);
    transpose_cast<<<dim3(16, 16), blk, 0, stream>>>(Wk, WkT);
    transpose_cast<<<dim3(16, 16), blk, 0, stream>>>(Wv, WvT);

    // low-rank hidden projections (fp32, token-shift fused)
    gemm_f32<<<dim3(1, M / 64), blk, 0, stream>>>(x, w1, hw, x_w, nullptr, M, 64, Cc, 1);   // tanh
    gemm_f32<<<dim3(1, M / 64), blk, 0, stream>>>(x, a1, ha, x_a, nullptr, M, 64, Cc, 0);
    gemm_f32<<<dim3(2, M / 64), blk, 0, stream>>>(x, g1, hg, x_g, nullptr, M, 128, Cc, 2);  // sigmoid

    // big projections: bf16 MFMA
    gemm_bf16<<<dim3(8, 32), blk, 0, stream>>>(xr, WrT, rb, M, Cc, Cc);
    gemm_bf16<<<dim3(8, 32), blk, 0, stream>>>(xk, WkT, kb, M, Cc, Cc);
    gemm_bf16<<<dim3(8, 32), blk, 0, stream>>>(xv, WvT, vb, M, Cc, Cc);

    // second-stage low-rank (fp32) — xr/xk/xv and W*T are dead now
    gemm_f32<<<dim3(16, M / 64), blk, 0, stream>>>(hw, w2, wdb, nullptr, w0, M, Cc, 64, 3); // decay
    gemm_f32<<<dim3(16, M / 64), blk, 0, stream>>>(ha, a2, ab, nullptr, a0, M, Cc, 64, 2);  // sigmoid
    gemm_f32<<<dim3(16, M / 64), blk, 0, stream>>>(hg, g2, gb, nullptr, nullptr, M, Cc, 128, 0);

    // k / kk / aa / bb
    prep_k_kernel<<<dim3(M), blk, 0, stream>>>(kb, ab, k_k, k_a, kb, aab, bbb);

    // sequential recurrence (producer/consumer LDS pipeline, 512 threads)
    wkv_kernel<<<dim3(Bsz * Hh), dim3(512), 0, stream>>>(rb, wdb, kb, vb, aab, bbb, yb);

    // Wo transpose (into dead wdb slot), groupnorm+bonus+gate -> z (bf16)
    transpose_cast<<<dim3(16, 16), blk, 0, stream>>>(Wo, WoT);
    gn_rt_kernel<<<dim3(M), blk, 0, stream>>>(yb, rb, kb, vb, gb, r_k, ln_w, ln_b, zb);

    // output projection: bf16 MFMA
    gemm_bf16<<<dim3(8, 32), blk, 0, stream>>>(zb, WoT, (float*)d_out, M, Cc, Cc);
}

// Round 5
// 884.779 us; speedup vs baseline: 2.9374x; 1.1711x over previous
//
#include <hip/hip_runtime.h>
#include <math.h>

#define Bsz 4
#define Tt  1024
#define Cc  1024
#define Hh  16
#define HSs 64
#define WCHUNK 16

typedef __attribute__((ext_vector_type(8))) short bf16x8;
typedef __attribute__((ext_vector_type(4))) float f32x4;

__device__ __forceinline__ float sigf(float x) { return 1.f / (1.f + expf(-x)); }

__device__ __forceinline__ unsigned short f2bf(float f) {
    unsigned int u = __float_as_uint(f);
    u = u + 0x7fffu + ((u >> 16) & 1u);   // RNE
    return (unsigned short)(u >> 16);
}

// ---------------------------------------------------------------------------
// fp32 tiled GEMM (second-stage low-rank paths): out[M,N] = f( A@W + bias )
// epi: 0=none 1=tanh 2=sigmoid 3=decay
// ---------------------------------------------------------------------------
__global__ __launch_bounds__(256) void gemm_f32(
    const float* __restrict__ A, const float* __restrict__ W,
    float* __restrict__ out, const float* __restrict__ mix,
    const float* __restrict__ bias, int M, int N, int K, int epi)
{
    __shared__ float As[16][65];
    __shared__ float Bs[16][65];
    const int row0 = blockIdx.y * 64;
    const int col0 = blockIdx.x * 64;
    const int tid = threadIdx.x;
    const int tr = tid >> 4, tc = tid & 15;

    float acc[4][4];
#pragma unroll
    for (int i = 0; i < 4; ++i)
#pragma unroll
        for (int j = 0; j < 4; ++j) acc[i][j] = 0.f;

    for (int k0 = 0; k0 < K; k0 += 16) {
#pragma unroll
        for (int s = 0; s < 4; ++s) {
            int i = tid + s * 256;
            int rr = i >> 4, kk = i & 15;
            int r = row0 + rr;
            int c = k0 + kk;
            float xv = A[r * K + c];
            float val;
            if (mix) {
                int t = r & (Tt - 1);
                float xp = (t > 0) ? A[(r - 1) * K + c] : 0.f;
                val = xv + (xp - xv) * mix[c];
            } else val = xv;
            As[kk][rr] = val;
        }
#pragma unroll
        for (int s = 0; s < 4; ++s) {
            int i = tid + s * 256;
            int kk = i >> 6, cc = i & 63;
            Bs[kk][cc] = W[(k0 + kk) * N + col0 + cc];
        }
        __syncthreads();
#pragma unroll
        for (int kk = 0; kk < 16; ++kk) {
            float a[4], b[4];
#pragma unroll
            for (int u = 0; u < 4; ++u) a[u] = As[kk][tr * 4 + u];
#pragma unroll
            for (int u = 0; u < 4; ++u) b[u] = Bs[kk][tc * 4 + u];
#pragma unroll
            for (int i = 0; i < 4; ++i)
#pragma unroll
                for (int j = 0; j < 4; ++j) acc[i][j] += a[i] * b[j];
        }
        __syncthreads();
    }

#pragma unroll
    for (int i = 0; i < 4; ++i) {
        int r = row0 + tr * 4 + i;
#pragma unroll
        for (int j = 0; j < 4; ++j) {
            int c = col0 + tc * 4 + j;
            float v = acc[i][j];
            if (bias) v += bias[c];
            if (epi == 1) v = tanhf(v);
            else if (epi == 2) v = sigf(v);
            else if (epi == 3) v = expf(-0.60653065971263342f * sigf(v));
            out[(size_t)r * N + c] = v;
        }
    }
}

// ---------------------------------------------------------------------------
// Fused first-stage low-rank: hw=tanh(xw@w1) [N=64], ha=xa@a1 [N=64],
// hg=sig(xg@g1) [N=128]. blockIdx.x = segment 0..3, blockIdx.y = 64-row block.
// Token-shift mix fused into A load. One launch, 256 blocks.
// ---------------------------------------------------------------------------
__global__ __launch_bounds__(256) void lowrank_fused(
    const float* __restrict__ x,
    const float* __restrict__ x_w, const float* __restrict__ x_a,
    const float* __restrict__ x_g,
    const float* __restrict__ w1, const float* __restrict__ a1,
    const float* __restrict__ g1,
    float* __restrict__ hw, float* __restrict__ ha, float* __restrict__ hg)
{
    const int seg = blockIdx.x;
    const float* mix; const float* W; float* out; int N, col0, epi;
    if (seg == 0)      { mix = x_w; W = w1; out = hw; N = 64;  col0 = 0;  epi = 1; }
    else if (seg == 1) { mix = x_a; W = a1; out = ha; N = 64;  col0 = 0;  epi = 0; }
    else               { mix = x_g; W = g1; out = hg; N = 128; col0 = (seg - 2) * 64; epi = 2; }

    __shared__ float As[16][65];
    __shared__ float Bs[16][65];
    const int row0 = blockIdx.y * 64;
    const int tid = threadIdx.x;
    const int tr = tid >> 4, tc = tid & 15;

    float acc[4][4];
#pragma unroll
    for (int i = 0; i < 4; ++i)
#pragma unroll
        for (int j = 0; j < 4; ++j) acc[i][j] = 0.f;

    for (int k0 = 0; k0 < Cc; k0 += 16) {
#pragma unroll
        for (int s = 0; s < 4; ++s) {
            int i = tid + s * 256;
            int rr = i >> 4, kk = i & 15;
            int r = row0 + rr;
            int c = k0 + kk;
            float xv = x[r * Cc + c];
            float xp = (r & (Tt - 1)) ? x[(r - 1) * Cc + c] : 0.f;
            As[kk][rr] = xv + (xp - xv) * mix[c];
        }
#pragma unroll
        for (int s = 0; s < 4; ++s) {
            int i = tid + s * 256;
            int kk = i >> 6, cc = i & 63;
            Bs[kk][cc] = W[(k0 + kk) * N + col0 + cc];
        }
        __syncthreads();
#pragma unroll
        for (int kk = 0; kk < 16; ++kk) {
            float a[4], b[4];
#pragma unroll
            for (int u = 0; u < 4; ++u) a[u] = As[kk][tr * 4 + u];
#pragma unroll
            for (int u = 0; u < 4; ++u) b[u] = Bs[kk][tc * 4 + u];
#pragma unroll
            for (int i = 0; i < 4; ++i)
#pragma unroll
                for (int j = 0; j < 4; ++j) acc[i][j] += a[i] * b[j];
        }
        __syncthreads();
    }

#pragma unroll
    for (int i = 0; i < 4; ++i) {
        int r = row0 + tr * 4 + i;
#pragma unroll
        for (int j = 0; j < 4; ++j) {
            int c = col0 + tc * 4 + j;
            float v = acc[i][j];
            if (epi == 1) v = tanhf(v);
            else if (epi == 2) v = sigf(v);
            out[(size_t)r * N + c] = v;
        }
    }
}

// ---------------------------------------------------------------------------
// mixcast: xr/xk/xv = bf16( x + (shift(x)-x)*mix )   one block per token row
// ---------------------------------------------------------------------------
__global__ __launch_bounds__(256) void mixcast_kernel(
    const float* __restrict__ x, const float* __restrict__ x_r,
    const float* __restrict__ x_k, const float* __restrict__ x_v,
    unsigned short* __restrict__ xr, unsigned short* __restrict__ xk,
    unsigned short* __restrict__ xv)
{
    const int row = blockIdx.x;
    const int c0 = threadIdx.x * 4;
    const size_t o = (size_t)row * Cc;
    float4 xc = *(const float4*)(x + o + c0);
    float4 xp;
    if (row & (Tt - 1)) xp = *(const float4*)(x + o - Cc + c0);
    else { xp.x = xp.y = xp.z = xp.w = 0.f; }
    float4 mr = *(const float4*)(x_r + c0);
    float4 mk = *(const float4*)(x_k + c0);
    float4 mv = *(const float4*)(x_v + c0);
    const float* xcf = (const float*)&xc; const float* xpf = (const float*)&xp;
    const float* mrf = (const float*)&mr; const float* mkf = (const float*)&mk;
    const float* mvf = (const float*)&mv;
    ushort4 r4, k4, v4;
    unsigned short* rp = (unsigned short*)&r4;
    unsigned short* kp = (unsigned short*)&k4;
    unsigned short* vp = (unsigned short*)&v4;
#pragma unroll
    for (int j = 0; j < 4; ++j) {
        float xx = xpf[j] - xcf[j];
        rp[j] = f2bf(xcf[j] + xx * mrf[j]);
        kp[j] = f2bf(xcf[j] + xx * mkf[j]);
        vp[j] = f2bf(xcf[j] + xx * mvf[j]);
    }
    *(ushort4*)(xr + o + c0) = r4;
    *(ushort4*)(xk + o + c0) = k4;
    *(ushort4*)(xv + o + c0) = v4;
}

// ---------------------------------------------------------------------------
// transpose+cast: WT[n][k] = bf16(W[k][n]),  W is 1024x1024 fp32
// ---------------------------------------------------------------------------
__global__ __launch_bounds__(256) void transpose_cast(
    const float* __restrict__ W, unsigned short* __restrict__ WT)
{
    __shared__ unsigned short tile[64][68];
    const int n0 = blockIdx.x * 64, k0 = blockIdx.y * 64;
    const int tid = threadIdx.x;
    const int tr = tid >> 4, tc4 = (tid & 15) * 4;
#pragma unroll
    for (int s = 0; s < 4; ++s) {
        int kk = tr + s * 16;
        float4 w4 = *(const float4*)(W + (size_t)(k0 + kk) * Cc + n0 + tc4);
        tile[kk][tc4 + 0] = f2bf(w4.x);
        tile[kk][tc4 + 1] = f2bf(w4.y);
        tile[kk][tc4 + 2] = f2bf(w4.z);
        tile[kk][tc4 + 3] = f2bf(w4.w);
    }
    __syncthreads();
#pragma unroll
    for (int s = 0; s < 4; ++s) {
        int nn = tr + s * 16;
        ushort4 o4;
        o4.x = tile[tc4 + 0][nn];
        o4.y = tile[tc4 + 1][nn];
        o4.z = tile[tc4 + 2][nn];
        o4.w = tile[tc4 + 3][nn];
        *(ushort4*)(WT + (size_t)(n0 + nn) * Cc + k0 + tc4) = o4;
    }
}

// ---------------------------------------------------------------------------
// bf16 MFMA GEMM: out[M,N] (fp32) = A[M,K](bf16) @ W[K,N], W given as WT[N][K] bf16
// 128x128 tile, BK=32, 4 waves (2x2), 16x16x32 MFMA, padded LDS (stride 40)
// ---------------------------------------------------------------------------
__global__ __launch_bounds__(256) void gemm_bf16(
    const unsigned short* __restrict__ A, const unsigned short* __restrict__ WT,
    float* __restrict__ out, int M, int N, int K)
{
    __shared__ __attribute__((aligned(16))) unsigned short As[128][40];
    __shared__ __attribute__((aligned(16))) unsigned short Bs[128][40];
    const int row0 = blockIdx.y * 128;
    const int col0 = blockIdx.x * 128;
    const int tid = threadIdx.x;
    const int wave = tid >> 6, lane = tid & 63;
    const int wr = wave >> 1, wc = wave & 1;
    const int lr = lane & 15, lk = lane >> 4;

    f32x4 acc[4][4];
#pragma unroll
    for (int m = 0; m < 4; ++m)
#pragma unroll
        for (int n = 0; n < 4; ++n)
#pragma unroll
            for (int r = 0; r < 4; ++r) acc[m][n][r] = 0.f;

    const int sr = tid >> 2;           // 0..63
    const int sc = (tid & 3) * 8;      // 0,8,16,24 (ushort offset; 16B chunks)

    for (int k0 = 0; k0 < K; k0 += 32) {
        uint4 a0v = *(const uint4*)(A  + (size_t)(row0 + sr) * K + k0 + sc);
        uint4 a1v = *(const uint4*)(A  + (size_t)(row0 + 64 + sr) * K + k0 + sc);
        uint4 b0v = *(const uint4*)(WT + (size_t)(col0 + sr) * K + k0 + sc);
        uint4 b1v = *(const uint4*)(WT + (size_t)(col0 + 64 + sr) * K + k0 + sc);
        *(uint4*)&As[sr][sc]      = a0v;
        *(uint4*)&As[64 + sr][sc] = a1v;
        *(uint4*)&Bs[sr][sc]      = b0v;
        *(uint4*)&Bs[64 + sr][sc] = b1v;
        __syncthreads();
        bf16x8 af[4], bff[4];
#pragma unroll
        for (int m = 0; m < 4; ++m)
            af[m] = *(const bf16x8*)&As[wr * 64 + m * 16 + lr][lk * 8];
#pragma unroll
        for (int n = 0; n < 4; ++n)
            bff[n] = *(const bf16x8*)&Bs[wc * 64 + n * 16 + lr][lk * 8];
#pragma unroll
        for (int m = 0; m < 4; ++m)
#pragma unroll
            for (int n = 0; n < 4; ++n)
                acc[m][n] = __builtin_amdgcn_mfma_f32_16x16x32_bf16(af[m], bff[n], acc[m][n], 0, 0, 0);
        __syncthreads();
    }

#pragma unroll
    for (int m = 0; m < 4; ++m)
#pragma unroll
        for (int n = 0; n < 4; ++n) {
            int col = col0 + wc * 64 + n * 16 + lr;
#pragma unroll
            for (int r = 0; r < 4; ++r) {
                int row = row0 + wr * 64 + m * 16 + lk * 4 + r;
                out[(size_t)row * N + col] = acc[m][n][r];
            }
        }
}

// ---------------------------------------------------------------------------
// prep_k: kk = normalize_perhead(kraw*k_k); aa=-kk; bb=kk*a; k=kraw*(1+(a-1)*k_a)
// ---------------------------------------------------------------------------
__global__ __launch_bounds__(256) void prep_k_kernel(
    const float* kraw, const float* __restrict__ a,
    const float* __restrict__ k_k, const float* __restrict__ k_a,
    float* kout, float* __restrict__ aaout, float* __restrict__ bbout)
{
    const int row = blockIdx.x;
    const int tid = threadIdx.x;
    const int c0 = tid * 4;
    const size_t o = (size_t)row * Cc;

    float4 kr = *(const float4*)(kraw + o + c0);
    float4 kkw = *(const float4*)(k_k + c0);
    float4 av = *(const float4*)(a + o + c0);
    float4 kaw = *(const float4*)(k_a + c0);

    float kk[4] = { kr.x * kkw.x, kr.y * kkw.y, kr.z * kkw.z, kr.w * kkw.w };
    float ssq = kk[0]*kk[0] + kk[1]*kk[1] + kk[2]*kk[2] + kk[3]*kk[3];
    ssq += __shfl_xor(ssq, 1);
    ssq += __shfl_xor(ssq, 2);
    ssq += __shfl_xor(ssq, 4);
    ssq += __shfl_xor(ssq, 8);
    float inv = 1.f / fmaxf(sqrtf(ssq), 1e-12f);

    float krr[4] = { kr.x, kr.y, kr.z, kr.w };
    float av4[4] = { av.x, av.y, av.z, av.w };
    float ka4[4] = { kaw.x, kaw.y, kaw.z, kaw.w };
    float4 aa4, bb4, kf4;
    float* aap = (float*)&aa4; float* bbp = (float*)&bb4; float* kfp = (float*)&kf4;
#pragma unroll
    for (int j = 0; j < 4; ++j) {
        float kkn = kk[j] * inv;
        aap[j] = -kkn;
        bbp[j] = kkn * av4[j];
        kfp[j] = krr[j] * (1.f + (av4[j] - 1.f) * ka4[j]);
    }
    *(float4*)(aaout + o + c0) = aa4;
    *(float4*)(bbout + o + c0) = bb4;
    *(float4*)(kout + o + c0) = kf4;
}

// ---------------------------------------------------------------------------
// WKV recurrence, producer/consumer LDS pipeline.
// One block of 512 threads per (b,h).
// Consumers (tid<256): thread = (row-group rg: 4 rows) x (col-group cg: 4 cols),
//   S[4][4] in registers. 6 float4 LDS reads per step (a,w,b,k,r slice + v rows).
//   Reduce over the 16 cg lanes via shfl_xor 1/2/4/8.
// Producers (tid>=256): stage WCHUNK steps of {a,w,b,k,r,v} into LDS ring.
// LDS layout per step s: [s*384 + arr*64 + j], arr: 0=a 1=w 2=b 3=k 4=r 5=v.
// ---------------------------------------------------------------------------
__global__ __launch_bounds__(512, 1) void wkv_kernel(
    const float* __restrict__ rb, const float* __restrict__ wdb,
    const float* __restrict__ kb, const float* __restrict__ vb,
    const float* __restrict__ aab, const float* __restrict__ bbb,
    float* __restrict__ yb)
{
    __shared__ float lds[2][WCHUNK * 6 * 64];
    const int bh = blockIdx.x;
    const int b = bh >> 4, h = bh & 15;
    const int tid = threadIdx.x;
    const size_t base = (size_t)b * Tt * Cc + h * HSs;
    const int nph = Tt / WCHUNK;   // 64

    if (tid >= 256) {
        // ---- producer role: 256 threads, 1 float4 per array per phase ----
        const int st = tid - 256;
        const int s_ = st >> 4;           // step within chunk 0..15
        const int l16 = (st & 15) * 4;    // float offset within 64-col slice
        {
            float* dstp = lds[0] + s_ * 384 + l16;
            const size_t go = base + (size_t)s_ * Cc + l16;
            *(float4*)(dstp + 0 * 64) = *(const float4*)(aab + go);
            *(float4*)(dstp + 1 * 64) = *(const float4*)(wdb + go);
            *(float4*)(dstp + 2 * 64) = *(const float4*)(bbb + go);
            *(float4*)(dstp + 3 * 64) = *(const float4*)(kb + go);
            *(float4*)(dstp + 4 * 64) = *(const float4*)(rb + go);
            *(float4*)(dstp + 5 * 64) = *(const float4*)(vb + go);
        }
        __syncthreads();
        for (int p = 0; p < nph; ++p) {
            if (p + 1 < nph) {
                float* dstp = lds[(p + 1) & 1] + s_ * 384 + l16;
                const size_t go = base + (size_t)((p + 1) * WCHUNK + s_) * Cc + l16;
                *(float4*)(dstp + 0 * 64) = *(const float4*)(aab + go);
                *(float4*)(dstp + 1 * 64) = *(const float4*)(wdb + go);
                *(float4*)(dstp + 2 * 64) = *(const float4*)(bbb + go);
                *(float4*)(dstp + 3 * 64) = *(const float4*)(kb + go);
                *(float4*)(dstp + 4 * 64) = *(const float4*)(rb + go);
                *(float4*)(dstp + 5 * 64) = *(const float4*)(vb + go);
            }
            __syncthreads();
        }
    } else {
        // ---- consumer role ----
        const int rg = tid >> 4;     // 0..15 -> rows rg*4..rg*4+3
        const int cg = tid & 15;     // 0..15 -> cols cg*4..cg*4+3
        float S[4][4];
#pragma unroll
        for (int ri = 0; ri < 4; ++ri)
#pragma unroll
            for (int cj = 0; cj < 4; ++cj) S[ri][cj] = 0.f;

        __syncthreads();
        for (int p = 0; p < nph; ++p) {
            const float* bufp = lds[p & 1];
            const int t0 = p * WCHUNK;
#pragma unroll 4
            for (int s = 0; s < WCHUNK; ++s) {
                const float* sp = bufp + s * 384;
                float4 a4 = *(const float4*)(sp + 0 * 64 + cg * 4);
                float4 v4 = *(const float4*)(sp + 5 * 64 + rg * 4);
                const float* a4p = (const float*)&a4;
                const float* v4p = (const float*)&v4;

                float sa[4];
#pragma unroll
                for (int ri = 0; ri < 4; ++ri) {
                    sa[ri] = S[ri][0] * a4p[0];
#pragma unroll
                    for (int cj = 1; cj < 4; ++cj) sa[ri] = fmaf(S[ri][cj], a4p[cj], sa[ri]);
                }
#pragma unroll
                for (int m = 1; m <= 8; m <<= 1) {
#pragma unroll
                    for (int ri = 0; ri < 4; ++ri) sa[ri] += __shfl_xor(sa[ri], m);
                }

                float4 w4 = *(const float4*)(sp + 1 * 64 + cg * 4);
                float4 b4 = *(const float4*)(sp + 2 * 64 + cg * 4);
                float4 k4 = *(const float4*)(sp + 3 * 64 + cg * 4);
                float4 r4 = *(const float4*)(sp + 4 * 64 + cg * 4);
                const float* w4p = (const float*)&w4;
                const float* b4p = (const float*)&b4;
                const float* k4p = (const float*)&k4;
                const float* r4p = (const float*)&r4;

                float y[4];
#pragma unroll
                for (int ri = 0; ri < 4; ++ri) {
                    float yv = 0.f;
#pragma unroll
                    for (int cj = 0; cj < 4; ++cj) {
                        float tmp = fmaf(v4p[ri], k4p[cj], sa[ri] * b4p[cj]);
                        S[ri][cj] = fmaf(S[ri][cj], w4p[cj], tmp);
                        yv = fmaf(S[ri][cj], r4p[cj], yv);
                    }
                    y[ri] = yv;
                }
#pragma unroll
                for (int m = 1; m <= 8; m <<= 1) {
#pragma unroll
                    for (int ri = 0; ri < 4; ++ri) y[ri] += __shfl_xor(y[ri], m);
                }
                if (cg == 0) {
                    float4 yo;
                    float* yop = (float*)&yo;
#pragma unroll
                    for (int ri = 0; ri < 4; ++ri) yop[ri] = y[ri];
                    *(float4*)(yb + base + (size_t)(t0 + s) * Cc + rg * 4) = yo;
                }
            }
            __syncthreads();
        }
    }
}

// ---------------------------------------------------------------------------
// GroupNorm + r*k*r_k bonus + gate; writes z as bf16 for the Wo MFMA GEMM
// ---------------------------------------------------------------------------
__global__ __launch_bounds__(256) void gn_rt_kernel(
    const float* __restrict__ yb, const float* __restrict__ rb,
    const float* __restrict__ kb, const float* __restrict__ vb,
    const float* __restrict__ gb, const float* __restrict__ r_k,
    const float* __restrict__ ln_w, const float* __restrict__ ln_b,
    unsigned short* __restrict__ zb)
{
    const int row = blockIdx.x;
    const int tid = threadIdx.x;
    const int c0 = tid * 4;
    const int hd = tid >> 4;
    const int n0 = c0 & 63;
    const size_t o = (size_t)row * Cc;

    float4 y4 = *(const float4*)(yb + o + c0);
    float4 r4 = *(const float4*)(rb + o + c0);
    float4 k4 = *(const float4*)(kb + o + c0);
    float4 v4 = *(const float4*)(vb + o + c0);
    float4 g4 = *(const float4*)(gb + o + c0);
    float4 rk4 = *(const float4*)(r_k + hd * 64 + n0);

    float yv[4] = { y4.x, y4.y, y4.z, y4.w };
    float rv[4] = { r4.x, r4.y, r4.z, r4.w };
    float kv[4] = { k4.x, k4.y, k4.z, k4.w };
    float vv[4] = { v4.x, v4.y, v4.z, v4.w };
    float gv[4] = { g4.x, g4.y, g4.z, g4.w };
    float rkv[4] = { rk4.x, rk4.y, rk4.z, rk4.w };

    float sum = 0.f, ssq = 0.f, dot = 0.f;
#pragma unroll
    for (int j = 0; j < 4; ++j) {
        sum += yv[j];
        ssq += yv[j] * yv[j];
        dot += rv[j] * kv[j] * rkv[j];
    }
#pragma unroll
    for (int m = 1; m <= 8; m <<= 1) {
        sum += __shfl_xor(sum, m);
        ssq += __shfl_xor(ssq, m);
        dot += __shfl_xor(dot, m);
    }
    const float mu = sum * (1.f / 64.f);
    const float var = ssq * (1.f / 64.f) - mu * mu;
    const float inv = rsqrtf(var + 0.00064f);

    ushort4 z4;
    unsigned short* zp = (unsigned short*)&z4;
#pragma unroll
    for (int j = 0; j < 4; ++j) {
        int c = c0 + j;
        float yg = (yv[j] - mu) * inv * ln_w[c] + ln_b[c];
        yg += dot * vv[j];
        zp[j] = f2bf(yg * gv[j]);
    }
    *(ushort4*)(zb + o + c0) = z4;
}

// ---------------------------------------------------------------------------

extern "C" void kernel_launch(void* const* d_in, const int* in_sizes, int n_in,
                              void* d_out, int out_size, void* d_ws, size_t ws_size,
                              hipStream_t stream)
{
    const float* x   = (const float*)d_in[0];
    const float* x_r = (const float*)d_in[1];
    const float* x_w = (const float*)d_in[2];
    const float* x_k = (const float*)d_in[3];
    const float* x_v = (const float*)d_in[4];
    const float* x_a = (const float*)d_in[5];
    const float* x_g = (const float*)d_in[6];
    const float* w0  = (const float*)d_in[7];
    const float* w1  = (const float*)d_in[8];
    const float* w2  = (const float*)d_in[9];
    const float* a0  = (const float*)d_in[10];
    const float* a1  = (const float*)d_in[11];
    const float* a2  = (const float*)d_in[12];
    // v0,v1,v2 (13..15): forward no-op on first-layer call
    const float* g1  = (const float*)d_in[16];
    const float* g2  = (const float*)d_in[17];
    const float* k_k = (const float*)d_in[18];
    const float* k_a = (const float*)d_in[19];
    const float* r_k = (const float*)d_in[20];
    const float* Wr  = (const float*)d_in[21];
    const float* Wk  = (const float*)d_in[22];
    const float* Wv  = (const float*)d_in[23];
    const float* Wo  = (const float*)d_in[24];
    const float* ln_w = (const float*)d_in[25];
    const float* ln_b = (const float*)d_in[26];

    float* ws = (float*)d_ws;
    const size_t S = (size_t)Bsz * Tt * Cc;       // 4,194,304 floats
    const int M = Bsz * Tt;                        // 4096

    float* rb  = ws + 0 * S;
    float* wdb = ws + 1 * S;
    unsigned short* WoT = (unsigned short*)(ws + 1 * S);   // after wkv
    float* kb  = ws + 2 * S;
    float* vb  = ws + 3 * S;
    float* aab = ws + 4 * S;
    unsigned short* zb = (unsigned short*)(ws + 4 * S);    // after wkv
    float* bbb = ws + 5 * S;
    float* yb  = ws + 6 * S;
    float* hw  = yb;                    // 4096*64   (dead before wkv writes yb)
    float* ha  = yb + 262144;           // 4096*64
    float* hg  = yb + 524288;           // 4096*128
    unsigned short* xr = (unsigned short*)(ws + 7 * S);    // 8 MB
    unsigned short* xk = xr + S;                           // 8 MB
    float* ab  = ws + 7 * S;            // after xr/xk consumed
    unsigned short* xv = (unsigned short*)(ws + 8 * S);    // 8 MB
    unsigned short* WrT = xv + S;                          // 2 MB
    unsigned short* WkT = WrT + 1048576;
    unsigned short* WvT = WkT + 1048576;
    float* gb  = ws + 8 * S;            // after xv/W*T consumed

    dim3 blk(256);

    // mixed bf16 inputs + transposed bf16 weights
    mixcast_kernel<<<dim3(M), blk, 0, stream>>>(x, x_r, x_k, x_v, xr, xk, xv);
    transpose_cast<<<dim3(16, 16), blk, 0, stream>>>(Wr, WrT);
    transpose_cast<<<dim3(16, 16), blk, 0, stream>>>(Wk, WkT);
    transpose_cast<<<dim3(16, 16), blk, 0, stream>>>(Wv, WvT);

    // fused first-stage low-rank (hw=tanh, ha, hg=sigmoid), one launch
    lowrank_fused<<<dim3(4, M / 64), blk, 0, stream>>>(x, x_w, x_a, x_g, w1, a1, g1, hw, ha, hg);

    // big projections: bf16 MFMA
    gemm_bf16<<<dim3(8, 32), blk, 0, stream>>>(xr, WrT, rb, M, Cc, Cc);
    gemm_bf16<<<dim3(8, 32), blk, 0, stream>>>(xk, WkT, kb, M, Cc, Cc);
    gemm_bf16<<<dim3(8, 32), blk, 0, stream>>>(xv, WvT, vb, M, Cc, Cc);

    // second-stage low-rank (fp32) — xr/xk/xv and W*T are dead now
    gemm_f32<<<dim3(16, M / 64), blk, 0, stream>>>(hw, w2, wdb, nullptr, w0, M, Cc, 64, 3); // decay
    gemm_f32<<<dim3(16, M / 64), blk, 0, stream>>>(ha, a2, ab, nullptr, a0, M, Cc, 64, 2);  // sigmoid
    gemm_f32<<<dim3(16, M / 64), blk, 0, stream>>>(hg, g2, gb, nullptr, nullptr, M, Cc, 128, 0);

    // k / kk / aa / bb
    prep_k_kernel<<<dim3(M), blk, 0, stream>>>(kb, ab, k_k, k_a, kb, aab, bbb);

    // sequential recurrence (producer/consumer LDS pipeline, 512 threads)
    wkv_kernel<<<dim3(Bsz * Hh), dim3(512), 0, stream>>>(rb, wdb, kb, vb, aab, bbb, yb);

    // Wo transpose (into dead wdb slot), groupnorm+bonus+gate -> z (bf16)
    transpose_cast<<<dim3(16, 16), blk, 0, stream>>>(Wo, WoT);
    gn_rt_kernel<<<dim3(M), blk, 0, stream>>>(yb, rb, kb, vb, gb, r_k, ln_w, ln_b, zb);

    // output projection: bf16 MFMA
    gemm_bf16<<<dim3(8, 32), blk, 0, stream>>>(zb, WoT, (float*)d_out, M, Cc, Cc);
}

// Round 6
// 619.927 us; speedup vs baseline: 4.1924x; 1.4272x over previous
//
#include <hip/hip_runtime.h>
#include <math.h>

#define Bsz 4
#define Tt  1024
#define Cc  1024
#define Hh  16
#define HSs 64
#define CL  32            // wkv chunk length
#define NCH (Tt / CL)     // 32 chunks

typedef __attribute__((ext_vector_type(8))) short bf16x8;
typedef __attribute__((ext_vector_type(4))) float f32x4;

__device__ __forceinline__ float sigf(float x) { return 1.f / (1.f + expf(-x)); }

__device__ __forceinline__ unsigned short f2bf(float f) {
    unsigned int u = __float_as_uint(f);
    u = u + 0x7fffu + ((u >> 16) & 1u);   // RNE
    return (unsigned short)(u >> 16);
}
__device__ __forceinline__ float bf2f(unsigned short u) {
    return __uint_as_float(((unsigned int)u) << 16);
}

// ---------------------------------------------------------------------------
// fp32 tiled GEMM (second-stage low-rank paths): out[M,N] = f( A@W + bias )
// epi: 0=none 1=tanh 2=sigmoid 3=decay ; bf16out: write bf16 instead of f32
// ---------------------------------------------------------------------------
__global__ __launch_bounds__(256) void gemm_f32(
    const float* __restrict__ A, const float* __restrict__ W,
    float* __restrict__ out, const float* __restrict__ mix,
    const float* __restrict__ bias, int M, int N, int K, int epi, int bf16out)
{
    __shared__ float As[16][65];
    __shared__ float Bs[16][65];
    const int row0 = blockIdx.y * 64;
    const int col0 = blockIdx.x * 64;
    const int tid = threadIdx.x;
    const int tr = tid >> 4, tc = tid & 15;

    float acc[4][4];
#pragma unroll
    for (int i = 0; i < 4; ++i)
#pragma unroll
        for (int j = 0; j < 4; ++j) acc[i][j] = 0.f;

    for (int k0 = 0; k0 < K; k0 += 16) {
#pragma unroll
        for (int s = 0; s < 4; ++s) {
            int i = tid + s * 256;
            int rr = i >> 4, kk = i & 15;
            int r = row0 + rr;
            int c = k0 + kk;
            float xv = A[r * K + c];
            float val;
            if (mix) {
                int t = r & (Tt - 1);
                float xp = (t > 0) ? A[(r - 1) * K + c] : 0.f;
                val = xv + (xp - xv) * mix[c];
            } else val = xv;
            As[kk][rr] = val;
        }
#pragma unroll
        for (int s = 0; s < 4; ++s) {
            int i = tid + s * 256;
            int kk = i >> 6, cc = i & 63;
            Bs[kk][cc] = W[(k0 + kk) * N + col0 + cc];
        }
        __syncthreads();
#pragma unroll
        for (int kk = 0; kk < 16; ++kk) {
            float a[4], b[4];
#pragma unroll
            for (int u = 0; u < 4; ++u) a[u] = As[kk][tr * 4 + u];
#pragma unroll
            for (int u = 0; u < 4; ++u) b[u] = Bs[kk][tc * 4 + u];
#pragma unroll
            for (int i = 0; i < 4; ++i)
#pragma unroll
                for (int j = 0; j < 4; ++j) acc[i][j] += a[i] * b[j];
        }
        __syncthreads();
    }

#pragma unroll
    for (int i = 0; i < 4; ++i) {
        int r = row0 + tr * 4 + i;
#pragma unroll
        for (int j = 0; j < 4; ++j) {
            int c = col0 + tc * 4 + j;
            float v = acc[i][j];
            if (bias) v += bias[c];
            if (epi == 1) v = tanhf(v);
            else if (epi == 2) v = sigf(v);
            else if (epi == 3) v = expf(-0.60653065971263342f * sigf(v));
            if (bf16out) ((unsigned short*)out)[(size_t)r * N + c] = f2bf(v);
            else out[(size_t)r * N + c] = v;
        }
    }
}

// ---------------------------------------------------------------------------
// Fused first-stage low-rank: hw=tanh(xw@w1), ha=xa@a1, hg=sig(xg@g1)
// ---------------------------------------------------------------------------
__global__ __launch_bounds__(256) void lowrank_fused(
    const float* __restrict__ x,
    const float* __restrict__ x_w, const float* __restrict__ x_a,
    const float* __restrict__ x_g,
    const float* __restrict__ w1, const float* __restrict__ a1,
    const float* __restrict__ g1,
    float* __restrict__ hw, float* __restrict__ ha, float* __restrict__ hg)
{
    const int seg = blockIdx.x;
    const float* mix; const float* W; float* out; int N, col0, epi;
    if (seg == 0)      { mix = x_w; W = w1; out = hw; N = 64;  col0 = 0;  epi = 1; }
    else if (seg == 1) { mix = x_a; W = a1; out = ha; N = 64;  col0 = 0;  epi = 0; }
    else               { mix = x_g; W = g1; out = hg; N = 128; col0 = (seg - 2) * 64; epi = 2; }

    __shared__ float As[16][65];
    __shared__ float Bs[16][65];
    const int row0 = blockIdx.y * 64;
    const int tid = threadIdx.x;
    const int tr = tid >> 4, tc = tid & 15;

    float acc[4][4];
#pragma unroll
    for (int i = 0; i < 4; ++i)
#pragma unroll
        for (int j = 0; j < 4; ++j) acc[i][j] = 0.f;

    for (int k0 = 0; k0 < Cc; k0 += 16) {
#pragma unroll
        for (int s = 0; s < 4; ++s) {
            int i = tid + s * 256;
            int rr = i >> 4, kk = i & 15;
            int r = row0 + rr;
            int c = k0 + kk;
            float xv = x[r * Cc + c];
            float xp = (r & (Tt - 1)) ? x[(r - 1) * Cc + c] : 0.f;
            As[kk][rr] = xv + (xp - xv) * mix[c];
        }
#pragma unroll
        for (int s = 0; s < 4; ++s) {
            int i = tid + s * 256;
            int kk = i >> 6, cc = i & 63;
            Bs[kk][cc] = W[(k0 + kk) * N + col0 + cc];
        }
        __syncthreads();
#pragma unroll
        for (int kk = 0; kk < 16; ++kk) {
            float a[4], b[4];
#pragma unroll
            for (int u = 0; u < 4; ++u) a[u] = As[kk][tr * 4 + u];
#pragma unroll
            for (int u = 0; u < 4; ++u) b[u] = Bs[kk][tc * 4 + u];
#pragma unroll
            for (int i = 0; i < 4; ++i)
#pragma unroll
                for (int j = 0; j < 4; ++j) acc[i][j] += a[i] * b[j];
        }
        __syncthreads();
    }

#pragma unroll
    for (int i = 0; i < 4; ++i) {
        int r = row0 + tr * 4 + i;
#pragma unroll
        for (int j = 0; j < 4; ++j) {
            int c = col0 + tc * 4 + j;
            float v = acc[i][j];
            if (epi == 1) v = tanhf(v);
            else if (epi == 2) v = sigf(v);
            out[(size_t)r * N + c] = v;
        }
    }
}

// ---------------------------------------------------------------------------
// mixcast: xr/xk/xv = bf16( x + (shift(x)-x)*mix )
// ---------------------------------------------------------------------------
__global__ __launch_bounds__(256) void mixcast_kernel(
    const float* __restrict__ x, const float* __restrict__ x_r,
    const float* __restrict__ x_k, const float* __restrict__ x_v,
    unsigned short* __restrict__ xr, unsigned short* __restrict__ xk,
    unsigned short* __restrict__ xv)
{
    const int row = blockIdx.x;
    const int c0 = threadIdx.x * 4;
    const size_t o = (size_t)row * Cc;
    float4 xc = *(const float4*)(x + o + c0);
    float4 xp;
    if (row & (Tt - 1)) xp = *(const float4*)(x + o - Cc + c0);
    else { xp.x = xp.y = xp.z = xp.w = 0.f; }
    float4 mr = *(const float4*)(x_r + c0);
    float4 mk = *(const float4*)(x_k + c0);
    float4 mv = *(const float4*)(x_v + c0);
    const float* xcf = (const float*)&xc; const float* xpf = (const float*)&xp;
    const float* mrf = (const float*)&mr; const float* mkf = (const float*)&mk;
    const float* mvf = (const float*)&mv;
    ushort4 r4, k4, v4;
    unsigned short* rp = (unsigned short*)&r4;
    unsigned short* kp = (unsigned short*)&k4;
    unsigned short* vp = (unsigned short*)&v4;
#pragma unroll
    for (int j = 0; j < 4; ++j) {
        float xx = xpf[j] - xcf[j];
        rp[j] = f2bf(xcf[j] + xx * mrf[j]);
        kp[j] = f2bf(xcf[j] + xx * mkf[j]);
        vp[j] = f2bf(xcf[j] + xx * mvf[j]);
    }
    *(ushort4*)(xr + o + c0) = r4;
    *(ushort4*)(xk + o + c0) = k4;
    *(ushort4*)(xv + o + c0) = v4;
}

// ---------------------------------------------------------------------------
// transpose+cast: WT[n][k] = bf16(W[k][n])
// ---------------------------------------------------------------------------
__global__ __launch_bounds__(256) void transpose_cast(
    const float* __restrict__ W, unsigned short* __restrict__ WT)
{
    __shared__ unsigned short tile[64][68];
    const int n0 = blockIdx.x * 64, k0 = blockIdx.y * 64;
    const int tid = threadIdx.x;
    const int tr = tid >> 4, tc4 = (tid & 15) * 4;
#pragma unroll
    for (int s = 0; s < 4; ++s) {
        int kk = tr + s * 16;
        float4 w4 = *(const float4*)(W + (size_t)(k0 + kk) * Cc + n0 + tc4);
        tile[kk][tc4 + 0] = f2bf(w4.x);
        tile[kk][tc4 + 1] = f2bf(w4.y);
        tile[kk][tc4 + 2] = f2bf(w4.z);
        tile[kk][tc4 + 3] = f2bf(w4.w);
    }
    __syncthreads();
#pragma unroll
    for (int s = 0; s < 4; ++s) {
        int nn = tr + s * 16;
        ushort4 o4;
        o4.x = tile[tc4 + 0][nn];
        o4.y = tile[tc4 + 1][nn];
        o4.z = tile[tc4 + 2][nn];
        o4.w = tile[tc4 + 3][nn];
        *(ushort4*)(WT + (size_t)(n0 + nn) * Cc + k0 + tc4) = o4;
    }
}

// ---------------------------------------------------------------------------
// bf16 MFMA GEMM: out[M,N] = A[M,K](bf16) @ WT[N][K](bf16)
// ---------------------------------------------------------------------------
__global__ __launch_bounds__(256) void gemm_bf16(
    const unsigned short* __restrict__ A, const unsigned short* __restrict__ WT,
    float* __restrict__ out, int M, int N, int K)
{
    __shared__ __attribute__((aligned(16))) unsigned short As[128][40];
    __shared__ __attribute__((aligned(16))) unsigned short Bs[128][40];
    const int row0 = blockIdx.y * 128;
    const int col0 = blockIdx.x * 128;
    const int tid = threadIdx.x;
    const int wave = tid >> 6, lane = tid & 63;
    const int wr = wave >> 1, wc = wave & 1;
    const int lr = lane & 15, lk = lane >> 4;

    f32x4 acc[4][4];
#pragma unroll
    for (int m = 0; m < 4; ++m)
#pragma unroll
        for (int n = 0; n < 4; ++n)
#pragma unroll
            for (int r = 0; r < 4; ++r) acc[m][n][r] = 0.f;

    const int sr = tid >> 2;
    const int sc = (tid & 3) * 8;

    for (int k0 = 0; k0 < K; k0 += 32) {
        uint4 a0v = *(const uint4*)(A  + (size_t)(row0 + sr) * K + k0 + sc);
        uint4 a1v = *(const uint4*)(A  + (size_t)(row0 + 64 + sr) * K + k0 + sc);
        uint4 b0v = *(const uint4*)(WT + (size_t)(col0 + sr) * K + k0 + sc);
        uint4 b1v = *(const uint4*)(WT + (size_t)(col0 + 64 + sr) * K + k0 + sc);
        *(uint4*)&As[sr][sc]      = a0v;
        *(uint4*)&As[64 + sr][sc] = a1v;
        *(uint4*)&Bs[sr][sc]      = b0v;
        *(uint4*)&Bs[64 + sr][sc] = b1v;
        __syncthreads();
        bf16x8 af[4], bff[4];
#pragma unroll
        for (int m = 0; m < 4; ++m)
            af[m] = *(const bf16x8*)&As[wr * 64 + m * 16 + lr][lk * 8];
#pragma unroll
        for (int n = 0; n < 4; ++n)
            bff[n] = *(const bf16x8*)&Bs[wc * 64 + n * 16 + lr][lk * 8];
#pragma unroll
        for (int m = 0; m < 4; ++m)
#pragma unroll
            for (int n = 0; n < 4; ++n)
                acc[m][n] = __builtin_amdgcn_mfma_f32_16x16x32_bf16(af[m], bff[n], acc[m][n], 0, 0, 0);
        __syncthreads();
    }

#pragma unroll
    for (int m = 0; m < 4; ++m)
#pragma unroll
        for (int n = 0; n < 4; ++n) {
            int col = col0 + wc * 64 + n * 16 + lr;
#pragma unroll
            for (int r = 0; r < 4; ++r) {
                int row = row0 + wr * 64 + m * 16 + lk * 4 + r;
                out[(size_t)row * N + col] = acc[m][n][r];
            }
        }
}

// ---------------------------------------------------------------------------
// prep_k
// ---------------------------------------------------------------------------
__global__ __launch_bounds__(256) void prep_k_kernel(
    const float* kraw, const float* __restrict__ a,
    const float* __restrict__ k_k, const float* __restrict__ k_a,
    float* kout, float* __restrict__ aaout, float* __restrict__ bbout)
{
    const int row = blockIdx.x;
    const int tid = threadIdx.x;
    const int c0 = tid * 4;
    const size_t o = (size_t)row * Cc;

    float4 kr = *(const float4*)(kraw + o + c0);
    float4 kkw = *(const float4*)(k_k + c0);
    float4 av = *(const float4*)(a + o + c0);
    float4 kaw = *(const float4*)(k_a + c0);

    float kk[4] = { kr.x * kkw.x, kr.y * kkw.y, kr.z * kkw.z, kr.w * kkw.w };
    float ssq = kk[0]*kk[0] + kk[1]*kk[1] + kk[2]*kk[2] + kk[3]*kk[3];
    ssq += __shfl_xor(ssq, 1);
    ssq += __shfl_xor(ssq, 2);
    ssq += __shfl_xor(ssq, 4);
    ssq += __shfl_xor(ssq, 8);
    float inv = 1.f / fmaxf(sqrtf(ssq), 1e-12f);

    float krr[4] = { kr.x, kr.y, kr.z, kr.w };
    float av4[4] = { av.x, av.y, av.z, av.w };
    float ka4[4] = { kaw.x, kaw.y, kaw.z, kaw.w };
    float4 aa4, bb4, kf4;
    float* aap = (float*)&aa4; float* bbp = (float*)&bb4; float* kfp = (float*)&kf4;
#pragma unroll
    for (int j = 0; j < 4; ++j) {
        float kkn = kk[j] * inv;
        aap[j] = -kkn;
        bbp[j] = kkn * av4[j];
        kfp[j] = krr[j] * (1.f + (av4[j] - 1.f) * ka4[j]);
    }
    *(float4*)(aaout + o + c0) = aa4;
    *(float4*)(bbout + o + c0) = bb4;
    *(float4*)(kout + o + c0) = kf4;
}

// ---------------------------------------------------------------------------
// WKV chunked, phase 1. Grid = 64 bh * NCH chunks. Block 320 threads.
// Transition per step: S -> S*diag(w) + (S a) b^T  (+ v k^T for the real state).
// B-task (waves 0-3, 256 thr): evolve T (64x64, init I) through the chunk's
//   M_t products; emit rho_t = T_{1..t} r_t (bf16) and final T (bf16).
// C-task (wave 4, 64 thr): rows z_s = k_s^T T_{s+1..t}; emit alpha[t][s] = z_s.r_t
//   into LDS and final Z rows (bf16).
// Epilogue (waves 0-3): y_intra[t] = sum_{s<=t} alpha[t][s] * v_s  -> yb.
// ---------------------------------------------------------------------------
__global__ __launch_bounds__(320, 1) void wkv_chunk1(
    const float* __restrict__ rb, const float* __restrict__ wdb,
    const float* __restrict__ kb, const float* __restrict__ vb,
    const float* __restrict__ aab, const float* __restrict__ bbb,
    float* __restrict__ yb,
    unsigned short* __restrict__ TL,   // [blk][64*64]
    unsigned short* __restrict__ Rho,  // [blk][CL*64]  t*64+p
    unsigned short* __restrict__ ZL)   // [blk][CL*64]  s*64+j
{
    __shared__ float st[CL * 384];     // [s][arr][64]  0=a 1=w 2=b 3=k 4=r 5=v
    __shared__ float A_l[CL][CL + 1];  // alpha[t][s]
    const int blk = blockIdx.x;
    const int bh = blk >> 5;           // / NCH
    const int c  = blk & (NCH - 1);
    const int b = bh >> 4, h = bh & 15;
    const size_t base = (size_t)b * Tt * Cc + h * HSs + (size_t)c * CL * Cc;
    const int tid = threadIdx.x;

    // ---- stage chunk inputs ----
    if (tid < 256) {
#pragma unroll
        for (int e = 0; e < 2; ++e) {
            int idx = tid * 2 + e;             // 0..511
            int s = idx >> 4, jq = (idx & 15) * 4;
            size_t g = base + (size_t)s * Cc + jq;
            *(float4*)&st[s * 384 + 0 * 64 + jq] = *(const float4*)(aab + g);
            *(float4*)&st[s * 384 + 1 * 64 + jq] = *(const float4*)(wdb + g);
            *(float4*)&st[s * 384 + 2 * 64 + jq] = *(const float4*)(bbb + g);
            *(float4*)&st[s * 384 + 3 * 64 + jq] = *(const float4*)(kb + g);
            *(float4*)&st[s * 384 + 4 * 64 + jq] = *(const float4*)(rb + g);
            *(float4*)&st[s * 384 + 5 * 64 + jq] = *(const float4*)(vb + g);
        }
    }
    __syncthreads();

    if (tid < 256) {
        // ---- B-task ----
        const int i = tid >> 2, jc = tid & 3, j0 = jc * 16;
        float T[16];
#pragma unroll
        for (int u = 0; u < 16; ++u) T[u] = (j0 + u == i) ? 1.f : 0.f;
        const size_t rhob = (size_t)blk * (CL * 64);

        for (int t = 0; t < CL; ++t) {
            const float* sp = st + t * 384;
            float ta = 0.f;
#pragma unroll
            for (int q = 0; q < 4; ++q) {
                float4 a4 = *(const float4*)(sp + 0 * 64 + j0 + q * 4);
                ta += T[q*4+0]*a4.x + T[q*4+1]*a4.y + T[q*4+2]*a4.z + T[q*4+3]*a4.w;
            }
            ta += __shfl_xor(ta, 1);
            ta += __shfl_xor(ta, 2);
            float rp = 0.f;
#pragma unroll
            for (int q = 0; q < 4; ++q) {
                float4 w4 = *(const float4*)(sp + 1 * 64 + j0 + q * 4);
                float4 b4 = *(const float4*)(sp + 2 * 64 + j0 + q * 4);
                float4 r4 = *(const float4*)(sp + 4 * 64 + j0 + q * 4);
                T[q*4+0] = fmaf(T[q*4+0], w4.x, ta * b4.x); rp = fmaf(T[q*4+0], r4.x, rp);
                T[q*4+1] = fmaf(T[q*4+1], w4.y, ta * b4.y); rp = fmaf(T[q*4+1], r4.y, rp);
                T[q*4+2] = fmaf(T[q*4+2], w4.z, ta * b4.z); rp = fmaf(T[q*4+2], r4.z, rp);
                T[q*4+3] = fmaf(T[q*4+3], w4.w, ta * b4.w); rp = fmaf(T[q*4+3], r4.w, rp);
            }
            rp += __shfl_xor(rp, 1);
            rp += __shfl_xor(rp, 2);
            if (jc == 0) Rho[rhob + t * 64 + i] = f2bf(rp);
        }
        // final T -> TL (row i = T's row index p)
        const size_t tlb = (size_t)blk * 4096;
#pragma unroll
        for (int q = 0; q < 4; ++q) {
            ushort4 o4;
            o4.x = f2bf(T[q*4+0]); o4.y = f2bf(T[q*4+1]);
            o4.z = f2bf(T[q*4+2]); o4.w = f2bf(T[q*4+3]);
            *(ushort4*)(TL + tlb + (size_t)i * 64 + j0 + q * 4) = o4;
        }
    } else {
        // ---- C-task (wave 4) ----
        const int lane = tid - 256;
        const int s = lane >> 1, cc = lane & 1, j0 = cc * 32;
        float z[32];
#pragma unroll
        for (int u = 0; u < 32; ++u) z[u] = 0.f;

        for (int t = 0; t < CL; ++t) {
            const float* sp = st + t * 384;
            float za = 0.f;
#pragma unroll
            for (int q = 0; q < 8; ++q) {
                float4 a4 = *(const float4*)(sp + 0 * 64 + j0 + q * 4);
                za += z[q*4+0]*a4.x + z[q*4+1]*a4.y + z[q*4+2]*a4.z + z[q*4+3]*a4.w;
            }
            za += __shfl_xor(za, 1);
#pragma unroll
            for (int q = 0; q < 8; ++q) {
                float4 w4 = *(const float4*)(sp + 1 * 64 + j0 + q * 4);
                float4 b4 = *(const float4*)(sp + 2 * 64 + j0 + q * 4);
                z[q*4+0] = fmaf(z[q*4+0], w4.x, za * b4.x);
                z[q*4+1] = fmaf(z[q*4+1], w4.y, za * b4.y);
                z[q*4+2] = fmaf(z[q*4+2], w4.z, za * b4.z);
                z[q*4+3] = fmaf(z[q*4+3], w4.w, za * b4.w);
            }
            if (s == t) {
#pragma unroll
                for (int q = 0; q < 8; ++q) {
                    float4 k4 = *(const float4*)(sp + 3 * 64 + j0 + q * 4);
                    z[q*4+0] = k4.x; z[q*4+1] = k4.y; z[q*4+2] = k4.z; z[q*4+3] = k4.w;
                }
            }
            float al = 0.f;
#pragma unroll
            for (int q = 0; q < 8; ++q) {
                float4 r4 = *(const float4*)(sp + 4 * 64 + j0 + q * 4);
                al += z[q*4+0]*r4.x + z[q*4+1]*r4.y + z[q*4+2]*r4.z + z[q*4+3]*r4.w;
            }
            al += __shfl_xor(al, 1);
            if (cc == 0) A_l[t][s] = al;
        }
        // final Z -> ZL
        const size_t zlb = (size_t)blk * (CL * 64);
#pragma unroll
        for (int q = 0; q < 8; ++q) {
            ushort4 o4;
            o4.x = f2bf(z[q*4+0]); o4.y = f2bf(z[q*4+1]);
            o4.z = f2bf(z[q*4+2]); o4.w = f2bf(z[q*4+3]);
            *(ushort4*)(ZL + zlb + (size_t)s * 64 + j0 + q * 4) = o4;
        }
    }
    __syncthreads();

    // ---- y_intra = A_lower * V ----
    if (tid < 256) {
        const int t = tid >> 3, j0 = (tid & 7) * 8;
        float y[8];
#pragma unroll
        for (int e = 0; e < 8; ++e) y[e] = 0.f;
        for (int s = 0; s <= t; ++s) {
            float al = A_l[t][s];
            const float* vv = st + s * 384 + 5 * 64 + j0;
            float4 v0 = *(const float4*)(vv);
            float4 v1 = *(const float4*)(vv + 4);
            y[0] = fmaf(al, v0.x, y[0]); y[1] = fmaf(al, v0.y, y[1]);
            y[2] = fmaf(al, v0.z, y[2]); y[3] = fmaf(al, v0.w, y[3]);
            y[4] = fmaf(al, v1.x, y[4]); y[5] = fmaf(al, v1.y, y[5]);
            y[6] = fmaf(al, v1.z, y[6]); y[7] = fmaf(al, v1.w, y[7]);
        }
        float4 o0 = { y[0], y[1], y[2], y[3] };
        float4 o1 = { y[4], y[5], y[6], y[7] };
        *(float4*)(yb + base + (size_t)t * Cc + j0) = o0;
        *(float4*)(yb + base + (size_t)t * Cc + j0 + 4) = o1;
    }
}

// ---------------------------------------------------------------------------
// WKV chunked, phase 2. Grid = 64 bh * 16 row-groups (4 rows each), block 256.
// Sequential over chunks: y[t,i] += sum_p S0[i,p] rho_t[p];
//                         S <- S*T_L + V^T Z_L.
// ---------------------------------------------------------------------------
__global__ __launch_bounds__(256, 1) void wkv_chunk2(
    const float* __restrict__ vb, const unsigned short* __restrict__ TL,
    const unsigned short* __restrict__ Rho, const unsigned short* __restrict__ ZL,
    float* __restrict__ yb)
{
    __shared__ unsigned short T_l[64 * 64];   // [p][j]
    __shared__ unsigned short Z_l[32 * 64];   // [s][j]
    __shared__ unsigned short R_l[32 * 72];   // [t][p], padded stride 72
    __shared__ float V_l[32 * 4];             // [s][ii]
    __shared__ float S_l[4][68];              // [ii][p]
    const int blk = blockIdx.x;
    const int bh = blk >> 4, rg = blk & 15;
    const int b = bh >> 4, h = bh & 15;
    const int I0 = rg * 4;
    const size_t vbase = (size_t)b * Tt * Cc + h * HSs;
    const int tid = threadIdx.x;
    const int wv = tid >> 6, lane = tid & 63;

    S_l[wv][lane] = 0.f;

    for (int c = 0; c < NCH; ++c) {
        const size_t cb = (size_t)(bh * NCH + c);
        __syncthreads();
        // stage T (4096 u16)
        {
            const uint4* src = (const uint4*)(TL + cb * 4096);
            uint4 t0 = src[tid * 2];
            uint4 t1 = src[tid * 2 + 1];
            *(uint4*)&T_l[tid * 16] = t0;
            *(uint4*)&T_l[tid * 16 + 8] = t1;
        }
        // stage Z (2048 u16)
        *(uint4*)&Z_l[tid * 8] = *(const uint4*)(ZL + cb * 2048 + tid * 8);
        // stage Rho (2048 u16, padded rows)
        {
            int idx = tid * 8;
            int t_ = idx >> 6, p0 = idx & 63;
            *(uint4*)&R_l[t_ * 72 + p0] = *(const uint4*)(Rho + cb * 2048 + idx);
        }
        // stage V
        if (tid < 128) {
            int s = tid >> 2, ii = tid & 3;
            V_l[s * 4 + ii] = vb[vbase + (size_t)(c * CL + s) * Cc + I0 + ii];
        }
        __syncthreads();

        // y_state
        if (tid < 128) {
            int t_ = tid >> 2, ii = tid & 3;
            float acc = 0.f;
#pragma unroll
            for (int p8 = 0; p8 < 8; ++p8) {
                uint4 rv = *(const uint4*)&R_l[t_ * 72 + p8 * 8];
                const unsigned short* rp = (const unsigned short*)&rv;
                float4 s0 = *(const float4*)&S_l[ii][p8 * 8];
                float4 s1 = *(const float4*)&S_l[ii][p8 * 8 + 4];
                acc += bf2f(rp[0])*s0.x + bf2f(rp[1])*s0.y + bf2f(rp[2])*s0.z + bf2f(rp[3])*s0.w;
                acc += bf2f(rp[4])*s1.x + bf2f(rp[5])*s1.y + bf2f(rp[6])*s1.z + bf2f(rp[7])*s1.w;
            }
            size_t yo = vbase + (size_t)(c * CL + t_) * Cc + I0 + ii;
            yb[yo] += acc;
        }

        // S update: S_new[wv][lane] = sum_p S[wv][p]*T[p][lane] + sum_s v[s][wv]*Z[s][lane]
        float S_row[64];
#pragma unroll
        for (int p4 = 0; p4 < 16; ++p4) {
            float4 s4 = *(const float4*)&S_l[wv][p4 * 4];
            S_row[p4*4+0] = s4.x; S_row[p4*4+1] = s4.y;
            S_row[p4*4+2] = s4.z; S_row[p4*4+3] = s4.w;
        }
        float v_r[32];
#pragma unroll
        for (int s = 0; s < 32; ++s) v_r[s] = V_l[s * 4 + wv];

        float sn = 0.f;
#pragma unroll
        for (int p = 0; p < 64; ++p)
            sn = fmaf(S_row[p], bf2f(T_l[p * 64 + lane]), sn);
#pragma unroll
        for (int s = 0; s < 32; ++s)
            sn = fmaf(v_r[s], bf2f(Z_l[s * 64 + lane]), sn);

        __syncthreads();
        S_l[wv][lane] = sn;
    }
}

// ---------------------------------------------------------------------------
// GroupNorm + r*k*r_k bonus + gate (gb is bf16 now); writes z as bf16
// ---------------------------------------------------------------------------
__global__ __launch_bounds__(256) void gn_rt_kernel(
    const float* __restrict__ yb, const float* __restrict__ rb,
    const float* __restrict__ kb, const float* __restrict__ vb,
    const unsigned short* __restrict__ gb, const float* __restrict__ r_k,
    const float* __restrict__ ln_w, const float* __restrict__ ln_b,
    unsigned short* __restrict__ zb)
{
    const int row = blockIdx.x;
    const int tid = threadIdx.x;
    const int c0 = tid * 4;
    const int hd = tid >> 4;
    const int n0 = c0 & 63;
    const size_t o = (size_t)row * Cc;

    float4 y4 = *(const float4*)(yb + o + c0);
    float4 r4 = *(const float4*)(rb + o + c0);
    float4 k4 = *(const float4*)(kb + o + c0);
    float4 v4 = *(const float4*)(vb + o + c0);
    ushort4 g4u = *(const ushort4*)(gb + o + c0);
    float4 rk4 = *(const float4*)(r_k + hd * 64 + n0);

    float yv[4] = { y4.x, y4.y, y4.z, y4.w };
    float rv[4] = { r4.x, r4.y, r4.z, r4.w };
    float kv[4] = { k4.x, k4.y, k4.z, k4.w };
    float vv[4] = { v4.x, v4.y, v4.z, v4.w };
    float gv[4] = { bf2f(g4u.x), bf2f(g4u.y), bf2f(g4u.z), bf2f(g4u.w) };
    float rkv[4] = { rk4.x, rk4.y, rk4.z, rk4.w };

    float sum = 0.f, ssq = 0.f, dot = 0.f;
#pragma unroll
    for (int j = 0; j < 4; ++j) {
        sum += yv[j];
        ssq += yv[j] * yv[j];
        dot += rv[j] * kv[j] * rkv[j];
    }
#pragma unroll
    for (int m = 1; m <= 8; m <<= 1) {
        sum += __shfl_xor(sum, m);
        ssq += __shfl_xor(ssq, m);
        dot += __shfl_xor(dot, m);
    }
    const float mu = sum * (1.f / 64.f);
    const float var = ssq * (1.f / 64.f) - mu * mu;
    const float inv = rsqrtf(var + 0.00064f);

    ushort4 z4;
    unsigned short* zp = (unsigned short*)&z4;
#pragma unroll
    for (int j = 0; j < 4; ++j) {
        int c = c0 + j;
        float yg = (yv[j] - mu) * inv * ln_w[c] + ln_b[c];
        yg += dot * vv[j];
        zp[j] = f2bf(yg * gv[j]);
    }
    *(ushort4*)(zb + o + c0) = z4;
}

// ---------------------------------------------------------------------------

extern "C" void kernel_launch(void* const* d_in, const int* in_sizes, int n_in,
                              void* d_out, int out_size, void* d_ws, size_t ws_size,
                              hipStream_t stream)
{
    const float* x   = (const float*)d_in[0];
    const float* x_r = (const float*)d_in[1];
    const float* x_w = (const float*)d_in[2];
    const float* x_k = (const float*)d_in[3];
    const float* x_v = (const float*)d_in[4];
    const float* x_a = (const float*)d_in[5];
    const float* x_g = (const float*)d_in[6];
    const float* w0  = (const float*)d_in[7];
    const float* w1  = (const float*)d_in[8];
    const float* w2  = (const float*)d_in[9];
    const float* a0  = (const float*)d_in[10];
    const float* a1  = (const float*)d_in[11];
    const float* a2  = (const float*)d_in[12];
    // v0,v1,v2 (13..15): forward no-op on first-layer call
    const float* g1  = (const float*)d_in[16];
    const float* g2  = (const float*)d_in[17];
    const float* k_k = (const float*)d_in[18];
    const float* k_a = (const float*)d_in[19];
    const float* r_k = (const float*)d_in[20];
    const float* Wr  = (const float*)d_in[21];
    const float* Wk  = (const float*)d_in[22];
    const float* Wv  = (const float*)d_in[23];
    const float* Wo  = (const float*)d_in[24];
    const float* ln_w = (const float*)d_in[25];
    const float* ln_b = (const float*)d_in[26];

    float* ws = (float*)d_ws;
    const size_t S = (size_t)Bsz * Tt * Cc;       // 4,194,304 floats (16 MiB)
    const int M = Bsz * Tt;                        // 4096

    float* rb  = ws + 0 * S;
    float* wdb = ws + 1 * S;
    unsigned short* WoT = (unsigned short*)(ws + 1 * S);   // after chunk1 (wdb dead)
    float* kb  = ws + 2 * S;
    float* vb  = ws + 3 * S;
    float* aab = ws + 4 * S;
    unsigned short* zb = (unsigned short*)(ws + 4 * S);    // after chunk1 (aab dead)
    float* bbb = ws + 5 * S;
    float* yb  = ws + 6 * S;
    float* hw  = yb;                    // dead before wkv writes yb
    float* ha  = yb + 262144;
    float* hg  = yb + 524288;
    // slot7: xr,xk (bf16) -> ab (f32) -> TL (bf16, 16 MiB exactly)
    unsigned short* xr = (unsigned short*)(ws + 7 * S);
    unsigned short* xk = xr + S;
    float* ab  = ws + 7 * S;
    unsigned short* TL = (unsigned short*)(ws + 7 * S);
    // slot8: xv (bf16, 8MiB) + WrT/WkT/WvT -> gb (bf16, 8MiB) + Rho (bf16, 8MiB)
    unsigned short* xv = (unsigned short*)(ws + 8 * S);
    unsigned short* WrT = xv + S;
    unsigned short* WkT = WrT + 1048576;
    unsigned short* WvT = WkT + 1048576;
    unsigned short* gb  = (unsigned short*)(ws + 8 * S);
    unsigned short* Rho = gb + S;                          // second 8 MiB of slot8
    // slot9: ZL (bf16, 8 MiB)
    unsigned short* ZL  = (unsigned short*)(ws + 9 * S);

    dim3 blk(256);

    // mixed bf16 inputs + transposed bf16 weights
    mixcast_kernel<<<dim3(M), blk, 0, stream>>>(x, x_r, x_k, x_v, xr, xk, xv);
    transpose_cast<<<dim3(16, 16), blk, 0, stream>>>(Wr, WrT);
    transpose_cast<<<dim3(16, 16), blk, 0, stream>>>(Wk, WkT);
    transpose_cast<<<dim3(16, 16), blk, 0, stream>>>(Wv, WvT);

    // fused first-stage low-rank
    lowrank_fused<<<dim3(4, M / 64), blk, 0, stream>>>(x, x_w, x_a, x_g, w1, a1, g1, hw, ha, hg);

    // big projections: bf16 MFMA
    gemm_bf16<<<dim3(8, 32), blk, 0, stream>>>(xr, WrT, rb, M, Cc, Cc);
    gemm_bf16<<<dim3(8, 32), blk, 0, stream>>>(xk, WkT, kb, M, Cc, Cc);
    gemm_bf16<<<dim3(8, 32), blk, 0, stream>>>(xv, WvT, vb, M, Cc, Cc);

    // second-stage low-rank (fp32)
    gemm_f32<<<dim3(16, M / 64), blk, 0, stream>>>(hw, w2, wdb, nullptr, w0, M, Cc, 64, 3, 0);
    gemm_f32<<<dim3(16, M / 64), blk, 0, stream>>>(ha, a2, ab, nullptr, a0, M, Cc, 64, 2, 0);
    gemm_f32<<<dim3(16, M / 64), blk, 0, stream>>>(hg, g2, (float*)gb, nullptr, nullptr, M, Cc, 128, 0, 1);

    // k / kk / aa / bb
    prep_k_kernel<<<dim3(M), blk, 0, stream>>>(kb, ab, k_k, k_a, kb, aab, bbb);

    // chunked recurrence
    wkv_chunk1<<<dim3(64 * NCH), dim3(320), 0, stream>>>(rb, wdb, kb, vb, aab, bbb, yb, TL, Rho, ZL);
    wkv_chunk2<<<dim3(64 * 16), blk, 0, stream>>>(vb, TL, Rho, ZL, yb);

    // Wo transpose (into dead wdb slot), groupnorm+bonus+gate -> z (bf16)
    transpose_cast<<<dim3(16, 16), blk, 0, stream>>>(Wo, WoT);
    gn_rt_kernel<<<dim3(M), blk, 0, stream>>>(yb, rb, kb, vb, gb, r_k, ln_w, ln_b, zb);

    // output projection: bf16 MFMA
    gemm_bf16<<<dim3(8, 32), blk, 0, stream>>>(zb, WoT, (float*)d_out, M, Cc, Cc);
}

// Round 7
// 598.442 us; speedup vs baseline: 4.3429x; 1.0359x over previous
//
#include <hip/hip_runtime.h>
#include <math.h>

#define Bsz 4
#define Tt  1024
#define Cc  1024
#define Hh  16
#define HSs 64
#define CL  32            // wkv chunk length
#define NCH (Tt / CL)     // 32 chunks
#define STRD 388          // padded step stride in floats (388 % 32 = 4)

typedef __attribute__((ext_vector_type(8))) short bf16x8;
typedef __attribute__((ext_vector_type(4))) float f32x4;

__device__ __forceinline__ float sigf(float x) { return 1.f / (1.f + expf(-x)); }

__device__ __forceinline__ unsigned short f2bf(float f) {
    unsigned int u = __float_as_uint(f);
    u = u + 0x7fffu + ((u >> 16) & 1u);   // RNE
    return (unsigned short)(u >> 16);
}
__device__ __forceinline__ float bf2f(unsigned short u) {
    return __uint_as_float(((unsigned int)u) << 16);
}
// quad-lane butterflies on the VALU (DPP), no DS-pipe pressure
__device__ __forceinline__ float dpp_add_xor1(float x) {
    int y = __builtin_amdgcn_mov_dpp(__float_as_int(x), 0xB1, 0xF, 0xF, true);
    return x + __int_as_float(y);
}
__device__ __forceinline__ float dpp_add_xor2(float x) {
    int y = __builtin_amdgcn_mov_dpp(__float_as_int(x), 0x4E, 0xF, 0xF, true);
    return x + __int_as_float(y);
}

// ---------------------------------------------------------------------------
// fp32 tiled GEMM (second-stage low-rank paths)
// ---------------------------------------------------------------------------
__global__ __launch_bounds__(256) void gemm_f32(
    const float* __restrict__ A, const float* __restrict__ W,
    float* __restrict__ out, const float* __restrict__ mix,
    const float* __restrict__ bias, int M, int N, int K, int epi, int bf16out)
{
    __shared__ float As[16][65];
    __shared__ float Bs[16][65];
    const int row0 = blockIdx.y * 64;
    const int col0 = blockIdx.x * 64;
    const int tid = threadIdx.x;
    const int tr = tid >> 4, tc = tid & 15;

    float acc[4][4];
#pragma unroll
    for (int i = 0; i < 4; ++i)
#pragma unroll
        for (int j = 0; j < 4; ++j) acc[i][j] = 0.f;

    for (int k0 = 0; k0 < K; k0 += 16) {
#pragma unroll
        for (int s = 0; s < 4; ++s) {
            int i = tid + s * 256;
            int rr = i >> 4, kk = i & 15;
            int r = row0 + rr;
            int c = k0 + kk;
            float xv = A[r * K + c];
            float val;
            if (mix) {
                int t = r & (Tt - 1);
                float xp = (t > 0) ? A[(r - 1) * K + c] : 0.f;
                val = xv + (xp - xv) * mix[c];
            } else val = xv;
            As[kk][rr] = val;
        }
#pragma unroll
        for (int s = 0; s < 4; ++s) {
            int i = tid + s * 256;
            int kk = i >> 6, cc = i & 63;
            Bs[kk][cc] = W[(k0 + kk) * N + col0 + cc];
        }
        __syncthreads();
#pragma unroll
        for (int kk = 0; kk < 16; ++kk) {
            float a[4], b[4];
#pragma unroll
            for (int u = 0; u < 4; ++u) a[u] = As[kk][tr * 4 + u];
#pragma unroll
            for (int u = 0; u < 4; ++u) b[u] = Bs[kk][tc * 4 + u];
#pragma unroll
            for (int i = 0; i < 4; ++i)
#pragma unroll
                for (int j = 0; j < 4; ++j) acc[i][j] += a[i] * b[j];
        }
        __syncthreads();
    }

#pragma unroll
    for (int i = 0; i < 4; ++i) {
        int r = row0 + tr * 4 + i;
#pragma unroll
        for (int j = 0; j < 4; ++j) {
            int c = col0 + tc * 4 + j;
            float v = acc[i][j];
            if (bias) v += bias[c];
            if (epi == 1) v = tanhf(v);
            else if (epi == 2) v = sigf(v);
            else if (epi == 3) v = expf(-0.60653065971263342f * sigf(v));
            if (bf16out) ((unsigned short*)out)[(size_t)r * N + c] = f2bf(v);
            else out[(size_t)r * N + c] = v;
        }
    }
}

// ---------------------------------------------------------------------------
// Fused first-stage low-rank: hw=tanh(xw@w1), ha=xa@a1, hg=sig(xg@g1)
// ---------------------------------------------------------------------------
__global__ __launch_bounds__(256) void lowrank_fused(
    const float* __restrict__ x,
    const float* __restrict__ x_w, const float* __restrict__ x_a,
    const float* __restrict__ x_g,
    const float* __restrict__ w1, const float* __restrict__ a1,
    const float* __restrict__ g1,
    float* __restrict__ hw, float* __restrict__ ha, float* __restrict__ hg)
{
    const int seg = blockIdx.x;
    const float* mix; const float* W; float* out; int N, col0, epi;
    if (seg == 0)      { mix = x_w; W = w1; out = hw; N = 64;  col0 = 0;  epi = 1; }
    else if (seg == 1) { mix = x_a; W = a1; out = ha; N = 64;  col0 = 0;  epi = 0; }
    else               { mix = x_g; W = g1; out = hg; N = 128; col0 = (seg - 2) * 64; epi = 2; }

    __shared__ float As[16][65];
    __shared__ float Bs[16][65];
    const int row0 = blockIdx.y * 64;
    const int tid = threadIdx.x;
    const int tr = tid >> 4, tc = tid & 15;

    float acc[4][4];
#pragma unroll
    for (int i = 0; i < 4; ++i)
#pragma unroll
        for (int j = 0; j < 4; ++j) acc[i][j] = 0.f;

    for (int k0 = 0; k0 < Cc; k0 += 16) {
#pragma unroll
        for (int s = 0; s < 4; ++s) {
            int i = tid + s * 256;
            int rr = i >> 4, kk = i & 15;
            int r = row0 + rr;
            int c = k0 + kk;
            float xv = x[r * Cc + c];
            float xp = (r & (Tt - 1)) ? x[(r - 1) * Cc + c] : 0.f;
            As[kk][rr] = xv + (xp - xv) * mix[c];
        }
#pragma unroll
        for (int s = 0; s < 4; ++s) {
            int i = tid + s * 256;
            int kk = i >> 6, cc = i & 63;
            Bs[kk][cc] = W[(k0 + kk) * N + col0 + cc];
        }
        __syncthreads();
#pragma unroll
        for (int kk = 0; kk < 16; ++kk) {
            float a[4], b[4];
#pragma unroll
            for (int u = 0; u < 4; ++u) a[u] = As[kk][tr * 4 + u];
#pragma unroll
            for (int u = 0; u < 4; ++u) b[u] = Bs[kk][tc * 4 + u];
#pragma unroll
            for (int i = 0; i < 4; ++i)
#pragma unroll
                for (int j = 0; j < 4; ++j) acc[i][j] += a[i] * b[j];
        }
        __syncthreads();
    }

#pragma unroll
    for (int i = 0; i < 4; ++i) {
        int r = row0 + tr * 4 + i;
#pragma unroll
        for (int j = 0; j < 4; ++j) {
            int c = col0 + tc * 4 + j;
            float v = acc[i][j];
            if (epi == 1) v = tanhf(v);
            else if (epi == 2) v = sigf(v);
            out[(size_t)r * N + c] = v;
        }
    }
}

// ---------------------------------------------------------------------------
// mixcast: xr/xk/xv = bf16( x + (shift(x)-x)*mix )
// ---------------------------------------------------------------------------
__global__ __launch_bounds__(256) void mixcast_kernel(
    const float* __restrict__ x, const float* __restrict__ x_r,
    const float* __restrict__ x_k, const float* __restrict__ x_v,
    unsigned short* __restrict__ xr, unsigned short* __restrict__ xk,
    unsigned short* __restrict__ xv)
{
    const int row = blockIdx.x;
    const int c0 = threadIdx.x * 4;
    const size_t o = (size_t)row * Cc;
    float4 xc = *(const float4*)(x + o + c0);
    float4 xp;
    if (row & (Tt - 1)) xp = *(const float4*)(x + o - Cc + c0);
    else { xp.x = xp.y = xp.z = xp.w = 0.f; }
    float4 mr = *(const float4*)(x_r + c0);
    float4 mk = *(const float4*)(x_k + c0);
    float4 mv = *(const float4*)(x_v + c0);
    const float* xcf = (const float*)&xc; const float* xpf = (const float*)&xp;
    const float* mrf = (const float*)&mr; const float* mkf = (const float*)&mk;
    const float* mvf = (const float*)&mv;
    ushort4 r4, k4, v4;
    unsigned short* rp = (unsigned short*)&r4;
    unsigned short* kp = (unsigned short*)&k4;
    unsigned short* vp = (unsigned short*)&v4;
#pragma unroll
    for (int j = 0; j < 4; ++j) {
        float xx = xpf[j] - xcf[j];
        rp[j] = f2bf(xcf[j] + xx * mrf[j]);
        kp[j] = f2bf(xcf[j] + xx * mkf[j]);
        vp[j] = f2bf(xcf[j] + xx * mvf[j]);
    }
    *(ushort4*)(xr + o + c0) = r4;
    *(ushort4*)(xk + o + c0) = k4;
    *(ushort4*)(xv + o + c0) = v4;
}

// ---------------------------------------------------------------------------
// transpose+cast: WT[n][k] = bf16(W[k][n])
// ---------------------------------------------------------------------------
__global__ __launch_bounds__(256) void transpose_cast(
    const float* __restrict__ W, unsigned short* __restrict__ WT)
{
    __shared__ unsigned short tile[64][68];
    const int n0 = blockIdx.x * 64, k0 = blockIdx.y * 64;
    const int tid = threadIdx.x;
    const int tr = tid >> 4, tc4 = (tid & 15) * 4;
#pragma unroll
    for (int s = 0; s < 4; ++s) {
        int kk = tr + s * 16;
        float4 w4 = *(const float4*)(W + (size_t)(k0 + kk) * Cc + n0 + tc4);
        tile[kk][tc4 + 0] = f2bf(w4.x);
        tile[kk][tc4 + 1] = f2bf(w4.y);
        tile[kk][tc4 + 2] = f2bf(w4.z);
        tile[kk][tc4 + 3] = f2bf(w4.w);
    }
    __syncthreads();
#pragma unroll
    for (int s = 0; s < 4; ++s) {
        int nn = tr + s * 16;
        ushort4 o4;
        o4.x = tile[tc4 + 0][nn];
        o4.y = tile[tc4 + 1][nn];
        o4.z = tile[tc4 + 2][nn];
        o4.w = tile[tc4 + 3][nn];
        *(ushort4*)(WT + (size_t)(n0 + nn) * Cc + k0 + tc4) = o4;
    }
}

// ---------------------------------------------------------------------------
// bf16 MFMA GEMM: out[M,N] = A[M,K](bf16) @ WT[N][K](bf16)
// ---------------------------------------------------------------------------
__global__ __launch_bounds__(256) void gemm_bf16(
    const unsigned short* __restrict__ A, const unsigned short* __restrict__ WT,
    float* __restrict__ out, int M, int N, int K)
{
    __shared__ __attribute__((aligned(16))) unsigned short As[128][40];
    __shared__ __attribute__((aligned(16))) unsigned short Bs[128][40];
    const int row0 = blockIdx.y * 128;
    const int col0 = blockIdx.x * 128;
    const int tid = threadIdx.x;
    const int wave = tid >> 6, lane = tid & 63;
    const int wr = wave >> 1, wc = wave & 1;
    const int lr = lane & 15, lk = lane >> 4;

    f32x4 acc[4][4];
#pragma unroll
    for (int m = 0; m < 4; ++m)
#pragma unroll
        for (int n = 0; n < 4; ++n)
#pragma unroll
            for (int r = 0; r < 4; ++r) acc[m][n][r] = 0.f;

    const int sr = tid >> 2;
    const int sc = (tid & 3) * 8;

    for (int k0 = 0; k0 < K; k0 += 32) {
        uint4 a0v = *(const uint4*)(A  + (size_t)(row0 + sr) * K + k0 + sc);
        uint4 a1v = *(const uint4*)(A  + (size_t)(row0 + 64 + sr) * K + k0 + sc);
        uint4 b0v = *(const uint4*)(WT + (size_t)(col0 + sr) * K + k0 + sc);
        uint4 b1v = *(const uint4*)(WT + (size_t)(col0 + 64 + sr) * K + k0 + sc);
        *(uint4*)&As[sr][sc]      = a0v;
        *(uint4*)&As[64 + sr][sc] = a1v;
        *(uint4*)&Bs[sr][sc]      = b0v;
        *(uint4*)&Bs[64 + sr][sc] = b1v;
        __syncthreads();
        bf16x8 af[4], bff[4];
#pragma unroll
        for (int m = 0; m < 4; ++m)
            af[m] = *(const bf16x8*)&As[wr * 64 + m * 16 + lr][lk * 8];
#pragma unroll
        for (int n = 0; n < 4; ++n)
            bff[n] = *(const bf16x8*)&Bs[wc * 64 + n * 16 + lr][lk * 8];
#pragma unroll
        for (int m = 0; m < 4; ++m)
#pragma unroll
            for (int n = 0; n < 4; ++n)
                acc[m][n] = __builtin_amdgcn_mfma_f32_16x16x32_bf16(af[m], bff[n], acc[m][n], 0, 0, 0);
        __syncthreads();
    }

#pragma unroll
    for (int m = 0; m < 4; ++m)
#pragma unroll
        for (int n = 0; n < 4; ++n) {
            int col = col0 + wc * 64 + n * 16 + lr;
#pragma unroll
            for (int r = 0; r < 4; ++r) {
                int row = row0 + wr * 64 + m * 16 + lk * 4 + r;
                out[(size_t)row * N + col] = acc[m][n][r];
            }
        }
}

// ---------------------------------------------------------------------------
// prep_k
// ---------------------------------------------------------------------------
__global__ __launch_bounds__(256) void prep_k_kernel(
    const float* kraw, const float* __restrict__ a,
    const float* __restrict__ k_k, const float* __restrict__ k_a,
    float* kout, float* __restrict__ aaout, float* __restrict__ bbout)
{
    const int row = blockIdx.x;
    const int tid = threadIdx.x;
    const int c0 = tid * 4;
    const size_t o = (size_t)row * Cc;

    float4 kr = *(const float4*)(kraw + o + c0);
    float4 kkw = *(const float4*)(k_k + c0);
    float4 av = *(const float4*)(a + o + c0);
    float4 kaw = *(const float4*)(k_a + c0);

    float kk[4] = { kr.x * kkw.x, kr.y * kkw.y, kr.z * kkw.z, kr.w * kkw.w };
    float ssq = kk[0]*kk[0] + kk[1]*kk[1] + kk[2]*kk[2] + kk[3]*kk[3];
    ssq += __shfl_xor(ssq, 1);
    ssq += __shfl_xor(ssq, 2);
    ssq += __shfl_xor(ssq, 4);
    ssq += __shfl_xor(ssq, 8);
    float inv = 1.f / fmaxf(sqrtf(ssq), 1e-12f);

    float krr[4] = { kr.x, kr.y, kr.z, kr.w };
    float av4[4] = { av.x, av.y, av.z, av.w };
    float ka4[4] = { kaw.x, kaw.y, kaw.z, kaw.w };
    float4 aa4, bb4, kf4;
    float* aap = (float*)&aa4; float* bbp = (float*)&bb4; float* kfp = (float*)&kf4;
#pragma unroll
    for (int j = 0; j < 4; ++j) {
        float kkn = kk[j] * inv;
        aap[j] = -kkn;
        bbp[j] = kkn * av4[j];
        kfp[j] = krr[j] * (1.f + (av4[j] - 1.f) * ka4[j]);
    }
    *(float4*)(aaout + o + c0) = aa4;
    *(float4*)(bbout + o + c0) = bb4;
    *(float4*)(kout + o + c0) = kf4;
}

// ---------------------------------------------------------------------------
// WKV chunked, phase 1 (v2: register-blocked, DPP reductions).
// Grid = 64 bh * NCH chunks. Block 128 threads (2 waves).
// Wave 0 (B-task): thread = 4 rows x 16 cols, T[4][16] in regs.
//   16 ds_read_b128 per step (a,w,b,r slices shared across the 4 rows);
//   reductions over the 4 jc lanes via DPP quad_perm (VALU, no DS).
// Wave 1 (C-task): as before; 2-lane reduce via DPP xor1.
// Epilogue (both waves): y_intra[t] = sum_{s<=t} alpha[t][s] * v_s.
// LDS: st[CL*STRD] (stride 388 spreads banks), A_l[32][33].
// ---------------------------------------------------------------------------
__global__ __launch_bounds__(128, 1) void wkv_chunk1(
    const float* __restrict__ rb, const float* __restrict__ wdb,
    const float* __restrict__ kb, const float* __restrict__ vb,
    const float* __restrict__ aab, const float* __restrict__ bbb,
    float* __restrict__ yb,
    unsigned short* __restrict__ TL,   // [blk][64*64]
    unsigned short* __restrict__ Rho,  // [blk][CL*64]  t*64+p
    unsigned short* __restrict__ ZL)   // [blk][CL*64]  s*64+j
{
    __shared__ float st[CL * STRD];    // [s][arr][64]  0=a 1=w 2=b 3=k 4=r 5=v
    __shared__ float A_l[CL][CL + 1];  // alpha[t][s]
    const int blk = blockIdx.x;
    const int bh = blk >> 5;           // / NCH
    const int c  = blk & (NCH - 1);
    const int b = bh >> 4, h = bh & 15;
    const size_t base = (size_t)b * Tt * Cc + h * HSs + (size_t)c * CL * Cc;
    const int tid = threadIdx.x;

    // ---- stage chunk inputs: 6 arrays x 512 float4, 128 threads x 4 iters ----
    {
        const float* srcs[6] = { aab, wdb, bbb, kb, rb, vb };
#pragma unroll
        for (int arr = 0; arr < 6; ++arr) {
            const float* g = srcs[arr];
#pragma unroll
            for (int e = 0; e < 4; ++e) {
                int idx = tid + e * 128;          // 0..511
                int s = idx >> 4, jq = (idx & 15) * 4;
                *(float4*)&st[s * STRD + arr * 64 + jq] =
                    *(const float4*)(g + base + (size_t)s * Cc + jq);
            }
        }
    }
    __syncthreads();

    const int wv = tid >> 6, lane = tid & 63;
    if (wv == 0) {
        // ---- B-task: 4 rows x 16 cols per thread, one wave = all 64 rows ----
        const int rq = lane >> 2, jc = lane & 3;
        const int i0 = rq * 4, j0 = jc * 16;
        float T[4][16];
#pragma unroll
        for (int rr = 0; rr < 4; ++rr)
#pragma unroll
            for (int cc = 0; cc < 16; ++cc)
                T[rr][cc] = (i0 + rr == j0 + cc) ? 1.f : 0.f;
        const size_t rhob = (size_t)blk * (CL * 64);

        for (int t = 0; t < CL; ++t) {
            const float* sp = st + t * STRD;
            float a[16], w[16], bv[16], r[16];
#pragma unroll
            for (int q = 0; q < 4; ++q) {
                *(float4*)&a[q * 4]  = *(const float4*)(sp + 0 * 64 + j0 + q * 4);
                *(float4*)&w[q * 4]  = *(const float4*)(sp + 1 * 64 + j0 + q * 4);
                *(float4*)&bv[q * 4] = *(const float4*)(sp + 2 * 64 + j0 + q * 4);
                *(float4*)&r[q * 4]  = *(const float4*)(sp + 4 * 64 + j0 + q * 4);
            }
            float ta[4];
#pragma unroll
            for (int rr = 0; rr < 4; ++rr) {
                float s0 = T[rr][0] * a[0];
#pragma unroll
                for (int cc = 1; cc < 16; ++cc) s0 = fmaf(T[rr][cc], a[cc], s0);
                ta[rr] = s0;
            }
#pragma unroll
            for (int rr = 0; rr < 4; ++rr) {
                ta[rr] = dpp_add_xor1(ta[rr]);
                ta[rr] = dpp_add_xor2(ta[rr]);
            }
            float rp[4] = { 0.f, 0.f, 0.f, 0.f };
#pragma unroll
            for (int rr = 0; rr < 4; ++rr) {
#pragma unroll
                for (int cc = 0; cc < 16; ++cc) {
                    T[rr][cc] = fmaf(T[rr][cc], w[cc], ta[rr] * bv[cc]);
                    rp[rr] = fmaf(T[rr][cc], r[cc], rp[rr]);
                }
            }
#pragma unroll
            for (int rr = 0; rr < 4; ++rr) {
                rp[rr] = dpp_add_xor1(rp[rr]);
                rp[rr] = dpp_add_xor2(rp[rr]);
            }
            if (jc == 0) {
                ushort4 o4;
                o4.x = f2bf(rp[0]); o4.y = f2bf(rp[1]);
                o4.z = f2bf(rp[2]); o4.w = f2bf(rp[3]);
                *(ushort4*)(Rho + rhob + t * 64 + i0) = o4;
            }
        }
        // final T -> TL
        const size_t tlb = (size_t)blk * 4096;
#pragma unroll
        for (int rr = 0; rr < 4; ++rr) {
#pragma unroll
            for (int q = 0; q < 4; ++q) {
                ushort4 o4;
                o4.x = f2bf(T[rr][q*4+0]); o4.y = f2bf(T[rr][q*4+1]);
                o4.z = f2bf(T[rr][q*4+2]); o4.w = f2bf(T[rr][q*4+3]);
                *(ushort4*)(TL + tlb + (size_t)(i0 + rr) * 64 + j0 + q * 4) = o4;
            }
        }
    } else {
        // ---- C-task ----
        const int s = lane >> 1, cc = lane & 1, j0 = cc * 32;
        float z[32];
#pragma unroll
        for (int u = 0; u < 32; ++u) z[u] = 0.f;

        for (int t = 0; t < CL; ++t) {
            const float* sp = st + t * STRD;
            float za = 0.f;
#pragma unroll
            for (int q = 0; q < 8; ++q) {
                float4 a4 = *(const float4*)(sp + 0 * 64 + j0 + q * 4);
                za += z[q*4+0]*a4.x + z[q*4+1]*a4.y + z[q*4+2]*a4.z + z[q*4+3]*a4.w;
            }
            za = dpp_add_xor1(za);
#pragma unroll
            for (int q = 0; q < 8; ++q) {
                float4 w4 = *(const float4*)(sp + 1 * 64 + j0 + q * 4);
                float4 b4 = *(const float4*)(sp + 2 * 64 + j0 + q * 4);
                z[q*4+0] = fmaf(z[q*4+0], w4.x, za * b4.x);
                z[q*4+1] = fmaf(z[q*4+1], w4.y, za * b4.y);
                z[q*4+2] = fmaf(z[q*4+2], w4.z, za * b4.z);
                z[q*4+3] = fmaf(z[q*4+3], w4.w, za * b4.w);
            }
            if (s == t) {
#pragma unroll
                for (int q = 0; q < 8; ++q) {
                    float4 k4 = *(const float4*)(sp + 3 * 64 + j0 + q * 4);
                    z[q*4+0] = k4.x; z[q*4+1] = k4.y; z[q*4+2] = k4.z; z[q*4+3] = k4.w;
                }
            }
            float al = 0.f;
#pragma unroll
            for (int q = 0; q < 8; ++q) {
                float4 r4 = *(const float4*)(sp + 4 * 64 + j0 + q * 4);
                al += z[q*4+0]*r4.x + z[q*4+1]*r4.y + z[q*4+2]*r4.z + z[q*4+3]*r4.w;
            }
            al = dpp_add_xor1(al);
            if (cc == 0) A_l[t][s] = al;
        }
        // final Z -> ZL
        const size_t zlb = (size_t)blk * (CL * 64);
#pragma unroll
        for (int q = 0; q < 8; ++q) {
            ushort4 o4;
            o4.x = f2bf(z[q*4+0]); o4.y = f2bf(z[q*4+1]);
            o4.z = f2bf(z[q*4+2]); o4.w = f2bf(z[q*4+3]);
            *(ushort4*)(ZL + zlb + (size_t)s * 64 + j0 + q * 4) = o4;
        }
    }
    __syncthreads();

    // ---- y_intra = A_lower * V : 128 threads, t = tid>>2, 16 cols each ----
    {
        const int t = tid >> 2, jq = (tid & 3) * 16;
        float y[16];
#pragma unroll
        for (int e = 0; e < 16; ++e) y[e] = 0.f;
        for (int s = 0; s <= t; ++s) {
            float al = A_l[t][s];
            const float* vv = st + s * STRD + 5 * 64 + jq;
#pragma unroll
            for (int q = 0; q < 4; ++q) {
                float4 v4 = *(const float4*)(vv + q * 4);
                y[q*4+0] = fmaf(al, v4.x, y[q*4+0]);
                y[q*4+1] = fmaf(al, v4.y, y[q*4+1]);
                y[q*4+2] = fmaf(al, v4.z, y[q*4+2]);
                y[q*4+3] = fmaf(al, v4.w, y[q*4+3]);
            }
        }
#pragma unroll
        for (int q = 0; q < 4; ++q) {
            float4 o4 = { y[q*4+0], y[q*4+1], y[q*4+2], y[q*4+3] };
            *(float4*)(yb + base + (size_t)t * Cc + jq + q * 4) = o4;
        }
    }
}

// ---------------------------------------------------------------------------
// WKV chunked, phase 2 (unchanged).
// ---------------------------------------------------------------------------
__global__ __launch_bounds__(256, 1) void wkv_chunk2(
    const float* __restrict__ vb, const unsigned short* __restrict__ TL,
    const unsigned short* __restrict__ Rho, const unsigned short* __restrict__ ZL,
    float* __restrict__ yb)
{
    __shared__ unsigned short T_l[64 * 64];   // [p][j]
    __shared__ unsigned short Z_l[32 * 64];   // [s][j]
    __shared__ unsigned short R_l[32 * 72];   // [t][p], padded stride 72
    __shared__ float V_l[32 * 4];             // [s][ii]
    __shared__ float S_l[4][68];              // [ii][p]
    const int blk = blockIdx.x;
    const int bh = blk >> 4, rg = blk & 15;
    const int b = bh >> 4, h = bh & 15;
    const int I0 = rg * 4;
    const size_t vbase = (size_t)b * Tt * Cc + h * HSs;
    const int tid = threadIdx.x;
    const int wv = tid >> 6, lane = tid & 63;

    S_l[wv][lane] = 0.f;

    for (int c = 0; c < NCH; ++c) {
        const size_t cb = (size_t)(bh * NCH + c);
        __syncthreads();
        {
            const uint4* src = (const uint4*)(TL + cb * 4096);
            uint4 t0 = src[tid * 2];
            uint4 t1 = src[tid * 2 + 1];
            *(uint4*)&T_l[tid * 16] = t0;
            *(uint4*)&T_l[tid * 16 + 8] = t1;
        }
        *(uint4*)&Z_l[tid * 8] = *(const uint4*)(ZL + cb * 2048 + tid * 8);
        {
            int idx = tid * 8;
            int t_ = idx >> 6, p0 = idx & 63;
            *(uint4*)&R_l[t_ * 72 + p0] = *(const uint4*)(Rho + cb * 2048 + idx);
        }
        if (tid < 128) {
            int s = tid >> 2, ii = tid & 3;
            V_l[s * 4 + ii] = vb[vbase + (size_t)(c * CL + s) * Cc + I0 + ii];
        }
        __syncthreads();

        if (tid < 128) {
            int t_ = tid >> 2, ii = tid & 3;
            float acc = 0.f;
#pragma unroll
            for (int p8 = 0; p8 < 8; ++p8) {
                uint4 rv = *(const uint4*)&R_l[t_ * 72 + p8 * 8];
                const unsigned short* rp = (const unsigned short*)&rv;
                float4 s0 = *(const float4*)&S_l[ii][p8 * 8];
                float4 s1 = *(const float4*)&S_l[ii][p8 * 8 + 4];
                acc += bf2f(rp[0])*s0.x + bf2f(rp[1])*s0.y + bf2f(rp[2])*s0.z + bf2f(rp[3])*s0.w;
                acc += bf2f(rp[4])*s1.x + bf2f(rp[5])*s1.y + bf2f(rp[6])*s1.z + bf2f(rp[7])*s1.w;
            }
            size_t yo = vbase + (size_t)(c * CL + t_) * Cc + I0 + ii;
            yb[yo] += acc;
        }

        float S_row[64];
#pragma unroll
        for (int p4 = 0; p4 < 16; ++p4) {
            float4 s4 = *(const float4*)&S_l[wv][p4 * 4];
            S_row[p4*4+0] = s4.x; S_row[p4*4+1] = s4.y;
            S_row[p4*4+2] = s4.z; S_row[p4*4+3] = s4.w;
        }
        float v_r[32];
#pragma unroll
        for (int s = 0; s < 32; ++s) v_r[s] = V_l[s * 4 + wv];

        float sn = 0.f;
#pragma unroll
        for (int p = 0; p < 64; ++p)
            sn = fmaf(S_row[p], bf2f(T_l[p * 64 + lane]), sn);
#pragma unroll
        for (int s = 0; s < 32; ++s)
            sn = fmaf(v_r[s], bf2f(Z_l[s * 64 + lane]), sn);

        __syncthreads();
        S_l[wv][lane] = sn;
    }
}

// ---------------------------------------------------------------------------
// GroupNorm + r*k*r_k bonus + gate
// ---------------------------------------------------------------------------
__global__ __launch_bounds__(256) void gn_rt_kernel(
    const float* __restrict__ yb, const float* __restrict__ rb,
    const float* __restrict__ kb, const float* __restrict__ vb,
    const unsigned short* __restrict__ gb, const float* __restrict__ r_k,
    const float* __restrict__ ln_w, const float* __restrict__ ln_b,
    unsigned short* __restrict__ zb)
{
    const int row = blockIdx.x;
    const int tid = threadIdx.x;
    const int c0 = tid * 4;
    const int hd = tid >> 4;
    const int n0 = c0 & 63;
    const size_t o = (size_t)row * Cc;

    float4 y4 = *(const float4*)(yb + o + c0);
    float4 r4 = *(const float4*)(rb + o + c0);
    float4 k4 = *(const float4*)(kb + o + c0);
    float4 v4 = *(const float4*)(vb + o + c0);
    ushort4 g4u = *(const ushort4*)(gb + o + c0);
    float4 rk4 = *(const float4*)(r_k + hd * 64 + n0);

    float yv[4] = { y4.x, y4.y, y4.z, y4.w };
    float rv[4] = { r4.x, r4.y, r4.z, r4.w };
    float kv[4] = { k4.x, k4.y, k4.z, k4.w };
    float vv[4] = { v4.x, v4.y, v4.z, v4.w };
    float gv[4] = { bf2f(g4u.x), bf2f(g4u.y), bf2f(g4u.z), bf2f(g4u.w) };
    float rkv[4] = { rk4.x, rk4.y, rk4.z, rk4.w };

    float sum = 0.f, ssq = 0.f, dot = 0.f;
#pragma unroll
    for (int j = 0; j < 4; ++j) {
        sum += yv[j];
        ssq += yv[j] * yv[j];
        dot += rv[j] * kv[j] * rkv[j];
    }
#pragma unroll
    for (int m = 1; m <= 8; m <<= 1) {
        sum += __shfl_xor(sum, m);
        ssq += __shfl_xor(ssq, m);
        dot += __shfl_xor(dot, m);
    }
    const float mu = sum * (1.f / 64.f);
    const float var = ssq * (1.f / 64.f) - mu * mu;
    const float inv = rsqrtf(var + 0.00064f);

    ushort4 z4;
    unsigned short* zp = (unsigned short*)&z4;
#pragma unroll
    for (int j = 0; j < 4; ++j) {
        int c = c0 + j;
        float yg = (yv[j] - mu) * inv * ln_w[c] + ln_b[c];
        yg += dot * vv[j];
        zp[j] = f2bf(yg * gv[j]);
    }
    *(ushort4*)(zb + o + c0) = z4;
}

// ---------------------------------------------------------------------------

extern "C" void kernel_launch(void* const* d_in, const int* in_sizes, int n_in,
                              void* d_out, int out_size, void* d_ws, size_t ws_size,
                              hipStream_t stream)
{
    const float* x   = (const float*)d_in[0];
    const float* x_r = (const float*)d_in[1];
    const float* x_w = (const float*)d_in[2];
    const float* x_k = (const float*)d_in[3];
    const float* x_v = (const float*)d_in[4];
    const float* x_a = (const float*)d_in[5];
    const float* x_g = (const float*)d_in[6];
    const float* w0  = (const float*)d_in[7];
    const float* w1  = (const float*)d_in[8];
    const float* w2  = (const float*)d_in[9];
    const float* a0  = (const float*)d_in[10];
    const float* a1  = (const float*)d_in[11];
    const float* a2  = (const float*)d_in[12];
    // v0,v1,v2 (13..15): forward no-op on first-layer call
    const float* g1  = (const float*)d_in[16];
    const float* g2  = (const float*)d_in[17];
    const float* k_k = (const float*)d_in[18];
    const float* k_a = (const float*)d_in[19];
    const float* r_k = (const float*)d_in[20];
    const float* Wr  = (const float*)d_in[21];
    const float* Wk  = (const float*)d_in[22];
    const float* Wv  = (const float*)d_in[23];
    const float* Wo  = (const float*)d_in[24];
    const float* ln_w = (const float*)d_in[25];
    const float* ln_b = (const float*)d_in[26];

    float* ws = (float*)d_ws;
    const size_t S = (size_t)Bsz * Tt * Cc;       // 4,194,304 floats (16 MiB)
    const int M = Bsz * Tt;                        // 4096

    float* rb  = ws + 0 * S;
    float* wdb = ws + 1 * S;
    unsigned short* WoT = (unsigned short*)(ws + 1 * S);   // after chunk1 (wdb dead)
    float* kb  = ws + 2 * S;
    float* vb  = ws + 3 * S;
    float* aab = ws + 4 * S;
    unsigned short* zb = (unsigned short*)(ws + 4 * S);    // after chunk1 (aab dead)
    float* bbb = ws + 5 * S;
    float* yb  = ws + 6 * S;
    float* hw  = yb;                    // dead before wkv writes yb
    float* ha  = yb + 262144;
    float* hg  = yb + 524288;
    // slot7: xr,xk (bf16) -> ab (f32) -> TL (bf16, 16 MiB exactly)
    unsigned short* xr = (unsigned short*)(ws + 7 * S);
    unsigned short* xk = xr + S;
    float* ab  = ws + 7 * S;
    unsigned short* TL = (unsigned short*)(ws + 7 * S);
    // slot8: xv (bf16, 8MiB) + WrT/WkT/WvT -> gb (bf16, 8MiB) + Rho (bf16, 8MiB)
    unsigned short* xv = (unsigned short*)(ws + 8 * S);
    unsigned short* WrT = xv + S;
    unsigned short* WkT = WrT + 1048576;
    unsigned short* WvT = WkT + 1048576;
    unsigned short* gb  = (unsigned short*)(ws + 8 * S);
    unsigned short* Rho = gb + S;                          // second 8 MiB of slot8
    // slot9: ZL (bf16, 8 MiB)
    unsigned short* ZL  = (unsigned short*)(ws + 9 * S);

    dim3 blk(256);

    // mixed bf16 inputs + transposed bf16 weights
    mixcast_kernel<<<dim3(M), blk, 0, stream>>>(x, x_r, x_k, x_v, xr, xk, xv);
    transpose_cast<<<dim3(16, 16), blk, 0, stream>>>(Wr, WrT);
    transpose_cast<<<dim3(16, 16), blk, 0, stream>>>(Wk, WkT);
    transpose_cast<<<dim3(16, 16), blk, 0, stream>>>(Wv, WvT);

    // fused first-stage low-rank
    lowrank_fused<<<dim3(4, M / 64), blk, 0, stream>>>(x, x_w, x_a, x_g, w1, a1, g1, hw, ha, hg);

    // big projections: bf16 MFMA
    gemm_bf16<<<dim3(8, 32), blk, 0, stream>>>(xr, WrT, rb, M, Cc, Cc);
    gemm_bf16<<<dim3(8, 32), blk, 0, stream>>>(xk, WkT, kb, M, Cc, Cc);
    gemm_bf16<<<dim3(8, 32), blk, 0, stream>>>(xv, WvT, vb, M, Cc, Cc);

    // second-stage low-rank (fp32)
    gemm_f32<<<dim3(16, M / 64), blk, 0, stream>>>(hw, w2, wdb, nullptr, w0, M, Cc, 64, 3, 0);
    gemm_f32<<<dim3(16, M / 64), blk, 0, stream>>>(ha, a2, ab, nullptr, a0, M, Cc, 64, 2, 0);
    gemm_f32<<<dim3(16, M / 64), blk, 0, stream>>>(hg, g2, (float*)gb, nullptr, nullptr, M, Cc, 128, 0, 1);

    // k / kk / aa / bb
    prep_k_kernel<<<dim3(M), blk, 0, stream>>>(kb, ab, k_k, k_a, kb, aab, bbb);

    // chunked recurrence
    wkv_chunk1<<<dim3(64 * NCH), dim3(128), 0, stream>>>(rb, wdb, kb, vb, aab, bbb, yb, TL, Rho, ZL);
    wkv_chunk2<<<dim3(64 * 16), blk, 0, stream>>>(vb, TL, Rho, ZL, yb);

    // Wo transpose (into dead wdb slot), groupnorm+bonus+gate -> z (bf16)
    transpose_cast<<<dim3(16, 16), blk, 0, stream>>>(Wo, WoT);
    gn_rt_kernel<<<dim3(M), blk, 0, stream>>>(yb, rb, kb, vb, gb, r_k, ln_w, ln_b, zb);

    // output projection: bf16 MFMA
    gemm_bf16<<<dim3(8, 32), blk, 0, stream>>>(zb, WoT, (float*)d_out, M, Cc, Cc);
}

// Round 8
// 519.102 us; speedup vs baseline: 5.0066x; 1.1528x over previous
//
#include <hip/hip_runtime.h>
#include <math.h>

#define Bsz 4
#define Tt  1024
#define Cc  1024
#define Hh  16
#define HSs 64
#define CL  32            // wkv chunk length
#define NCH (Tt / CL)     // 32 chunks
#define STRD 388          // padded step stride in floats (388 % 32 = 4)

typedef __attribute__((ext_vector_type(8))) short bf16x8;
typedef __attribute__((ext_vector_type(4))) float f32x4;

__device__ __forceinline__ float sigf(float x) { return 1.f / (1.f + expf(-x)); }

__device__ __forceinline__ unsigned short f2bf(float f) {
    unsigned int u = __float_as_uint(f);
    u = u + 0x7fffu + ((u >> 16) & 1u);   // RNE
    return (unsigned short)(u >> 16);
}
__device__ __forceinline__ float bf2f(unsigned short u) {
    return __uint_as_float(((unsigned int)u) << 16);
}
// quad-lane butterflies on the VALU (DPP), no DS-pipe pressure
__device__ __forceinline__ float dpp_add_xor1(float x) {
    int y = __builtin_amdgcn_mov_dpp(__float_as_int(x), 0xB1, 0xF, 0xF, true);
    return x + __int_as_float(y);
}
__device__ __forceinline__ float dpp_add_xor2(float x) {
    int y = __builtin_amdgcn_mov_dpp(__float_as_int(x), 0x4E, 0xF, 0xF, true);
    return x + __int_as_float(y);
}

// ---------------------------------------------------------------------------
// fp32 tiled GEMM (second-stage low-rank paths)
// ---------------------------------------------------------------------------
__global__ __launch_bounds__(256) void gemm_f32(
    const float* __restrict__ A, const float* __restrict__ W,
    float* __restrict__ out, const float* __restrict__ mix,
    const float* __restrict__ bias, int M, int N, int K, int epi, int bf16out)
{
    __shared__ float As[16][65];
    __shared__ float Bs[16][65];
    const int row0 = blockIdx.y * 64;
    const int col0 = blockIdx.x * 64;
    const int tid = threadIdx.x;
    const int tr = tid >> 4, tc = tid & 15;

    float acc[4][4];
#pragma unroll
    for (int i = 0; i < 4; ++i)
#pragma unroll
        for (int j = 0; j < 4; ++j) acc[i][j] = 0.f;

    for (int k0 = 0; k0 < K; k0 += 16) {
#pragma unroll
        for (int s = 0; s < 4; ++s) {
            int i = tid + s * 256;
            int rr = i >> 4, kk = i & 15;
            int r = row0 + rr;
            int c = k0 + kk;
            float xv = A[r * K + c];
            float val;
            if (mix) {
                int t = r & (Tt - 1);
                float xp = (t > 0) ? A[(r - 1) * K + c] : 0.f;
                val = xv + (xp - xv) * mix[c];
            } else val = xv;
            As[kk][rr] = val;
        }
#pragma unroll
        for (int s = 0; s < 4; ++s) {
            int i = tid + s * 256;
            int kk = i >> 6, cc = i & 63;
            Bs[kk][cc] = W[(k0 + kk) * N + col0 + cc];
        }
        __syncthreads();
#pragma unroll
        for (int kk = 0; kk < 16; ++kk) {
            float a[4], b[4];
#pragma unroll
            for (int u = 0; u < 4; ++u) a[u] = As[kk][tr * 4 + u];
#pragma unroll
            for (int u = 0; u < 4; ++u) b[u] = Bs[kk][tc * 4 + u];
#pragma unroll
            for (int i = 0; i < 4; ++i)
#pragma unroll
                for (int j = 0; j < 4; ++j) acc[i][j] += a[i] * b[j];
        }
        __syncthreads();
    }

#pragma unroll
    for (int i = 0; i < 4; ++i) {
        int r = row0 + tr * 4 + i;
#pragma unroll
        for (int j = 0; j < 4; ++j) {
            int c = col0 + tc * 4 + j;
            float v = acc[i][j];
            if (bias) v += bias[c];
            if (epi == 1) v = tanhf(v);
            else if (epi == 2) v = sigf(v);
            else if (epi == 3) v = expf(-0.60653065971263342f * sigf(v));
            if (bf16out) ((unsigned short*)out)[(size_t)r * N + c] = f2bf(v);
            else out[(size_t)r * N + c] = v;
        }
    }
}

// ---------------------------------------------------------------------------
// Fused first-stage low-rank: hw=tanh(xw@w1), ha=xa@a1, hg=sig(xg@g1)
// ---------------------------------------------------------------------------
__global__ __launch_bounds__(256) void lowrank_fused(
    const float* __restrict__ x,
    const float* __restrict__ x_w, const float* __restrict__ x_a,
    const float* __restrict__ x_g,
    const float* __restrict__ w1, const float* __restrict__ a1,
    const float* __restrict__ g1,
    float* __restrict__ hw, float* __restrict__ ha, float* __restrict__ hg)
{
    const int seg = blockIdx.x;
    const float* mix; const float* W; float* out; int N, col0, epi;
    if (seg == 0)      { mix = x_w; W = w1; out = hw; N = 64;  col0 = 0;  epi = 1; }
    else if (seg == 1) { mix = x_a; W = a1; out = ha; N = 64;  col0 = 0;  epi = 0; }
    else               { mix = x_g; W = g1; out = hg; N = 128; col0 = (seg - 2) * 64; epi = 2; }

    __shared__ float As[16][65];
    __shared__ float Bs[16][65];
    const int row0 = blockIdx.y * 64;
    const int tid = threadIdx.x;
    const int tr = tid >> 4, tc = tid & 15;

    float acc[4][4];
#pragma unroll
    for (int i = 0; i < 4; ++i)
#pragma unroll
        for (int j = 0; j < 4; ++j) acc[i][j] = 0.f;

    for (int k0 = 0; k0 < Cc; k0 += 16) {
#pragma unroll
        for (int s = 0; s < 4; ++s) {
            int i = tid + s * 256;
            int rr = i >> 4, kk = i & 15;
            int r = row0 + rr;
            int c = k0 + kk;
            float xv = x[r * Cc + c];
            float xp = (r & (Tt - 1)) ? x[(r - 1) * Cc + c] : 0.f;
            As[kk][rr] = xv + (xp - xv) * mix[c];
        }
#pragma unroll
        for (int s = 0; s < 4; ++s) {
            int i = tid + s * 256;
            int kk = i >> 6, cc = i & 63;
            Bs[kk][cc] = W[(k0 + kk) * N + col0 + cc];
        }
        __syncthreads();
#pragma unroll
        for (int kk = 0; kk < 16; ++kk) {
            float a[4], b[4];
#pragma unroll
            for (int u = 0; u < 4; ++u) a[u] = As[kk][tr * 4 + u];
#pragma unroll
            for (int u = 0; u < 4; ++u) b[u] = Bs[kk][tc * 4 + u];
#pragma unroll
            for (int i = 0; i < 4; ++i)
#pragma unroll
                for (int j = 0; j < 4; ++j) acc[i][j] += a[i] * b[j];
        }
        __syncthreads();
    }

#pragma unroll
    for (int i = 0; i < 4; ++i) {
        int r = row0 + tr * 4 + i;
#pragma unroll
        for (int j = 0; j < 4; ++j) {
            int c = col0 + tc * 4 + j;
            float v = acc[i][j];
            if (epi == 1) v = tanhf(v);
            else if (epi == 2) v = sigf(v);
            out[(size_t)r * N + c] = v;
        }
    }
}

// ---------------------------------------------------------------------------
// mixcast: xr/xk/xv = bf16( x + (shift(x)-x)*mix )
// ---------------------------------------------------------------------------
__global__ __launch_bounds__(256) void mixcast_kernel(
    const float* __restrict__ x, const float* __restrict__ x_r,
    const float* __restrict__ x_k, const float* __restrict__ x_v,
    unsigned short* __restrict__ xr, unsigned short* __restrict__ xk,
    unsigned short* __restrict__ xv)
{
    const int row = blockIdx.x;
    const int c0 = threadIdx.x * 4;
    const size_t o = (size_t)row * Cc;
    float4 xc = *(const float4*)(x + o + c0);
    float4 xp;
    if (row & (Tt - 1)) xp = *(const float4*)(x + o - Cc + c0);
    else { xp.x = xp.y = xp.z = xp.w = 0.f; }
    float4 mr = *(const float4*)(x_r + c0);
    float4 mk = *(const float4*)(x_k + c0);
    float4 mv = *(const float4*)(x_v + c0);
    const float* xcf = (const float*)&xc; const float* xpf = (const float*)&xp;
    const float* mrf = (const float*)&mr; const float* mkf = (const float*)&mk;
    const float* mvf = (const float*)&mv;
    ushort4 r4, k4, v4;
    unsigned short* rp = (unsigned short*)&r4;
    unsigned short* kp = (unsigned short*)&k4;
    unsigned short* vp = (unsigned short*)&v4;
#pragma unroll
    for (int j = 0; j < 4; ++j) {
        float xx = xpf[j] - xcf[j];
        rp[j] = f2bf(xcf[j] + xx * mrf[j]);
        kp[j] = f2bf(xcf[j] + xx * mkf[j]);
        vp[j] = f2bf(xcf[j] + xx * mvf[j]);
    }
    *(ushort4*)(xr + o + c0) = r4;
    *(ushort4*)(xk + o + c0) = k4;
    *(ushort4*)(xv + o + c0) = v4;
}

// ---------------------------------------------------------------------------
// transpose+cast: WT[n][k] = bf16(W[k][n])
// ---------------------------------------------------------------------------
__global__ __launch_bounds__(256) void transpose_cast(
    const float* __restrict__ W, unsigned short* __restrict__ WT)
{
    __shared__ unsigned short tile[64][68];
    const int n0 = blockIdx.x * 64, k0 = blockIdx.y * 64;
    const int tid = threadIdx.x;
    const int tr = tid >> 4, tc4 = (tid & 15) * 4;
#pragma unroll
    for (int s = 0; s < 4; ++s) {
        int kk = tr + s * 16;
        float4 w4 = *(const float4*)(W + (size_t)(k0 + kk) * Cc + n0 + tc4);
        tile[kk][tc4 + 0] = f2bf(w4.x);
        tile[kk][tc4 + 1] = f2bf(w4.y);
        tile[kk][tc4 + 2] = f2bf(w4.z);
        tile[kk][tc4 + 3] = f2bf(w4.w);
    }
    __syncthreads();
#pragma unroll
    for (int s = 0; s < 4; ++s) {
        int nn = tr + s * 16;
        ushort4 o4;
        o4.x = tile[tc4 + 0][nn];
        o4.y = tile[tc4 + 1][nn];
        o4.z = tile[tc4 + 2][nn];
        o4.w = tile[tc4 + 3][nn];
        *(ushort4*)(WT + (size_t)(n0 + nn) * Cc + k0 + tc4) = o4;
    }
}

// ---------------------------------------------------------------------------
// bf16 MFMA GEMM: out[M,N] = A[M,K](bf16) @ WT[N][K](bf16)
// ---------------------------------------------------------------------------
__global__ __launch_bounds__(256) void gemm_bf16(
    const unsigned short* __restrict__ A, const unsigned short* __restrict__ WT,
    float* __restrict__ out, int M, int N, int K)
{
    __shared__ __attribute__((aligned(16))) unsigned short As[128][40];
    __shared__ __attribute__((aligned(16))) unsigned short Bs[128][40];
    const int row0 = blockIdx.y * 128;
    const int col0 = blockIdx.x * 128;
    const int tid = threadIdx.x;
    const int wave = tid >> 6, lane = tid & 63;
    const int wr = wave >> 1, wc = wave & 1;
    const int lr = lane & 15, lk = lane >> 4;

    f32x4 acc[4][4];
#pragma unroll
    for (int m = 0; m < 4; ++m)
#pragma unroll
        for (int n = 0; n < 4; ++n)
#pragma unroll
            for (int r = 0; r < 4; ++r) acc[m][n][r] = 0.f;

    const int sr = tid >> 2;
    const int sc = (tid & 3) * 8;

    for (int k0 = 0; k0 < K; k0 += 32) {
        uint4 a0v = *(const uint4*)(A  + (size_t)(row0 + sr) * K + k0 + sc);
        uint4 a1v = *(const uint4*)(A  + (size_t)(row0 + 64 + sr) * K + k0 + sc);
        uint4 b0v = *(const uint4*)(WT + (size_t)(col0 + sr) * K + k0 + sc);
        uint4 b1v = *(const uint4*)(WT + (size_t)(col0 + 64 + sr) * K + k0 + sc);
        *(uint4*)&As[sr][sc]      = a0v;
        *(uint4*)&As[64 + sr][sc] = a1v;
        *(uint4*)&Bs[sr][sc]      = b0v;
        *(uint4*)&Bs[64 + sr][sc] = b1v;
        __syncthreads();
        bf16x8 af[4], bff[4];
#pragma unroll
        for (int m = 0; m < 4; ++m)
            af[m] = *(const bf16x8*)&As[wr * 64 + m * 16 + lr][lk * 8];
#pragma unroll
        for (int n = 0; n < 4; ++n)
            bff[n] = *(const bf16x8*)&Bs[wc * 64 + n * 16 + lr][lk * 8];
#pragma unroll
        for (int m = 0; m < 4; ++m)
#pragma unroll
            for (int n = 0; n < 4; ++n)
                acc[m][n] = __builtin_amdgcn_mfma_f32_16x16x32_bf16(af[m], bff[n], acc[m][n], 0, 0, 0);
        __syncthreads();
    }

#pragma unroll
    for (int m = 0; m < 4; ++m)
#pragma unroll
        for (int n = 0; n < 4; ++n) {
            int col = col0 + wc * 64 + n * 16 + lr;
#pragma unroll
            for (int r = 0; r < 4; ++r) {
                int row = row0 + wr * 64 + m * 16 + lk * 4 + r;
                out[(size_t)row * N + col] = acc[m][n][r];
            }
        }
}

// ---------------------------------------------------------------------------
// prep_k
// ---------------------------------------------------------------------------
__global__ __launch_bounds__(256) void prep_k_kernel(
    const float* kraw, const float* __restrict__ a,
    const float* __restrict__ k_k, const float* __restrict__ k_a,
    float* kout, float* __restrict__ aaout, float* __restrict__ bbout)
{
    const int row = blockIdx.x;
    const int tid = threadIdx.x;
    const int c0 = tid * 4;
    const size_t o = (size_t)row * Cc;

    float4 kr = *(const float4*)(kraw + o + c0);
    float4 kkw = *(const float4*)(k_k + c0);
    float4 av = *(const float4*)(a + o + c0);
    float4 kaw = *(const float4*)(k_a + c0);

    float kk[4] = { kr.x * kkw.x, kr.y * kkw.y, kr.z * kkw.z, kr.w * kkw.w };
    float ssq = kk[0]*kk[0] + kk[1]*kk[1] + kk[2]*kk[2] + kk[3]*kk[3];
    ssq += __shfl_xor(ssq, 1);
    ssq += __shfl_xor(ssq, 2);
    ssq += __shfl_xor(ssq, 4);
    ssq += __shfl_xor(ssq, 8);
    float inv = 1.f / fmaxf(sqrtf(ssq), 1e-12f);

    float krr[4] = { kr.x, kr.y, kr.z, kr.w };
    float av4[4] = { av.x, av.y, av.z, av.w };
    float ka4[4] = { kaw.x, kaw.y, kaw.z, kaw.w };
    float4 aa4, bb4, kf4;
    float* aap = (float*)&aa4; float* bbp = (float*)&bb4; float* kfp = (float*)&kf4;
#pragma unroll
    for (int j = 0; j < 4; ++j) {
        float kkn = kk[j] * inv;
        aap[j] = -kkn;
        bbp[j] = kkn * av4[j];
        kfp[j] = krr[j] * (1.f + (av4[j] - 1.f) * ka4[j]);
    }
    *(float4*)(aaout + o + c0) = aa4;
    *(float4*)(bbout + o + c0) = bb4;
    *(float4*)(kout + o + c0) = kf4;
}

// ---------------------------------------------------------------------------
// WKV chunked, phase 1 (register-blocked, DPP reductions).
// Emits TLt[j][p] = T[p][j] and ZLt[j][s] = Z[s][j] (transposed for chunk2's
// MFMA B-fragments); Rho[t][p] unchanged.
// ---------------------------------------------------------------------------
__global__ __launch_bounds__(128, 1) void wkv_chunk1(
    const float* __restrict__ rb, const float* __restrict__ wdb,
    const float* __restrict__ kb, const float* __restrict__ vb,
    const float* __restrict__ aab, const float* __restrict__ bbb,
    float* __restrict__ yb,
    unsigned short* __restrict__ TLt,  // [blk][j=64][p=64]
    unsigned short* __restrict__ Rho,  // [blk][t=32][p=64]
    unsigned short* __restrict__ ZLt)  // [blk][j=64][s=32]
{
    __shared__ float st[CL * STRD];    // [s][arr][64]  0=a 1=w 2=b 3=k 4=r 5=v
    __shared__ float A_l[CL][CL + 1];  // alpha[t][s]
    const int blk = blockIdx.x;
    const int bh = blk >> 5;           // / NCH
    const int c  = blk & (NCH - 1);
    const int b = bh >> 4, h = bh & 15;
    const size_t base = (size_t)b * Tt * Cc + h * HSs + (size_t)c * CL * Cc;
    const int tid = threadIdx.x;

    // ---- stage chunk inputs ----
    {
        const float* srcs[6] = { aab, wdb, bbb, kb, rb, vb };
#pragma unroll
        for (int arr = 0; arr < 6; ++arr) {
            const float* g = srcs[arr];
#pragma unroll
            for (int e = 0; e < 4; ++e) {
                int idx = tid + e * 128;          // 0..511
                int s = idx >> 4, jq = (idx & 15) * 4;
                *(float4*)&st[s * STRD + arr * 64 + jq] =
                    *(const float4*)(g + base + (size_t)s * Cc + jq);
            }
        }
    }
    __syncthreads();

    const int wv = tid >> 6, lane = tid & 63;
    if (wv == 0) {
        // ---- B-task: 4 rows x 16 cols per thread ----
        const int rq = lane >> 2, jc = lane & 3;
        const int i0 = rq * 4, j0 = jc * 16;
        float T[4][16];
#pragma unroll
        for (int rr = 0; rr < 4; ++rr)
#pragma unroll
            for (int cc = 0; cc < 16; ++cc)
                T[rr][cc] = (i0 + rr == j0 + cc) ? 1.f : 0.f;
        const size_t rhob = (size_t)blk * (CL * 64);

        for (int t = 0; t < CL; ++t) {
            const float* sp = st + t * STRD;
            float a[16], w[16], bv[16], r[16];
#pragma unroll
            for (int q = 0; q < 4; ++q) {
                *(float4*)&a[q * 4]  = *(const float4*)(sp + 0 * 64 + j0 + q * 4);
                *(float4*)&w[q * 4]  = *(const float4*)(sp + 1 * 64 + j0 + q * 4);
                *(float4*)&bv[q * 4] = *(const float4*)(sp + 2 * 64 + j0 + q * 4);
                *(float4*)&r[q * 4]  = *(const float4*)(sp + 4 * 64 + j0 + q * 4);
            }
            float ta[4];
#pragma unroll
            for (int rr = 0; rr < 4; ++rr) {
                float s0 = T[rr][0] * a[0];
#pragma unroll
                for (int cc = 1; cc < 16; ++cc) s0 = fmaf(T[rr][cc], a[cc], s0);
                ta[rr] = s0;
            }
#pragma unroll
            for (int rr = 0; rr < 4; ++rr) {
                ta[rr] = dpp_add_xor1(ta[rr]);
                ta[rr] = dpp_add_xor2(ta[rr]);
            }
            float rp[4] = { 0.f, 0.f, 0.f, 0.f };
#pragma unroll
            for (int rr = 0; rr < 4; ++rr) {
#pragma unroll
                for (int cc = 0; cc < 16; ++cc) {
                    T[rr][cc] = fmaf(T[rr][cc], w[cc], ta[rr] * bv[cc]);
                    rp[rr] = fmaf(T[rr][cc], r[cc], rp[rr]);
                }
            }
#pragma unroll
            for (int rr = 0; rr < 4; ++rr) {
                rp[rr] = dpp_add_xor1(rp[rr]);
                rp[rr] = dpp_add_xor2(rp[rr]);
            }
            if (jc == 0) {
                ushort4 o4;
                o4.x = f2bf(rp[0]); o4.y = f2bf(rp[1]);
                o4.z = f2bf(rp[2]); o4.w = f2bf(rp[3]);
                *(ushort4*)(Rho + rhob + t * 64 + i0) = o4;
            }
        }
        // final T -> TLt TRANSPOSED: TLt[j][p] = T[p][j]; thread owns rows
        // i0..i0+3 (=p), cols j0..j0+15 (=j)
        const size_t tlb = (size_t)blk * 4096;
#pragma unroll
        for (int cc = 0; cc < 16; ++cc) {
            ushort4 o4;
            o4.x = f2bf(T[0][cc]); o4.y = f2bf(T[1][cc]);
            o4.z = f2bf(T[2][cc]); o4.w = f2bf(T[3][cc]);
            *(ushort4*)(TLt + tlb + (size_t)(j0 + cc) * 64 + i0) = o4;
        }
    } else {
        // ---- C-task ----
        const int s = lane >> 1, cc = lane & 1, j0 = cc * 32;
        float z[32];
#pragma unroll
        for (int u = 0; u < 32; ++u) z[u] = 0.f;

        for (int t = 0; t < CL; ++t) {
            const float* sp = st + t * STRD;
            float za = 0.f;
#pragma unroll
            for (int q = 0; q < 8; ++q) {
                float4 a4 = *(const float4*)(sp + 0 * 64 + j0 + q * 4);
                za += z[q*4+0]*a4.x + z[q*4+1]*a4.y + z[q*4+2]*a4.z + z[q*4+3]*a4.w;
            }
            za = dpp_add_xor1(za);
#pragma unroll
            for (int q = 0; q < 8; ++q) {
                float4 w4 = *(const float4*)(sp + 1 * 64 + j0 + q * 4);
                float4 b4 = *(const float4*)(sp + 2 * 64 + j0 + q * 4);
                z[q*4+0] = fmaf(z[q*4+0], w4.x, za * b4.x);
                z[q*4+1] = fmaf(z[q*4+1], w4.y, za * b4.y);
                z[q*4+2] = fmaf(z[q*4+2], w4.z, za * b4.z);
                z[q*4+3] = fmaf(z[q*4+3], w4.w, za * b4.w);
            }
            if (s == t) {
#pragma unroll
                for (int q = 0; q < 8; ++q) {
                    float4 k4 = *(const float4*)(sp + 3 * 64 + j0 + q * 4);
                    z[q*4+0] = k4.x; z[q*4+1] = k4.y; z[q*4+2] = k4.z; z[q*4+3] = k4.w;
                }
            }
            float al = 0.f;
#pragma unroll
            for (int q = 0; q < 8; ++q) {
                float4 r4 = *(const float4*)(sp + 4 * 64 + j0 + q * 4);
                al += z[q*4+0]*r4.x + z[q*4+1]*r4.y + z[q*4+2]*r4.z + z[q*4+3]*r4.w;
            }
            al = dpp_add_xor1(al);
            if (cc == 0) A_l[t][s] = al;
        }
        // final Z -> ZLt TRANSPOSED: ZLt[j][s] = Z[s][j]
        const size_t zlb = (size_t)blk * (CL * 64);
#pragma unroll
        for (int u = 0; u < 32; ++u)
            ZLt[zlb + (size_t)(j0 + u) * 32 + s] = f2bf(z[u]);
    }
    __syncthreads();

    // ---- y_intra = A_lower * V ----
    {
        const int t = tid >> 2, jq = (tid & 3) * 16;
        float y[16];
#pragma unroll
        for (int e = 0; e < 16; ++e) y[e] = 0.f;
        for (int s = 0; s <= t; ++s) {
            float al = A_l[t][s];
            const float* vv = st + s * STRD + 5 * 64 + jq;
#pragma unroll
            for (int q = 0; q < 4; ++q) {
                float4 v4 = *(const float4*)(vv + q * 4);
                y[q*4+0] = fmaf(al, v4.x, y[q*4+0]);
                y[q*4+1] = fmaf(al, v4.y, y[q*4+1]);
                y[q*4+2] = fmaf(al, v4.z, y[q*4+2]);
                y[q*4+3] = fmaf(al, v4.w, y[q*4+3]);
            }
        }
#pragma unroll
        for (int q = 0; q < 4; ++q) {
            float4 o4 = { y[q*4+0], y[q*4+1], y[q*4+2], y[q*4+3] };
            *(float4*)(yb + base + (size_t)t * Cc + jq + q * 4) = o4;
        }
    }
}

// ---------------------------------------------------------------------------
// WKV chunked, phase 2 — MFMA version. Grid = 64 blocks (one per bh), 256 thr.
// Wave w owns S rows [16w,16w+16) as 4 C-layout f32x4 accumulators (S[i][p],
// p-tile n: col = n*16+lr, row = 16w+lk*4+r). Per chunk:
//   y[t][i] += (S0 · rho^T)[i][t]        (C-in loaded from yb, 4 MFMAs)
//   S <- S·T + V^T·Z                     (T,Z via transposed B-frags, 12 MFMAs)
// S->bf16 A-frags via LDS round-trip. Next chunk's T/Z/rho/V prefetched to regs.
// ---------------------------------------------------------------------------
__global__ __launch_bounds__(256, 1) void wkv_chunk2(
    const float* __restrict__ vb, const unsigned short* __restrict__ TLt,
    const unsigned short* __restrict__ Rho, const unsigned short* __restrict__ ZLt,
    float* __restrict__ yb)
{
    __shared__ unsigned short Sl[64 * 72];    // [i][p]
    __shared__ unsigned short Ttl[64 * 72];   // [j][p]
    __shared__ unsigned short Ztl[64 * 40];   // [j][s]
    __shared__ unsigned short Rl[32 * 72];    // [t][p]
    __shared__ unsigned short Vtl[64 * 40];   // [i][s]
    const int bh = blockIdx.x;
    const size_t vbase = (size_t)(bh >> 4) * Tt * Cc + (bh & 15) * HSs;
    const int tid = threadIdx.x;
    const int wv = tid >> 6, lane = tid & 63;
    const int lr = lane & 15, lk = lane >> 4;
    const int i0w = wv * 16;

    f32x4 S[4];
#pragma unroll
    for (int n = 0; n < 4; ++n)
#pragma unroll
        for (int r = 0; r < 4; ++r) S[n][r] = 0.f;

    // prefetch registers
    uint4 pT0, pT1, pZ, pR;
    float4 pV0, pV1;
    const int vs = tid >> 3, vi0 = (tid & 7) * 8;   // V transpose mapping

#define C2_LOAD(c_) do { \
    size_t cb_ = (size_t)(bh * NCH + (c_)); \
    const uint4* tp_ = (const uint4*)(TLt + cb_ * 4096); \
    pT0 = tp_[tid * 2]; pT1 = tp_[tid * 2 + 1]; \
    pZ = ((const uint4*)(ZLt + cb_ * 2048))[tid]; \
    pR = ((const uint4*)(Rho + cb_ * 2048))[tid]; \
    const float* vp_ = vb + vbase + (size_t)((c_) * CL + vs) * Cc + vi0; \
    pV0 = *(const float4*)vp_; pV1 = *(const float4*)(vp_ + 4); \
} while (0)

#define C2_STORE() do { \
    *(uint4*)&Ttl[(tid >> 2) * 72 + (tid & 3) * 16] = pT0; \
    *(uint4*)&Ttl[(tid >> 2) * 72 + (tid & 3) * 16 + 8] = pT1; \
    *(uint4*)&Ztl[(tid >> 2) * 40 + (tid & 3) * 8] = pZ; \
    *(uint4*)&Rl[(tid >> 3) * 72 + (tid & 7) * 8] = pR; \
    const float* pv_ = (const float*)&pV0; \
    Vtl[(vi0 + 0) * 40 + vs] = f2bf(pv_[0]); \
    Vtl[(vi0 + 1) * 40 + vs] = f2bf(pv_[1]); \
    Vtl[(vi0 + 2) * 40 + vs] = f2bf(pv_[2]); \
    Vtl[(vi0 + 3) * 40 + vs] = f2bf(pv_[3]); \
    const float* pw_ = (const float*)&pV1; \
    Vtl[(vi0 + 4) * 40 + vs] = f2bf(pw_[0]); \
    Vtl[(vi0 + 5) * 40 + vs] = f2bf(pw_[1]); \
    Vtl[(vi0 + 6) * 40 + vs] = f2bf(pw_[2]); \
    Vtl[(vi0 + 7) * 40 + vs] = f2bf(pw_[3]); \
} while (0)

    C2_LOAD(0);
    for (int c = 0; c < NCH; ++c) {
        __syncthreads();   // prior compute done; LDS writable
        // S -> bf16 Sl[i][p]
#pragma unroll
        for (int n = 0; n < 4; ++n) {
#pragma unroll
            for (int r = 0; r < 4; ++r)
                Sl[(i0w + lk * 4 + r) * 72 + n * 16 + lr] = f2bf(S[n][r]);
        }
        C2_STORE();
        if (c + 1 < NCH) C2_LOAD(c + 1);
        __syncthreads();

        // A-frags of S0 (rows i0w+lr, k-contig)
        bf16x8 sA0 = *(const bf16x8*)&Sl[(i0w + lr) * 72 + lk * 8];
        bf16x8 sA1 = *(const bf16x8*)&Sl[(i0w + lr) * 72 + 32 + lk * 8];

        // y[t][i] += S0 · rho^T  (C-in from yb)
#pragma unroll
        for (int nt = 0; nt < 2; ++nt) {
            int t = nt * 16 + lr;
            float* yp = yb + vbase + (size_t)(c * CL + t) * Cc + i0w + lk * 4;
            f32x4 yc = *(f32x4*)yp;
            bf16x8 b0 = *(const bf16x8*)&Rl[t * 72 + lk * 8];
            bf16x8 b1 = *(const bf16x8*)&Rl[t * 72 + 32 + lk * 8];
            yc = __builtin_amdgcn_mfma_f32_16x16x32_bf16(sA0, b0, yc, 0, 0, 0);
            yc = __builtin_amdgcn_mfma_f32_16x16x32_bf16(sA1, b1, yc, 0, 0, 0);
            *(f32x4*)yp = yc;
        }

        // S <- S·T + V^T·Z
        bf16x8 vA = *(const bf16x8*)&Vtl[(i0w + lr) * 40 + lk * 8];
#pragma unroll
        for (int n = 0; n < 4; ++n) {
            int j = n * 16 + lr;
            bf16x8 t0 = *(const bf16x8*)&Ttl[j * 72 + lk * 8];
            bf16x8 t1 = *(const bf16x8*)&Ttl[j * 72 + 32 + lk * 8];
            bf16x8 z0 = *(const bf16x8*)&Ztl[j * 40 + lk * 8];
            f32x4 acc = { 0.f, 0.f, 0.f, 0.f };
            acc = __builtin_amdgcn_mfma_f32_16x16x32_bf16(sA0, t0, acc, 0, 0, 0);
            acc = __builtin_amdgcn_mfma_f32_16x16x32_bf16(sA1, t1, acc, 0, 0, 0);
            acc = __builtin_amdgcn_mfma_f32_16x16x32_bf16(vA, z0, acc, 0, 0, 0);
            S[n] = acc;
        }
    }
#undef C2_LOAD
#undef C2_STORE
}

// ---------------------------------------------------------------------------
// GroupNorm + r*k*r_k bonus + gate
// ---------------------------------------------------------------------------
__global__ __launch_bounds__(256) void gn_rt_kernel(
    const float* __restrict__ yb, const float* __restrict__ rb,
    const float* __restrict__ kb, const float* __restrict__ vb,
    const unsigned short* __restrict__ gb, const float* __restrict__ r_k,
    const float* __restrict__ ln_w, const float* __restrict__ ln_b,
    unsigned short* __restrict__ zb)
{
    const int row = blockIdx.x;
    const int tid = threadIdx.x;
    const int c0 = tid * 4;
    const int hd = tid >> 4;
    const int n0 = c0 & 63;
    const size_t o = (size_t)row * Cc;

    float4 y4 = *(const float4*)(yb + o + c0);
    float4 r4 = *(const float4*)(rb + o + c0);
    float4 k4 = *(const float4*)(kb + o + c0);
    float4 v4 = *(const float4*)(vb + o + c0);
    ushort4 g4u = *(const ushort4*)(gb + o + c0);
    float4 rk4 = *(const float4*)(r_k + hd * 64 + n0);

    float yv[4] = { y4.x, y4.y, y4.z, y4.w };
    float rv[4] = { r4.x, r4.y, r4.z, r4.w };
    float kv[4] = { k4.x, k4.y, k4.z, k4.w };
    float vv[4] = { v4.x, v4.y, v4.z, v4.w };
    float gv[4] = { bf2f(g4u.x), bf2f(g4u.y), bf2f(g4u.z), bf2f(g4u.w) };
    float rkv[4] = { rk4.x, rk4.y, rk4.z, rk4.w };

    float sum = 0.f, ssq = 0.f, dot = 0.f;
#pragma unroll
    for (int j = 0; j < 4; ++j) {
        sum += yv[j];
        ssq += yv[j] * yv[j];
        dot += rv[j] * kv[j] * rkv[j];
    }
#pragma unroll
    for (int m = 1; m <= 8; m <<= 1) {
        sum += __shfl_xor(sum, m);
        ssq += __shfl_xor(ssq, m);
        dot += __shfl_xor(dot, m);
    }
    const float mu = sum * (1.f / 64.f);
    const float var = ssq * (1.f / 64.f) - mu * mu;
    const float inv = rsqrtf(var + 0.00064f);

    ushort4 z4;
    unsigned short* zp = (unsigned short*)&z4;
#pragma unroll
    for (int j = 0; j < 4; ++j) {
        int c = c0 + j;
        float yg = (yv[j] - mu) * inv * ln_w[c] + ln_b[c];
        yg += dot * vv[j];
        zp[j] = f2bf(yg * gv[j]);
    }
    *(ushort4*)(zb + o + c0) = z4;
}

// ---------------------------------------------------------------------------

extern "C" void kernel_launch(void* const* d_in, const int* in_sizes, int n_in,
                              void* d_out, int out_size, void* d_ws, size_t ws_size,
                              hipStream_t stream)
{
    const float* x   = (const float*)d_in[0];
    const float* x_r = (const float*)d_in[1];
    const float* x_w = (const float*)d_in[2];
    const float* x_k = (const float*)d_in[3];
    const float* x_v = (const float*)d_in[4];
    const float* x_a = (const float*)d_in[5];
    const float* x_g = (const float*)d_in[6];
    const float* w0  = (const float*)d_in[7];
    const float* w1  = (const float*)d_in[8];
    const float* w2  = (const float*)d_in[9];
    const float* a0  = (const float*)d_in[10];
    const float* a1  = (const float*)d_in[11];
    const float* a2  = (const float*)d_in[12];
    // v0,v1,v2 (13..15): forward no-op on first-layer call
    const float* g1  = (const float*)d_in[16];
    const float* g2  = (const float*)d_in[17];
    const float* k_k = (const float*)d_in[18];
    const float* k_a = (const float*)d_in[19];
    const float* r_k = (const float*)d_in[20];
    const float* Wr  = (const float*)d_in[21];
    const float* Wk  = (const float*)d_in[22];
    const float* Wv  = (const float*)d_in[23];
    const float* Wo  = (const float*)d_in[24];
    const float* ln_w = (const float*)d_in[25];
    const float* ln_b = (const float*)d_in[26];

    float* ws = (float*)d_ws;
    const size_t S = (size_t)Bsz * Tt * Cc;       // 4,194,304 floats (16 MiB)
    const int M = Bsz * Tt;                        // 4096

    float* rb  = ws + 0 * S;
    float* wdb = ws + 1 * S;
    unsigned short* WoT = (unsigned short*)(ws + 1 * S);   // after chunk1 (wdb dead)
    float* kb  = ws + 2 * S;
    float* vb  = ws + 3 * S;
    float* aab = ws + 4 * S;
    unsigned short* zb = (unsigned short*)(ws + 4 * S);    // after chunk1 (aab dead)
    float* bbb = ws + 5 * S;
    float* yb  = ws + 6 * S;
    float* hw  = yb;                    // dead before wkv writes yb
    float* ha  = yb + 262144;
    float* hg  = yb + 524288;
    // slot7: xr,xk (bf16) -> ab (f32) -> TLt (bf16, 16 MiB exactly)
    unsigned short* xr = (unsigned short*)(ws + 7 * S);
    unsigned short* xk = xr + S;
    float* ab  = ws + 7 * S;
    unsigned short* TLt = (unsigned short*)(ws + 7 * S);
    // slot8: xv (bf16, 8MiB) + WrT/WkT/WvT -> gb (bf16, 8MiB) + Rho (bf16, 8MiB)
    unsigned short* xv = (unsigned short*)(ws + 8 * S);
    unsigned short* WrT = xv + S;
    unsigned short* WkT = WrT + 1048576;
    unsigned short* WvT = WkT + 1048576;
    unsigned short* gb  = (unsigned short*)(ws + 8 * S);
    unsigned short* Rho = gb + S;                          // second 8 MiB of slot8
    // slot9: ZLt (bf16, 8 MiB)
    unsigned short* ZLt = (unsigned short*)(ws + 9 * S);

    dim3 blk(256);

    // mixed bf16 inputs + transposed bf16 weights
    mixcast_kernel<<<dim3(M), blk, 0, stream>>>(x, x_r, x_k, x_v, xr, xk, xv);
    transpose_cast<<<dim3(16, 16), blk, 0, stream>>>(Wr, WrT);
    transpose_cast<<<dim3(16, 16), blk, 0, stream>>>(Wk, WkT);
    transpose_cast<<<dim3(16, 16), blk, 0, stream>>>(Wv, WvT);

    // fused first-stage low-rank
    lowrank_fused<<<dim3(4, M / 64), blk, 0, stream>>>(x, x_w, x_a, x_g, w1, a1, g1, hw, ha, hg);

    // big projections: bf16 MFMA
    gemm_bf16<<<dim3(8, 32), blk, 0, stream>>>(xr, WrT, rb, M, Cc, Cc);
    gemm_bf16<<<dim3(8, 32), blk, 0, stream>>>(xk, WkT, kb, M, Cc, Cc);
    gemm_bf16<<<dim3(8, 32), blk, 0, stream>>>(xv, WvT, vb, M, Cc, Cc);

    // second-stage low-rank (fp32)
    gemm_f32<<<dim3(16, M / 64), blk, 0, stream>>>(hw, w2, wdb, nullptr, w0, M, Cc, 64, 3, 0);
    gemm_f32<<<dim3(16, M / 64), blk, 0, stream>>>(ha, a2, ab, nullptr, a0, M, Cc, 64, 2, 0);
    gemm_f32<<<dim3(16, M / 64), blk, 0, stream>>>(hg, g2, (float*)gb, nullptr, nullptr, M, Cc, 128, 0, 1);

    // k / kk / aa / bb
    prep_k_kernel<<<dim3(M), blk, 0, stream>>>(kb, ab, k_k, k_a, kb, aab, bbb);

    // chunked recurrence
    wkv_chunk1<<<dim3(64 * NCH), dim3(128), 0, stream>>>(rb, wdb, kb, vb, aab, bbb, yb, TLt, Rho, ZLt);
    wkv_chunk2<<<dim3(64), blk, 0, stream>>>(vb, TLt, Rho, ZLt, yb);

    // Wo transpose (into dead wdb slot), groupnorm+bonus+gate -> z (bf16)
    transpose_cast<<<dim3(16, 16), blk, 0, stream>>>(Wo, WoT);
    gn_rt_kernel<<<dim3(M), blk, 0, stream>>>(yb, rb, kb, vb, gb, r_k, ln_w, ln_b, zb);

    // output projection: bf16 MFMA
    gemm_bf16<<<dim3(8, 32), blk, 0, stream>>>(zb, WoT, (float*)d_out, M, Cc, Cc);
}

// Round 9
// 491.872 us; speedup vs baseline: 5.2838x; 1.0554x over previous
//
#include <hip/hip_runtime.h>
#include <math.h>

#define Bsz 4
#define Tt  1024
#define Cc  1024
#define Hh  16
#define HSs 64
#define CL  32            // wkv chunk length
#define NCH (Tt / CL)     // 32 chunks
#define STRD 324          // padded step stride in floats (324 % 32 = 4); 5 arrays

typedef __attribute__((ext_vector_type(8))) short bf16x8;
typedef __attribute__((ext_vector_type(4))) float f32x4;

__device__ __forceinline__ float sigf(float x) { return 1.f / (1.f + expf(-x)); }

__device__ __forceinline__ unsigned short f2bf(float f) {
    unsigned int u = __float_as_uint(f);
    u = u + 0x7fffu + ((u >> 16) & 1u);   // RNE
    return (unsigned short)(u >> 16);
}
__device__ __forceinline__ float bf2f(unsigned short u) {
    return __uint_as_float(((unsigned int)u) << 16);
}
__device__ __forceinline__ float dpp_add_xor1(float x) {
    int y = __builtin_amdgcn_mov_dpp(__float_as_int(x), 0xB1, 0xF, 0xF, true);
    return x + __int_as_float(y);
}
__device__ __forceinline__ float dpp_add_xor2(float x) {
    int y = __builtin_amdgcn_mov_dpp(__float_as_int(x), 0x4E, 0xF, 0xF, true);
    return x + __int_as_float(y);
}

// ---------------------------------------------------------------------------
// mixcast: xr/xk/xv = bf16( x + (shift(x)-x)*mix )
// ---------------------------------------------------------------------------
__global__ __launch_bounds__(256) void mixcast_kernel(
    const float* __restrict__ x, const float* __restrict__ x_r,
    const float* __restrict__ x_k, const float* __restrict__ x_v,
    unsigned short* __restrict__ xr, unsigned short* __restrict__ xk,
    unsigned short* __restrict__ xv)
{
    const int row = blockIdx.x;
    const int c0 = threadIdx.x * 4;
    const size_t o = (size_t)row * Cc;
    float4 xc = *(const float4*)(x + o + c0);
    float4 xp;
    if (row & (Tt - 1)) xp = *(const float4*)(x + o - Cc + c0);
    else { xp.x = xp.y = xp.z = xp.w = 0.f; }
    float4 mr = *(const float4*)(x_r + c0);
    float4 mk = *(const float4*)(x_k + c0);
    float4 mv = *(const float4*)(x_v + c0);
    const float* xcf = (const float*)&xc; const float* xpf = (const float*)&xp;
    const float* mrf = (const float*)&mr; const float* mkf = (const float*)&mk;
    const float* mvf = (const float*)&mv;
    ushort4 r4, k4, v4;
    unsigned short* rp = (unsigned short*)&r4;
    unsigned short* kp = (unsigned short*)&k4;
    unsigned short* vp = (unsigned short*)&v4;
#pragma unroll
    for (int j = 0; j < 4; ++j) {
        float xx = xpf[j] - xcf[j];
        rp[j] = f2bf(xcf[j] + xx * mrf[j]);
        kp[j] = f2bf(xcf[j] + xx * mkf[j]);
        vp[j] = f2bf(xcf[j] + xx * mvf[j]);
    }
    *(ushort4*)(xr + o + c0) = r4;
    *(ushort4*)(xk + o + c0) = k4;
    *(ushort4*)(xv + o + c0) = v4;
}

// ---------------------------------------------------------------------------
// generic transpose+cast: WT[n][k] = bf16(W[k][n]); W is [K][N] fp32.
// grid (N/64, K/64)
// ---------------------------------------------------------------------------
__global__ __launch_bounds__(256) void transpose_cast_g(
    const float* __restrict__ W, unsigned short* __restrict__ WT, int K, int N)
{
    __shared__ unsigned short tile[64][68];
    const int n0 = blockIdx.x * 64, k0 = blockIdx.y * 64;
    const int tid = threadIdx.x;
    const int tr = tid >> 4, tc4 = (tid & 15) * 4;
#pragma unroll
    for (int s = 0; s < 4; ++s) {
        int kk = tr + s * 16;
        float4 w4 = *(const float4*)(W + (size_t)(k0 + kk) * N + n0 + tc4);
        tile[kk][tc4 + 0] = f2bf(w4.x);
        tile[kk][tc4 + 1] = f2bf(w4.y);
        tile[kk][tc4 + 2] = f2bf(w4.z);
        tile[kk][tc4 + 3] = f2bf(w4.w);
    }
    __syncthreads();
#pragma unroll
    for (int s = 0; s < 4; ++s) {
        int nn = tr + s * 16;
        ushort4 o4;
        o4.x = tile[tc4 + 0][nn];
        o4.y = tile[tc4 + 1][nn];
        o4.z = tile[tc4 + 2][nn];
        o4.w = tile[tc4 + 3][nn];
        *(ushort4*)(WT + (size_t)(n0 + nn) * K + k0 + tc4) = o4;
    }
}

// ---------------------------------------------------------------------------
// big bf16 MFMA GEMM: out[M,N] fp32 = A[M,K](bf16) @ WT[N][K](bf16), 128x128
// ---------------------------------------------------------------------------
__global__ __launch_bounds__(256) void gemm_bf16(
    const unsigned short* __restrict__ A, const unsigned short* __restrict__ WT,
    float* __restrict__ out, int M, int N, int K)
{
    __shared__ __attribute__((aligned(16))) unsigned short As[128][40];
    __shared__ __attribute__((aligned(16))) unsigned short Bs[128][40];
    const int row0 = blockIdx.y * 128;
    const int col0 = blockIdx.x * 128;
    const int tid = threadIdx.x;
    const int wave = tid >> 6, lane = tid & 63;
    const int wr = wave >> 1, wc = wave & 1;
    const int lr = lane & 15, lk = lane >> 4;

    f32x4 acc[4][4];
#pragma unroll
    for (int m = 0; m < 4; ++m)
#pragma unroll
        for (int n = 0; n < 4; ++n)
#pragma unroll
            for (int r = 0; r < 4; ++r) acc[m][n][r] = 0.f;

    const int sr = tid >> 2;
    const int sc = (tid & 3) * 8;

    for (int k0 = 0; k0 < K; k0 += 32) {
        uint4 a0v = *(const uint4*)(A  + (size_t)(row0 + sr) * K + k0 + sc);
        uint4 a1v = *(const uint4*)(A  + (size_t)(row0 + 64 + sr) * K + k0 + sc);
        uint4 b0v = *(const uint4*)(WT + (size_t)(col0 + sr) * K + k0 + sc);
        uint4 b1v = *(const uint4*)(WT + (size_t)(col0 + 64 + sr) * K + k0 + sc);
        *(uint4*)&As[sr][sc]      = a0v;
        *(uint4*)&As[64 + sr][sc] = a1v;
        *(uint4*)&Bs[sr][sc]      = b0v;
        *(uint4*)&Bs[64 + sr][sc] = b1v;
        __syncthreads();
        bf16x8 af[4], bff[4];
#pragma unroll
        for (int m = 0; m < 4; ++m)
            af[m] = *(const bf16x8*)&As[wr * 64 + m * 16 + lr][lk * 8];
#pragma unroll
        for (int n = 0; n < 4; ++n)
            bff[n] = *(const bf16x8*)&Bs[wc * 64 + n * 16 + lr][lk * 8];
#pragma unroll
        for (int m = 0; m < 4; ++m)
#pragma unroll
            for (int n = 0; n < 4; ++n)
                acc[m][n] = __builtin_amdgcn_mfma_f32_16x16x32_bf16(af[m], bff[n], acc[m][n], 0, 0, 0);
        __syncthreads();
    }

#pragma unroll
    for (int m = 0; m < 4; ++m)
#pragma unroll
        for (int n = 0; n < 4; ++n) {
            int col = col0 + wc * 64 + n * 16 + lr;
#pragma unroll
            for (int r = 0; r < 4; ++r) {
                int row = row0 + wr * 64 + m * 16 + lk * 4 + r;
                out[(size_t)row * N + col] = acc[m][n][r];
            }
        }
}

// ---------------------------------------------------------------------------
// generic bf16 MFMA GEMM (128x64 tile, BK=32): out = f(A@WT^T + bias)
// A[M][K] bf16, WT[N][K] bf16. epi: 0 none, 1 tanh, 2 sigmoid, 3 decay.
// bf16out: write bf16. grid (N/64, M/128), 256 thr (4 waves stacked in M).
// ---------------------------------------------------------------------------
__global__ __launch_bounds__(256) void gemm_bf16_g(
    const unsigned short* __restrict__ A, const unsigned short* __restrict__ WT,
    void* __restrict__ outp, const float* __restrict__ bias,
    int M, int N, int K, int epi, int bf16out)
{
    __shared__ __attribute__((aligned(16))) unsigned short As[128][40];
    __shared__ __attribute__((aligned(16))) unsigned short Bs[64][40];
    const int row0 = blockIdx.y * 128;
    const int col0 = blockIdx.x * 64;
    const int tid = threadIdx.x;
    const int wave = tid >> 6, lane = tid & 63;
    const int lr = lane & 15, lk = lane >> 4;

    f32x4 acc[2][4];
#pragma unroll
    for (int m = 0; m < 2; ++m)
#pragma unroll
        for (int n = 0; n < 4; ++n)
#pragma unroll
            for (int r = 0; r < 4; ++r) acc[m][n][r] = 0.f;

    for (int k0 = 0; k0 < K; k0 += 32) {
#pragma unroll
        for (int e = 0; e < 2; ++e) {
            int idx = tid * 2 + e;
            int ar = idx >> 2, ac = (idx & 3) * 8;
            *(uint4*)&As[ar][ac] = *(const uint4*)(A + (size_t)(row0 + ar) * K + k0 + ac);
        }
        {
            int br = tid >> 2, bc = (tid & 3) * 8;
            *(uint4*)&Bs[br][bc] = *(const uint4*)(WT + (size_t)(col0 + br) * K + k0 + bc);
        }
        __syncthreads();
        bf16x8 af[2], bff[4];
#pragma unroll
        for (int m = 0; m < 2; ++m)
            af[m] = *(const bf16x8*)&As[wave * 32 + m * 16 + lr][lk * 8];
#pragma unroll
        for (int n = 0; n < 4; ++n)
            bff[n] = *(const bf16x8*)&Bs[n * 16 + lr][lk * 8];
#pragma unroll
        for (int m = 0; m < 2; ++m)
#pragma unroll
            for (int n = 0; n < 4; ++n)
                acc[m][n] = __builtin_amdgcn_mfma_f32_16x16x32_bf16(af[m], bff[n], acc[m][n], 0, 0, 0);
        __syncthreads();
    }

#pragma unroll
    for (int m = 0; m < 2; ++m)
#pragma unroll
        for (int n = 0; n < 4; ++n) {
            int col = col0 + n * 16 + lr;
#pragma unroll
            for (int r = 0; r < 4; ++r) {
                int row = row0 + wave * 32 + m * 16 + lk * 4 + r;
                float v = acc[m][n][r];
                if (bias) v += bias[col];
                if (epi == 1) v = tanhf(v);
                else if (epi == 2) v = sigf(v);
                else if (epi == 3) v = expf(-0.60653065971263342f * sigf(v));
                if (bf16out) ((unsigned short*)outp)[(size_t)row * N + col] = f2bf(v);
                else ((float*)outp)[(size_t)row * N + col] = v;
            }
        }
}

// ---------------------------------------------------------------------------
// stage-1 low-rank MFMA with fused token-shift mix (A built from fp32 x):
// out[M][N] bf16 = f( (x + (shift(x)-x)*mix) @ WT^T ). grid (N/64, M/128).
// ---------------------------------------------------------------------------
__global__ __launch_bounds__(256) void lowrank1_mfma(
    const float* __restrict__ x, const float* __restrict__ mix,
    const unsigned short* __restrict__ WT, unsigned short* __restrict__ out,
    int N, int epi)
{
    __shared__ __attribute__((aligned(16))) unsigned short As[128][40];
    __shared__ __attribute__((aligned(16))) unsigned short Bs[64][40];
    const int row0 = blockIdx.y * 128;
    const int col0 = blockIdx.x * 64;
    const int tid = threadIdx.x;
    const int wave = tid >> 6, lane = tid & 63;
    const int lr = lane & 15, lk = lane >> 4;

    f32x4 acc[2][4];
#pragma unroll
    for (int m = 0; m < 2; ++m)
#pragma unroll
        for (int n = 0; n < 4; ++n)
#pragma unroll
            for (int r = 0; r < 4; ++r) acc[m][n][r] = 0.f;

    for (int k0 = 0; k0 < Cc; k0 += 32) {
#pragma unroll
        for (int e = 0; e < 2; ++e) {
            int idx = tid * 2 + e;
            int ar = idx >> 2, ac = (idx & 3) * 8;
            int row = row0 + ar;
            const float* xp = x + (size_t)row * Cc + k0 + ac;
            float4 c0 = *(const float4*)xp;
            float4 c1 = *(const float4*)(xp + 4);
            float4 p0, p1;
            if (row & (Tt - 1)) {
                p0 = *(const float4*)(xp - Cc);
                p1 = *(const float4*)(xp - Cc + 4);
            } else {
                p0.x = p0.y = p0.z = p0.w = 0.f;
                p1.x = p1.y = p1.z = p1.w = 0.f;
            }
            float4 m0 = *(const float4*)(mix + k0 + ac);
            float4 m1 = *(const float4*)(mix + k0 + ac + 4);
            const float* cf0 = (const float*)&c0; const float* cf1 = (const float*)&c1;
            const float* pf0 = (const float*)&p0; const float* pf1 = (const float*)&p1;
            const float* mf0 = (const float*)&m0; const float* mf1 = (const float*)&m1;
            ushort4 u0, u1;
            unsigned short* up0 = (unsigned short*)&u0;
            unsigned short* up1 = (unsigned short*)&u1;
#pragma unroll
            for (int j = 0; j < 4; ++j) {
                up0[j] = f2bf(cf0[j] + (pf0[j] - cf0[j]) * mf0[j]);
                up1[j] = f2bf(cf1[j] + (pf1[j] - cf1[j]) * mf1[j]);
            }
            *(ushort4*)&As[ar][ac] = u0;
            *(ushort4*)&As[ar][ac + 4] = u1;
        }
        {
            int br = tid >> 2, bc = (tid & 3) * 8;
            *(uint4*)&Bs[br][bc] = *(const uint4*)(WT + (size_t)(col0 + br) * Cc + k0 + bc);
        }
        __syncthreads();
        bf16x8 af[2], bff[4];
#pragma unroll
        for (int m = 0; m < 2; ++m)
            af[m] = *(const bf16x8*)&As[wave * 32 + m * 16 + lr][lk * 8];
#pragma unroll
        for (int n = 0; n < 4; ++n)
            bff[n] = *(const bf16x8*)&Bs[n * 16 + lr][lk * 8];
#pragma unroll
        for (int m = 0; m < 2; ++m)
#pragma unroll
            for (int n = 0; n < 4; ++n)
                acc[m][n] = __builtin_amdgcn_mfma_f32_16x16x32_bf16(af[m], bff[n], acc[m][n], 0, 0, 0);
        __syncthreads();
    }

#pragma unroll
    for (int m = 0; m < 2; ++m)
#pragma unroll
        for (int n = 0; n < 4; ++n) {
            int col = col0 + n * 16 + lr;
#pragma unroll
            for (int r = 0; r < 4; ++r) {
                int row = row0 + wave * 32 + m * 16 + lk * 4 + r;
                float v = acc[m][n][r];
                if (epi == 1) v = tanhf(v);
                else if (epi == 2) v = sigf(v);
                out[(size_t)row * N + col] = f2bf(v);
            }
        }
}

// ---------------------------------------------------------------------------
// prep_k
// ---------------------------------------------------------------------------
__global__ __launch_bounds__(256) void prep_k_kernel(
    const float* kraw, const float* __restrict__ a,
    const float* __restrict__ k_k, const float* __restrict__ k_a,
    float* kout, float* __restrict__ aaout, float* __restrict__ bbout)
{
    const int row = blockIdx.x;
    const int tid = threadIdx.x;
    const int c0 = tid * 4;
    const size_t o = (size_t)row * Cc;

    float4 kr = *(const float4*)(kraw + o + c0);
    float4 kkw = *(const float4*)(k_k + c0);
    float4 av = *(const float4*)(a + o + c0);
    float4 kaw = *(const float4*)(k_a + c0);

    float kk[4] = { kr.x * kkw.x, kr.y * kkw.y, kr.z * kkw.z, kr.w * kkw.w };
    float ssq = kk[0]*kk[0] + kk[1]*kk[1] + kk[2]*kk[2] + kk[3]*kk[3];
    ssq += __shfl_xor(ssq, 1);
    ssq += __shfl_xor(ssq, 2);
    ssq += __shfl_xor(ssq, 4);
    ssq += __shfl_xor(ssq, 8);
    float inv = 1.f / fmaxf(sqrtf(ssq), 1e-12f);

    float krr[4] = { kr.x, kr.y, kr.z, kr.w };
    float av4[4] = { av.x, av.y, av.z, av.w };
    float ka4[4] = { kaw.x, kaw.y, kaw.z, kaw.w };
    float4 aa4, bb4, kf4;
    float* aap = (float*)&aa4; float* bbp = (float*)&bb4; float* kfp = (float*)&kf4;
#pragma unroll
    for (int j = 0; j < 4; ++j) {
        float kkn = kk[j] * inv;
        aap[j] = -kkn;
        bbp[j] = kkn * av4[j];
        kfp[j] = krr[j] * (1.f + (av4[j] - 1.f) * ka4[j]);
    }
    *(float4*)(aaout + o + c0) = aa4;
    *(float4*)(bbout + o + c0) = bb4;
    *(float4*)(kout + o + c0) = kf4;
}

// ---------------------------------------------------------------------------
// WKV chunked, phase 1 (v3: tree reductions, k read from global, 5-array LDS).
// st arrays: 0=a 1=w 2=b 3=r 4=v
// ---------------------------------------------------------------------------
__global__ __launch_bounds__(128, 1) void wkv_chunk1(
    const float* __restrict__ rb, const float* __restrict__ wdb,
    const float* __restrict__ kb, const float* __restrict__ vb,
    const float* __restrict__ aab, const float* __restrict__ bbb,
    float* __restrict__ yb,
    unsigned short* __restrict__ TLt,  // [blk][j=64][p=64]
    unsigned short* __restrict__ Rho,  // [blk][t=32][p=64]
    unsigned short* __restrict__ ZLt)  // [blk][j=64][s=32]
{
    __shared__ float st[CL * STRD];
    __shared__ float A_l[CL][CL + 1];
    const int blk = blockIdx.x;
    const int bh = blk >> 5;
    const int c  = blk & (NCH - 1);
    const int b = bh >> 4, h = bh & 15;
    const size_t base = (size_t)b * Tt * Cc + h * HSs + (size_t)c * CL * Cc;
    const int tid = threadIdx.x;

    {
        const float* srcs[5] = { aab, wdb, bbb, rb, vb };
#pragma unroll
        for (int arr = 0; arr < 5; ++arr) {
            const float* g = srcs[arr];
#pragma unroll
            for (int e = 0; e < 4; ++e) {
                int idx = tid + e * 128;
                int s = idx >> 4, jq = (idx & 15) * 4;
                *(float4*)&st[s * STRD + arr * 64 + jq] =
                    *(const float4*)(g + base + (size_t)s * Cc + jq);
            }
        }
    }
    __syncthreads();

    const int wv = tid >> 6, lane = tid & 63;
    if (wv == 0) {
        // ---- B-task: 4 rows x 16 cols per thread ----
        const int rq = lane >> 2, jc = lane & 3;
        const int i0 = rq * 4, j0 = jc * 16;
        float T[4][16];
#pragma unroll
        for (int rr = 0; rr < 4; ++rr)
#pragma unroll
            for (int cc = 0; cc < 16; ++cc)
                T[rr][cc] = (i0 + rr == j0 + cc) ? 1.f : 0.f;
        const size_t rhob = (size_t)blk * (CL * 64);

        for (int t = 0; t < CL; ++t) {
            const float* sp = st + t * STRD;
            float a[16], w[16], bv[16], r[16];
#pragma unroll
            for (int q = 0; q < 4; ++q) {
                *(float4*)&a[q * 4]  = *(const float4*)(sp + 0 * 64 + j0 + q * 4);
                *(float4*)&w[q * 4]  = *(const float4*)(sp + 1 * 64 + j0 + q * 4);
                *(float4*)&bv[q * 4] = *(const float4*)(sp + 2 * 64 + j0 + q * 4);
                *(float4*)&r[q * 4]  = *(const float4*)(sp + 3 * 64 + j0 + q * 4);
            }
            float ta[4];
#pragma unroll
            for (int rr = 0; rr < 4; ++rr) {
                float q0 = T[rr][0] * a[0], q1 = T[rr][4] * a[4];
                float q2 = T[rr][8] * a[8], q3 = T[rr][12] * a[12];
#pragma unroll
                for (int e = 1; e < 4; ++e) {
                    q0 = fmaf(T[rr][e], a[e], q0);
                    q1 = fmaf(T[rr][4 + e], a[4 + e], q1);
                    q2 = fmaf(T[rr][8 + e], a[8 + e], q2);
                    q3 = fmaf(T[rr][12 + e], a[12 + e], q3);
                }
                ta[rr] = (q0 + q1) + (q2 + q3);
            }
#pragma unroll
            for (int rr = 0; rr < 4; ++rr) {
                ta[rr] = dpp_add_xor1(ta[rr]);
                ta[rr] = dpp_add_xor2(ta[rr]);
            }
            float rp[4];
#pragma unroll
            for (int rr = 0; rr < 4; ++rr) {
                float q0 = 0.f, q1 = 0.f, q2 = 0.f, q3 = 0.f;
#pragma unroll
                for (int e = 0; e < 4; ++e) {
                    T[rr][e]      = fmaf(T[rr][e],      w[e],      ta[rr] * bv[e]);
                    T[rr][4 + e]  = fmaf(T[rr][4 + e],  w[4 + e],  ta[rr] * bv[4 + e]);
                    T[rr][8 + e]  = fmaf(T[rr][8 + e],  w[8 + e],  ta[rr] * bv[8 + e]);
                    T[rr][12 + e] = fmaf(T[rr][12 + e], w[12 + e], ta[rr] * bv[12 + e]);
                    q0 = fmaf(T[rr][e], r[e], q0);
                    q1 = fmaf(T[rr][4 + e], r[4 + e], q1);
                    q2 = fmaf(T[rr][8 + e], r[8 + e], q2);
                    q3 = fmaf(T[rr][12 + e], r[12 + e], q3);
                }
                rp[rr] = (q0 + q1) + (q2 + q3);
            }
#pragma unroll
            for (int rr = 0; rr < 4; ++rr) {
                rp[rr] = dpp_add_xor1(rp[rr]);
                rp[rr] = dpp_add_xor2(rp[rr]);
            }
            if (jc == 0) {
                ushort4 o4;
                o4.x = f2bf(rp[0]); o4.y = f2bf(rp[1]);
                o4.z = f2bf(rp[2]); o4.w = f2bf(rp[3]);
                *(ushort4*)(Rho + rhob + t * 64 + i0) = o4;
            }
        }
        const size_t tlb = (size_t)blk * 4096;
#pragma unroll
        for (int cc = 0; cc < 16; ++cc) {
            ushort4 o4;
            o4.x = f2bf(T[0][cc]); o4.y = f2bf(T[1][cc]);
            o4.z = f2bf(T[2][cc]); o4.w = f2bf(T[3][cc]);
            *(ushort4*)(TLt + tlb + (size_t)(j0 + cc) * 64 + i0) = o4;
        }
    } else {
        // ---- C-task ----
        const int s = lane >> 1, cc = lane & 1, j0 = cc * 32;
        float kreg[32];
#pragma unroll
        for (int q = 0; q < 8; ++q)
            *(float4*)&kreg[q * 4] = *(const float4*)(kb + base + (size_t)s * Cc + j0 + q * 4);
        float z[32];
#pragma unroll
        for (int u = 0; u < 32; ++u) z[u] = 0.f;

        for (int t = 0; t < CL; ++t) {
            const float* sp = st + t * STRD;
            float p[8];
#pragma unroll
            for (int q = 0; q < 8; ++q) {
                float4 a4 = *(const float4*)(sp + 0 * 64 + j0 + q * 4);
                p[q] = z[q*4+0]*a4.x + z[q*4+1]*a4.y;
                p[q] = fmaf(z[q*4+2], a4.z, p[q]);
                p[q] = fmaf(z[q*4+3], a4.w, p[q]);
            }
            float za = ((p[0]+p[1])+(p[2]+p[3])) + ((p[4]+p[5])+(p[6]+p[7]));
            za = dpp_add_xor1(za);
#pragma unroll
            for (int q = 0; q < 8; ++q) {
                float4 w4 = *(const float4*)(sp + 1 * 64 + j0 + q * 4);
                float4 b4 = *(const float4*)(sp + 2 * 64 + j0 + q * 4);
                z[q*4+0] = fmaf(z[q*4+0], w4.x, za * b4.x);
                z[q*4+1] = fmaf(z[q*4+1], w4.y, za * b4.y);
                z[q*4+2] = fmaf(z[q*4+2], w4.z, za * b4.z);
                z[q*4+3] = fmaf(z[q*4+3], w4.w, za * b4.w);
            }
            if (s == t) {
#pragma unroll
                for (int u = 0; u < 32; ++u) z[u] = kreg[u];
            }
            float q8[8];
#pragma unroll
            for (int q = 0; q < 8; ++q) {
                float4 r4 = *(const float4*)(sp + 3 * 64 + j0 + q * 4);
                q8[q] = z[q*4+0]*r4.x + z[q*4+1]*r4.y;
                q8[q] = fmaf(z[q*4+2], r4.z, q8[q]);
                q8[q] = fmaf(z[q*4+3], r4.w, q8[q]);
            }
            float al = ((q8[0]+q8[1])+(q8[2]+q8[3])) + ((q8[4]+q8[5])+(q8[6]+q8[7]));
            al = dpp_add_xor1(al);
            if (cc == 0) A_l[t][s] = al;
        }
        const size_t zlb = (size_t)blk * (CL * 64);
#pragma unroll
        for (int u = 0; u < 32; ++u)
            ZLt[zlb + (size_t)(j0 + u) * 32 + s] = f2bf(z[u]);
    }
    __syncthreads();

    // ---- y_intra = A_lower * V ----
    {
        const int t = tid >> 2, jq = (tid & 3) * 16;
        float y[16];
#pragma unroll
        for (int e = 0; e < 16; ++e) y[e] = 0.f;
        for (int s = 0; s <= t; ++s) {
            float al = A_l[t][s];
            const float* vv = st + s * STRD + 4 * 64 + jq;
#pragma unroll
            for (int q = 0; q < 4; ++q) {
                float4 v4 = *(const float4*)(vv + q * 4);
                y[q*4+0] = fmaf(al, v4.x, y[q*4+0]);
                y[q*4+1] = fmaf(al, v4.y, y[q*4+1]);
                y[q*4+2] = fmaf(al, v4.z, y[q*4+2]);
                y[q*4+3] = fmaf(al, v4.w, y[q*4+3]);
            }
        }
#pragma unroll
        for (int q = 0; q < 4; ++q) {
            float4 o4 = { y[q*4+0], y[q*4+1], y[q*4+2], y[q*4+3] };
            *(float4*)(yb + base + (size_t)t * Cc + jq + q * 4) = o4;
        }
    }
}

// ---------------------------------------------------------------------------
// WKV chunked, phase 2 — MFMA (unchanged from R8).
// ---------------------------------------------------------------------------
__global__ __launch_bounds__(256, 1) void wkv_chunk2(
    const float* __restrict__ vb, const unsigned short* __restrict__ TLt,
    const unsigned short* __restrict__ Rho, const unsigned short* __restrict__ ZLt,
    float* __restrict__ yb)
{
    __shared__ unsigned short Sl[64 * 72];
    __shared__ unsigned short Ttl[64 * 72];
    __shared__ unsigned short Ztl[64 * 40];
    __shared__ unsigned short Rl[32 * 72];
    __shared__ unsigned short Vtl[64 * 40];
    const int bh = blockIdx.x;
    const size_t vbase = (size_t)(bh >> 4) * Tt * Cc + (bh & 15) * HSs;
    const int tid = threadIdx.x;
    const int wv = tid >> 6, lane = tid & 63;
    const int lr = lane & 15, lk = lane >> 4;
    const int i0w = wv * 16;

    f32x4 S[4];
#pragma unroll
    for (int n = 0; n < 4; ++n)
#pragma unroll
        for (int r = 0; r < 4; ++r) S[n][r] = 0.f;

    uint4 pT0, pT1, pZ, pR;
    float4 pV0, pV1;
    const int vs = tid >> 3, vi0 = (tid & 7) * 8;

#define C2_LOAD(c_) do { \
    size_t cb_ = (size_t)(bh * NCH + (c_)); \
    const uint4* tp_ = (const uint4*)(TLt + cb_ * 4096); \
    pT0 = tp_[tid * 2]; pT1 = tp_[tid * 2 + 1]; \
    pZ = ((const uint4*)(ZLt + cb_ * 2048))[tid]; \
    pR = ((const uint4*)(Rho + cb_ * 2048))[tid]; \
    const float* vp_ = vb + vbase + (size_t)((c_) * CL + vs) * Cc + vi0; \
    pV0 = *(const float4*)vp_; pV1 = *(const float4*)(vp_ + 4); \
} while (0)

#define C2_STORE() do { \
    *(uint4*)&Ttl[(tid >> 2) * 72 + (tid & 3) * 16] = pT0; \
    *(uint4*)&Ttl[(tid >> 2) * 72 + (tid & 3) * 16 + 8] = pT1; \
    *(uint4*)&Ztl[(tid >> 2) * 40 + (tid & 3) * 8] = pZ; \
    *(uint4*)&Rl[(tid >> 3) * 72 + (tid & 7) * 8] = pR; \
    const float* pv_ = (const float*)&pV0; \
    Vtl[(vi0 + 0) * 40 + vs] = f2bf(pv_[0]); \
    Vtl[(vi0 + 1) * 40 + vs] = f2bf(pv_[1]); \
    Vtl[(vi0 + 2) * 40 + vs] = f2bf(pv_[2]); \
    Vtl[(vi0 + 3) * 40 + vs] = f2bf(pv_[3]); \
    const float* pw_ = (const float*)&pV1; \
    Vtl[(vi0 + 4) * 40 + vs] = f2bf(pw_[0]); \
    Vtl[(vi0 + 5) * 40 + vs] = f2bf(pw_[1]); \
    Vtl[(vi0 + 6) * 40 + vs] = f2bf(pw_[2]); \
    Vtl[(vi0 + 7) * 40 + vs] = f2bf(pw_[3]); \
} while (0)

    C2_LOAD(0);
    for (int c = 0; c < NCH; ++c) {
        __syncthreads();
#pragma unroll
        for (int n = 0; n < 4; ++n) {
#pragma unroll
            for (int r = 0; r < 4; ++r)
                Sl[(i0w + lk * 4 + r) * 72 + n * 16 + lr] = f2bf(S[n][r]);
        }
        C2_STORE();
        if (c + 1 < NCH) C2_LOAD(c + 1);
        __syncthreads();

        bf16x8 sA0 = *(const bf16x8*)&Sl[(i0w + lr) * 72 + lk * 8];
        bf16x8 sA1 = *(const bf16x8*)&Sl[(i0w + lr) * 72 + 32 + lk * 8];

#pragma unroll
        for (int nt = 0; nt < 2; ++nt) {
            int t = nt * 16 + lr;
            float* yp = yb + vbase + (size_t)(c * CL + t) * Cc + i0w + lk * 4;
            f32x4 yc = *(f32x4*)yp;
            bf16x8 b0 = *(const bf16x8*)&Rl[t * 72 + lk * 8];
            bf16x8 b1 = *(const bf16x8*)&Rl[t * 72 + 32 + lk * 8];
            yc = __builtin_amdgcn_mfma_f32_16x16x32_bf16(sA0, b0, yc, 0, 0, 0);
            yc = __builtin_amdgcn_mfma_f32_16x16x32_bf16(sA1, b1, yc, 0, 0, 0);
            *(f32x4*)yp = yc;
        }

        bf16x8 vA = *(const bf16x8*)&Vtl[(i0w + lr) * 40 + lk * 8];
#pragma unroll
        for (int n = 0; n < 4; ++n) {
            int j = n * 16 + lr;
            bf16x8 t0 = *(const bf16x8*)&Ttl[j * 72 + lk * 8];
            bf16x8 t1 = *(const bf16x8*)&Ttl[j * 72 + 32 + lk * 8];
            bf16x8 z0 = *(const bf16x8*)&Ztl[j * 40 + lk * 8];
            f32x4 acc = { 0.f, 0.f, 0.f, 0.f };
            acc = __builtin_amdgcn_mfma_f32_16x16x32_bf16(sA0, t0, acc, 0, 0, 0);
            acc = __builtin_amdgcn_mfma_f32_16x16x32_bf16(sA1, t1, acc, 0, 0, 0);
            acc = __builtin_amdgcn_mfma_f32_16x16x32_bf16(vA, z0, acc, 0, 0, 0);
            S[n] = acc;
        }
    }
#undef C2_LOAD
#undef C2_STORE
}

// ---------------------------------------------------------------------------
// GroupNorm + r*k*r_k bonus + gate
// ---------------------------------------------------------------------------
__global__ __launch_bounds__(256) void gn_rt_kernel(
    const float* __restrict__ yb, const float* __restrict__ rb,
    const float* __restrict__ kb, const float* __restrict__ vb,
    const unsigned short* __restrict__ gb, const float* __restrict__ r_k,
    const float* __restrict__ ln_w, const float* __restrict__ ln_b,
    unsigned short* __restrict__ zb)
{
    const int row = blockIdx.x;
    const int tid = threadIdx.x;
    const int c0 = tid * 4;
    const int hd = tid >> 4;
    const int n0 = c0 & 63;
    const size_t o = (size_t)row * Cc;

    float4 y4 = *(const float4*)(yb + o + c0);
    float4 r4 = *(const float4*)(rb + o + c0);
    float4 k4 = *(const float4*)(kb + o + c0);
    float4 v4 = *(const float4*)(vb + o + c0);
    ushort4 g4u = *(const ushort4*)(gb + o + c0);
    float4 rk4 = *(const float4*)(r_k + hd * 64 + n0);

    float yv[4] = { y4.x, y4.y, y4.z, y4.w };
    float rv[4] = { r4.x, r4.y, r4.z, r4.w };
    float kv[4] = { k4.x, k4.y, k4.z, k4.w };
    float vv[4] = { v4.x, v4.y, v4.z, v4.w };
    float gv[4] = { bf2f(g4u.x), bf2f(g4u.y), bf2f(g4u.z), bf2f(g4u.w) };
    float rkv[4] = { rk4.x, rk4.y, rk4.z, rk4.w };

    float sum = 0.f, ssq = 0.f, dot = 0.f;
#pragma unroll
    for (int j = 0; j < 4; ++j) {
        sum += yv[j];
        ssq += yv[j] * yv[j];
        dot += rv[j] * kv[j] * rkv[j];
    }
#pragma unroll
    for (int m = 1; m <= 8; m <<= 1) {
        sum += __shfl_xor(sum, m);
        ssq += __shfl_xor(ssq, m);
        dot += __shfl_xor(dot, m);
    }
    const float mu = sum * (1.f / 64.f);
    const float var = ssq * (1.f / 64.f) - mu * mu;
    const float inv = rsqrtf(var + 0.00064f);

    ushort4 z4;
    unsigned short* zp = (unsigned short*)&z4;
#pragma unroll
    for (int j = 0; j < 4; ++j) {
        int c = c0 + j;
        float yg = (yv[j] - mu) * inv * ln_w[c] + ln_b[c];
        yg += dot * vv[j];
        zp[j] = f2bf(yg * gv[j]);
    }
    *(ushort4*)(zb + o + c0) = z4;
}

// ---------------------------------------------------------------------------

extern "C" void kernel_launch(void* const* d_in, const int* in_sizes, int n_in,
                              void* d_out, int out_size, void* d_ws, size_t ws_size,
                              hipStream_t stream)
{
    const float* x   = (const float*)d_in[0];
    const float* x_r = (const float*)d_in[1];
    const float* x_w = (const float*)d_in[2];
    const float* x_k = (const float*)d_in[3];
    const float* x_v = (const float*)d_in[4];
    const float* x_a = (const float*)d_in[5];
    const float* x_g = (const float*)d_in[6];
    const float* w0  = (const float*)d_in[7];
    const float* w1  = (const float*)d_in[8];
    const float* w2  = (const float*)d_in[9];
    const float* a0  = (const float*)d_in[10];
    const float* a1  = (const float*)d_in[11];
    const float* a2  = (const float*)d_in[12];
    // v0,v1,v2 (13..15): forward no-op on first-layer call
    const float* g1  = (const float*)d_in[16];
    const float* g2  = (const float*)d_in[17];
    const float* k_k = (const float*)d_in[18];
    const float* k_a = (const float*)d_in[19];
    const float* r_k = (const float*)d_in[20];
    const float* Wr  = (const float*)d_in[21];
    const float* Wk  = (const float*)d_in[22];
    const float* Wv  = (const float*)d_in[23];
    const float* Wo  = (const float*)d_in[24];
    const float* ln_w = (const float*)d_in[25];
    const float* ln_b = (const float*)d_in[26];

    float* ws = (float*)d_ws;
    const size_t S = (size_t)Bsz * Tt * Cc;       // 4,194,304 floats (16 MiB)
    const int M = Bsz * Tt;                        // 4096

    float* rb  = ws + 0 * S;
    float* wdb = ws + 1 * S;
    unsigned short* WoT = (unsigned short*)(ws + 1 * S);   // after chunk1 (wdb dead)
    float* kb  = ws + 2 * S;
    float* vb  = ws + 3 * S;
    float* aab = ws + 4 * S;
    unsigned short* zb = (unsigned short*)(ws + 4 * S);    // after chunk1 (aab dead)
    float* bbb = ws + 5 * S;
    float* yb  = ws + 6 * S;
    unsigned short* hw = (unsigned short*)yb;              // bf16, dead before chunk1
    unsigned short* ha = hw + 262144;                      // 4096*64
    unsigned short* hg = ha + 262144;                      // 4096*128
    // slot7: xr,xk (bf16) -> ab (f32) -> TLt (bf16)
    unsigned short* xr = (unsigned short*)(ws + 7 * S);
    unsigned short* xk = xr + S;
    float* ab  = ws + 7 * S;
    unsigned short* TLt = (unsigned short*)(ws + 7 * S);
    // slot8 first half: xv (bf16 8MiB) -> gb (bf16 8MiB)
    unsigned short* xv = (unsigned short*)(ws + 8 * S);
    unsigned short* gb = xv;
    // slot8 second half: W transposes (bf16) -> Rho (bf16 8MiB)
    unsigned short* WrT = xv + S;            // 1M ushort
    unsigned short* WkT = WrT + 1048576;
    unsigned short* WvT = WkT + 1048576;
    unsigned short* w1t = WvT + 1048576;     // 64*1024 = 65536
    unsigned short* a1t = w1t + 65536;
    unsigned short* g1t = a1t + 65536;       // 128*1024 = 131072
    unsigned short* w2t = g1t + 131072;      // 1024*64
    unsigned short* a2t = w2t + 65536;
    unsigned short* g2t = a2t + 65536;       // 1024*128
    unsigned short* Rho = xv + S;            // overwrites W*T at chunk1
    // slot9: ZLt
    unsigned short* ZLt = (unsigned short*)(ws + 9 * S);

    dim3 blk(256);

    // bf16 mixes + transposed bf16 weights
    mixcast_kernel<<<dim3(M), blk, 0, stream>>>(x, x_r, x_k, x_v, xr, xk, xv);
    transpose_cast_g<<<dim3(16, 16), blk, 0, stream>>>(Wr, WrT, Cc, Cc);
    transpose_cast_g<<<dim3(16, 16), blk, 0, stream>>>(Wk, WkT, Cc, Cc);
    transpose_cast_g<<<dim3(16, 16), blk, 0, stream>>>(Wv, WvT, Cc, Cc);
    transpose_cast_g<<<dim3(1, 16), blk, 0, stream>>>(w1, w1t, Cc, 64);
    transpose_cast_g<<<dim3(1, 16), blk, 0, stream>>>(a1, a1t, Cc, 64);
    transpose_cast_g<<<dim3(2, 16), blk, 0, stream>>>(g1, g1t, Cc, 128);
    transpose_cast_g<<<dim3(16, 1), blk, 0, stream>>>(w2, w2t, 64, Cc);
    transpose_cast_g<<<dim3(16, 1), blk, 0, stream>>>(a2, a2t, 64, Cc);
    transpose_cast_g<<<dim3(16, 2), blk, 0, stream>>>(g2, g2t, 128, Cc);

    // stage-1 low-rank (fused mix, bf16 MFMA): hw=tanh, ha=none, hg=sigmoid
    lowrank1_mfma<<<dim3(1, 32), blk, 0, stream>>>(x, x_w, w1t, hw, 64, 1);
    lowrank1_mfma<<<dim3(1, 32), blk, 0, stream>>>(x, x_a, a1t, ha, 64, 0);
    lowrank1_mfma<<<dim3(2, 32), blk, 0, stream>>>(x, x_g, g1t, hg, 128, 2);

    // big projections: bf16 MFMA
    gemm_bf16<<<dim3(8, 32), blk, 0, stream>>>(xr, WrT, rb, M, Cc, Cc);
    gemm_bf16<<<dim3(8, 32), blk, 0, stream>>>(xk, WkT, kb, M, Cc, Cc);
    gemm_bf16<<<dim3(8, 32), blk, 0, stream>>>(xv, WvT, vb, M, Cc, Cc);

    // stage-2 low-rank (bf16 MFMA): wdb=decay(+w0), ab=sigmoid(+a0), gb=bf16
    gemm_bf16_g<<<dim3(16, 32), blk, 0, stream>>>(hw, w2t, wdb, w0, M, Cc, 64, 3, 0);
    gemm_bf16_g<<<dim3(16, 32), blk, 0, stream>>>(ha, a2t, ab, a0, M, Cc, 64, 2, 0);
    gemm_bf16_g<<<dim3(16, 32), blk, 0, stream>>>(hg, g2t, gb, nullptr, M, Cc, 128, 0, 1);

    // k / kk / aa / bb
    prep_k_kernel<<<dim3(M), blk, 0, stream>>>(kb, ab, k_k, k_a, kb, aab, bbb);

    // chunked recurrence
    wkv_chunk1<<<dim3(64 * NCH), dim3(128), 0, stream>>>(rb, wdb, kb, vb, aab, bbb, yb, TLt, Rho, ZLt);
    wkv_chunk2<<<dim3(64), blk, 0, stream>>>(vb, TLt, Rho, ZLt, yb);

    // Wo transpose (into dead wdb slot), groupnorm+bonus+gate -> z (bf16)
    transpose_cast_g<<<dim3(16, 16), blk, 0, stream>>>(Wo, WoT, Cc, Cc);
    gn_rt_kernel<<<dim3(M), blk, 0, stream>>>(yb, rb, kb, vb, gb, r_k, ln_w, ln_b, zb);

    // output projection: bf16 MFMA
    gemm_bf16<<<dim3(8, 32), blk, 0, stream>>>(zb, WoT, (float*)d_out, M, Cc, Cc);
}

// Round 10
// 321.056 us; speedup vs baseline: 8.0950x; 1.5320x over previous
//
#include <hip/hip_runtime.h>
#include <math.h>

#define Bsz 4
#define Tt  1024
#define Cc  1024
#define Hh  16
#define HSs 64
#define CL  32            // wkv chunk length
#define NCH (Tt / CL)     // 32 chunks
#define STRD 260          // padded step stride in floats (260 % 32 = 4); 4 arrays

typedef __attribute__((ext_vector_type(8))) short bf16x8;
typedef __attribute__((ext_vector_type(4))) float f32x4;

__device__ __forceinline__ float sigf(float x) { return 1.f / (1.f + expf(-x)); }

__device__ __forceinline__ unsigned short f2bf(float f) {
    unsigned int u = __float_as_uint(f);
    u = u + 0x7fffu + ((u >> 16) & 1u);   // RNE
    return (unsigned short)(u >> 16);
}
__device__ __forceinline__ float bf2f(unsigned short u) {
    return __uint_as_float(((unsigned int)u) << 16);
}
__device__ __forceinline__ float dpp_add_xor1(float x) {
    int y = __builtin_amdgcn_mov_dpp(__float_as_int(x), 0xB1, 0xF, 0xF, true);
    return x + __int_as_float(y);
}
__device__ __forceinline__ float dpp_add_xor2(float x) {
    int y = __builtin_amdgcn_mov_dpp(__float_as_int(x), 0x4E, 0xF, 0xF, true);
    return x + __int_as_float(y);
}

// ---------------------------------------------------------------------------
// 64x64 transpose+cast helper: WT[n][k] = bf16(W[k][n]); W is [K][N] fp32.
// ---------------------------------------------------------------------------
__device__ __forceinline__ void tcast64(
    const float* __restrict__ W, unsigned short* __restrict__ WT,
    int K, int N, int n0, int k0, int tid, unsigned short tile[64][68])
{
    const int tr = tid >> 4, tc4 = (tid & 15) * 4;
#pragma unroll
    for (int s = 0; s < 4; ++s) {
        int kk = tr + s * 16;
        float4 w4 = *(const float4*)(W + (size_t)(k0 + kk) * N + n0 + tc4);
        tile[kk][tc4 + 0] = f2bf(w4.x);
        tile[kk][tc4 + 1] = f2bf(w4.y);
        tile[kk][tc4 + 2] = f2bf(w4.z);
        tile[kk][tc4 + 3] = f2bf(w4.w);
    }
    __syncthreads();
#pragma unroll
    for (int s = 0; s < 4; ++s) {
        int nn = tr + s * 16;
        ushort4 o4;
        o4.x = tile[tc4 + 0][nn];
        o4.y = tile[tc4 + 1][nn];
        o4.z = tile[tc4 + 2][nn];
        o4.w = tile[tc4 + 3][nn];
        *(ushort4*)(WT + (size_t)(n0 + nn) * K + k0 + tc4) = o4;
    }
}

// ---------------------------------------------------------------------------
// prep_all: mixcast (blocks 0..4095) + 10 weight transposes (block-id dispatch)
// ---------------------------------------------------------------------------
__global__ __launch_bounds__(256) void prep_all(
    const float* __restrict__ x, const float* __restrict__ x_r,
    const float* __restrict__ x_k, const float* __restrict__ x_v,
    const float* __restrict__ Wr, const float* __restrict__ Wk,
    const float* __restrict__ Wv, const float* __restrict__ Wo,
    const float* __restrict__ w1, const float* __restrict__ a1,
    const float* __restrict__ g1, const float* __restrict__ w2,
    const float* __restrict__ a2, const float* __restrict__ g2,
    unsigned short* __restrict__ xr, unsigned short* __restrict__ xk,
    unsigned short* __restrict__ xvo,
    unsigned short* __restrict__ WrT, unsigned short* __restrict__ WkT,
    unsigned short* __restrict__ WvT, unsigned short* __restrict__ WoT,
    unsigned short* __restrict__ w1t, unsigned short* __restrict__ a1t,
    unsigned short* __restrict__ g1t, unsigned short* __restrict__ w2t,
    unsigned short* __restrict__ a2t, unsigned short* __restrict__ g2t)
{
    __shared__ unsigned short tile[64][68];
    const int tid = threadIdx.x;
    int bid = blockIdx.x;

    if (bid < 4096) {
        // ---- mixcast ----
        const int row = bid;
        const int c0 = tid * 4;
        const size_t o = (size_t)row * Cc;
        float4 xc = *(const float4*)(x + o + c0);
        float4 xp;
        if (row & (Tt - 1)) xp = *(const float4*)(x + o - Cc + c0);
        else { xp.x = xp.y = xp.z = xp.w = 0.f; }
        float4 mr = *(const float4*)(x_r + c0);
        float4 mk = *(const float4*)(x_k + c0);
        float4 mv = *(const float4*)(x_v + c0);
        const float* xcf = (const float*)&xc; const float* xpf = (const float*)&xp;
        const float* mrf = (const float*)&mr; const float* mkf = (const float*)&mk;
        const float* mvf = (const float*)&mv;
        ushort4 r4, k4, v4;
        unsigned short* rp = (unsigned short*)&r4;
        unsigned short* kp = (unsigned short*)&k4;
        unsigned short* vp = (unsigned short*)&v4;
#pragma unroll
        for (int j = 0; j < 4; ++j) {
            float xx = xpf[j] - xcf[j];
            rp[j] = f2bf(xcf[j] + xx * mrf[j]);
            kp[j] = f2bf(xcf[j] + xx * mkf[j]);
            vp[j] = f2bf(xcf[j] + xx * mvf[j]);
        }
        *(ushort4*)(xr + o + c0) = r4;
        *(ushort4*)(xk + o + c0) = k4;
        *(ushort4*)(xvo + o + c0) = v4;
        return;
    }
    bid -= 4096;
    if (bid < 1024) {       // Wr/Wk/Wv/Wo, 256 blocks each
        int which = bid >> 8, id0 = bid & 255;
        const float* W = which == 0 ? Wr : which == 1 ? Wk : which == 2 ? Wv : Wo;
        unsigned short* WT = which == 0 ? WrT : which == 1 ? WkT : which == 2 ? WvT : WoT;
        tcast64(W, WT, Cc, Cc, (id0 & 15) * 64, (id0 >> 4) * 64, tid, tile);
        return;
    }
    bid -= 1024;
    if (bid < 16) { tcast64(w1, w1t, Cc, 64, 0, bid * 64, tid, tile); return; }
    bid -= 16;
    if (bid < 16) { tcast64(a1, a1t, Cc, 64, 0, bid * 64, tid, tile); return; }
    bid -= 16;
    if (bid < 32) { tcast64(g1, g1t, Cc, 128, (bid & 1) * 64, (bid >> 1) * 64, tid, tile); return; }
    bid -= 32;
    if (bid < 16) { tcast64(w2, w2t, 64, Cc, bid * 64, 0, tid, tile); return; }
    bid -= 16;
    if (bid < 16) { tcast64(a2, a2t, 64, Cc, bid * 64, 0, tid, tile); return; }
    bid -= 16;
    tcast64(g2, g2t, 128, Cc, (bid & 15) * 64, (bid >> 4) * 64, tid, tile);
}

// ---------------------------------------------------------------------------
// big bf16 MFMA GEMM, r/k/v fused (z selects operands): 128x128 tile
// ---------------------------------------------------------------------------
__global__ __launch_bounds__(256) void gemm_rkv(
    const unsigned short* __restrict__ xr, const unsigned short* __restrict__ xk,
    const unsigned short* __restrict__ xv,
    const unsigned short* __restrict__ WrT, const unsigned short* __restrict__ WkT,
    const unsigned short* __restrict__ WvT,
    float* __restrict__ rb, float* __restrict__ kb, float* __restrict__ vb)
{
    const int z = blockIdx.z;
    const unsigned short* A  = z == 0 ? xr : z == 1 ? xk : xv;
    const unsigned short* WT = z == 0 ? WrT : z == 1 ? WkT : WvT;
    float* out = z == 0 ? rb : z == 1 ? kb : vb;
    const int K = Cc, N = Cc;

    __shared__ __attribute__((aligned(16))) unsigned short As[128][40];
    __shared__ __attribute__((aligned(16))) unsigned short Bs[128][40];
    const int row0 = blockIdx.y * 128;
    const int col0 = blockIdx.x * 128;
    const int tid = threadIdx.x;
    const int wave = tid >> 6, lane = tid & 63;
    const int wr = wave >> 1, wc = wave & 1;
    const int lr = lane & 15, lk = lane >> 4;

    f32x4 acc[4][4];
#pragma unroll
    for (int m = 0; m < 4; ++m)
#pragma unroll
        for (int n = 0; n < 4; ++n)
#pragma unroll
            for (int r = 0; r < 4; ++r) acc[m][n][r] = 0.f;

    const int sr = tid >> 2;
    const int sc = (tid & 3) * 8;

    for (int k0 = 0; k0 < K; k0 += 32) {
        uint4 a0v = *(const uint4*)(A  + (size_t)(row0 + sr) * K + k0 + sc);
        uint4 a1v = *(const uint4*)(A  + (size_t)(row0 + 64 + sr) * K + k0 + sc);
        uint4 b0v = *(const uint4*)(WT + (size_t)(col0 + sr) * K + k0 + sc);
        uint4 b1v = *(const uint4*)(WT + (size_t)(col0 + 64 + sr) * K + k0 + sc);
        *(uint4*)&As[sr][sc]      = a0v;
        *(uint4*)&As[64 + sr][sc] = a1v;
        *(uint4*)&Bs[sr][sc]      = b0v;
        *(uint4*)&Bs[64 + sr][sc] = b1v;
        __syncthreads();
        bf16x8 af[4], bff[4];
#pragma unroll
        for (int m = 0; m < 4; ++m)
            af[m] = *(const bf16x8*)&As[wr * 64 + m * 16 + lr][lk * 8];
#pragma unroll
        for (int n = 0; n < 4; ++n)
            bff[n] = *(const bf16x8*)&Bs[wc * 64 + n * 16 + lr][lk * 8];
#pragma unroll
        for (int m = 0; m < 4; ++m)
#pragma unroll
            for (int n = 0; n < 4; ++n)
                acc[m][n] = __builtin_amdgcn_mfma_f32_16x16x32_bf16(af[m], bff[n], acc[m][n], 0, 0, 0);
        __syncthreads();
    }

#pragma unroll
    for (int m = 0; m < 4; ++m)
#pragma unroll
        for (int n = 0; n < 4; ++n) {
            int col = col0 + wc * 64 + n * 16 + lr;
#pragma unroll
            for (int r = 0; r < 4; ++r) {
                int row = row0 + wr * 64 + m * 16 + lk * 4 + r;
                out[(size_t)row * N + col] = acc[m][n][r];
            }
        }
}

// ---------------------------------------------------------------------------
// plain 128x128 bf16 GEMM (Wo projection)
// ---------------------------------------------------------------------------
__global__ __launch_bounds__(256) void gemm_bf16(
    const unsigned short* __restrict__ A, const unsigned short* __restrict__ WT,
    float* __restrict__ out, int M, int N, int K)
{
    __shared__ __attribute__((aligned(16))) unsigned short As[128][40];
    __shared__ __attribute__((aligned(16))) unsigned short Bs[128][40];
    const int row0 = blockIdx.y * 128;
    const int col0 = blockIdx.x * 128;
    const int tid = threadIdx.x;
    const int wave = tid >> 6, lane = tid & 63;
    const int wr = wave >> 1, wc = wave & 1;
    const int lr = lane & 15, lk = lane >> 4;

    f32x4 acc[4][4];
#pragma unroll
    for (int m = 0; m < 4; ++m)
#pragma unroll
        for (int n = 0; n < 4; ++n)
#pragma unroll
            for (int r = 0; r < 4; ++r) acc[m][n][r] = 0.f;

    const int sr = tid >> 2;
    const int sc = (tid & 3) * 8;

    for (int k0 = 0; k0 < K; k0 += 32) {
        uint4 a0v = *(const uint4*)(A  + (size_t)(row0 + sr) * K + k0 + sc);
        uint4 a1v = *(const uint4*)(A  + (size_t)(row0 + 64 + sr) * K + k0 + sc);
        uint4 b0v = *(const uint4*)(WT + (size_t)(col0 + sr) * K + k0 + sc);
        uint4 b1v = *(const uint4*)(WT + (size_t)(col0 + 64 + sr) * K + k0 + sc);
        *(uint4*)&As[sr][sc]      = a0v;
        *(uint4*)&As[64 + sr][sc] = a1v;
        *(uint4*)&Bs[sr][sc]      = b0v;
        *(uint4*)&Bs[64 + sr][sc] = b1v;
        __syncthreads();
        bf16x8 af[4], bff[4];
#pragma unroll
        for (int m = 0; m < 4; ++m)
            af[m] = *(const bf16x8*)&As[wr * 64 + m * 16 + lr][lk * 8];
#pragma unroll
        for (int n = 0; n < 4; ++n)
            bff[n] = *(const bf16x8*)&Bs[wc * 64 + n * 16 + lr][lk * 8];
#pragma unroll
        for (int m = 0; m < 4; ++m)
#pragma unroll
            for (int n = 0; n < 4; ++n)
                acc[m][n] = __builtin_amdgcn_mfma_f32_16x16x32_bf16(af[m], bff[n], acc[m][n], 0, 0, 0);
        __syncthreads();
    }

#pragma unroll
    for (int m = 0; m < 4; ++m)
#pragma unroll
        for (int n = 0; n < 4; ++n) {
            int col = col0 + wc * 64 + n * 16 + lr;
#pragma unroll
            for (int r = 0; r < 4; ++r) {
                int row = row0 + wr * 64 + m * 16 + lk * 4 + r;
                out[(size_t)row * N + col] = acc[m][n][r];
            }
        }
}

// ---------------------------------------------------------------------------
// stage-1 low-rank MFMA, all three paths fused (seg on blockIdx.x).
// seg 0: hw=tanh(xw@w1) N=64; seg 1: ha=xa@a1 N=64; seg 2,3: hg=sig(xg@g1) N=128.
// ---------------------------------------------------------------------------
__global__ __launch_bounds__(256) void lowrank1_fused(
    const float* __restrict__ x,
    const float* __restrict__ x_w, const float* __restrict__ x_a,
    const float* __restrict__ x_g,
    const unsigned short* __restrict__ w1t, const unsigned short* __restrict__ a1t,
    const unsigned short* __restrict__ g1t,
    unsigned short* __restrict__ hw, unsigned short* __restrict__ ha,
    unsigned short* __restrict__ hg)
{
    const int seg = blockIdx.x;
    const float* mix; const unsigned short* WT; unsigned short* out;
    int N, col0, epi;
    if (seg == 0)      { mix = x_w; WT = w1t; out = hw; N = 64;  col0 = 0; epi = 1; }
    else if (seg == 1) { mix = x_a; WT = a1t; out = ha; N = 64;  col0 = 0; epi = 0; }
    else               { mix = x_g; WT = g1t; out = hg; N = 128; col0 = (seg - 2) * 64; epi = 2; }

    __shared__ __attribute__((aligned(16))) unsigned short As[128][40];
    __shared__ __attribute__((aligned(16))) unsigned short Bs[64][40];
    const int row0 = blockIdx.y * 128;
    const int tid = threadIdx.x;
    const int wave = tid >> 6, lane = tid & 63;
    const int lr = lane & 15, lk = lane >> 4;

    f32x4 acc[2][4];
#pragma unroll
    for (int m = 0; m < 2; ++m)
#pragma unroll
        for (int n = 0; n < 4; ++n)
#pragma unroll
            for (int r = 0; r < 4; ++r) acc[m][n][r] = 0.f;

    for (int k0 = 0; k0 < Cc; k0 += 32) {
#pragma unroll
        for (int e = 0; e < 2; ++e) {
            int idx = tid * 2 + e;
            int ar = idx >> 2, ac = (idx & 3) * 8;
            int row = row0 + ar;
            const float* xp = x + (size_t)row * Cc + k0 + ac;
            float4 c0 = *(const float4*)xp;
            float4 c1 = *(const float4*)(xp + 4);
            float4 p0, p1;
            if (row & (Tt - 1)) {
                p0 = *(const float4*)(xp - Cc);
                p1 = *(const float4*)(xp - Cc + 4);
            } else {
                p0.x = p0.y = p0.z = p0.w = 0.f;
                p1.x = p1.y = p1.z = p1.w = 0.f;
            }
            float4 m0 = *(const float4*)(mix + k0 + ac);
            float4 m1 = *(const float4*)(mix + k0 + ac + 4);
            const float* cf0 = (const float*)&c0; const float* cf1 = (const float*)&c1;
            const float* pf0 = (const float*)&p0; const float* pf1 = (const float*)&p1;
            const float* mf0 = (const float*)&m0; const float* mf1 = (const float*)&m1;
            ushort4 u0, u1;
            unsigned short* up0 = (unsigned short*)&u0;
            unsigned short* up1 = (unsigned short*)&u1;
#pragma unroll
            for (int j = 0; j < 4; ++j) {
                up0[j] = f2bf(cf0[j] + (pf0[j] - cf0[j]) * mf0[j]);
                up1[j] = f2bf(cf1[j] + (pf1[j] - cf1[j]) * mf1[j]);
            }
            *(ushort4*)&As[ar][ac] = u0;
            *(ushort4*)&As[ar][ac + 4] = u1;
        }
        {
            int br = tid >> 2, bc = (tid & 3) * 8;
            *(uint4*)&Bs[br][bc] = *(const uint4*)(WT + (size_t)(col0 + br) * Cc + k0 + bc);
        }
        __syncthreads();
        bf16x8 af[2], bff[4];
#pragma unroll
        for (int m = 0; m < 2; ++m)
            af[m] = *(const bf16x8*)&As[wave * 32 + m * 16 + lr][lk * 8];
#pragma unroll
        for (int n = 0; n < 4; ++n)
            bff[n] = *(const bf16x8*)&Bs[n * 16 + lr][lk * 8];
#pragma unroll
        for (int m = 0; m < 2; ++m)
#pragma unroll
            for (int n = 0; n < 4; ++n)
                acc[m][n] = __builtin_amdgcn_mfma_f32_16x16x32_bf16(af[m], bff[n], acc[m][n], 0, 0, 0);
        __syncthreads();
    }

#pragma unroll
    for (int m = 0; m < 2; ++m)
#pragma unroll
        for (int n = 0; n < 4; ++n) {
            int col = col0 + n * 16 + lr;
#pragma unroll
            for (int r = 0; r < 4; ++r) {
                int row = row0 + wave * 32 + m * 16 + lk * 4 + r;
                float v = acc[m][n][r];
                if (epi == 1) v = tanhf(v);
                else if (epi == 2) v = sigf(v);
                out[(size_t)row * N + col] = f2bf(v);
            }
        }
}

// ---------------------------------------------------------------------------
// stage-2 low-rank MFMA, fused (z selects path). 128x64 tile, BK=32.
// z0: wdb=decay(hw@w2+w0) f32; z1: ab=sig(ha@a2+a0) f32; z2: gb=hg@g2 bf16.
// ---------------------------------------------------------------------------
__global__ __launch_bounds__(256) void stage2_fused(
    const unsigned short* __restrict__ hw, const unsigned short* __restrict__ ha,
    const unsigned short* __restrict__ hg,
    const unsigned short* __restrict__ w2t, const unsigned short* __restrict__ a2t,
    const unsigned short* __restrict__ g2t,
    float* __restrict__ wdb, float* __restrict__ ab, unsigned short* __restrict__ gb,
    const float* __restrict__ w0, const float* __restrict__ a0)
{
    const int z = blockIdx.z;
    const unsigned short* A  = z == 0 ? hw : z == 1 ? ha : hg;
    const unsigned short* WT = z == 0 ? w2t : z == 1 ? a2t : g2t;
    const float* bias = z == 0 ? w0 : z == 1 ? a0 : nullptr;
    const int K = (z == 2) ? 128 : 64;
    const int N = Cc;

    __shared__ __attribute__((aligned(16))) unsigned short As[128][40];
    __shared__ __attribute__((aligned(16))) unsigned short Bs[64][40];
    const int row0 = blockIdx.y * 128;
    const int col0 = blockIdx.x * 64;
    const int tid = threadIdx.x;
    const int wave = tid >> 6, lane = tid & 63;
    const int lr = lane & 15, lk = lane >> 4;

    f32x4 acc[2][4];
#pragma unroll
    for (int m = 0; m < 2; ++m)
#pragma unroll
        for (int n = 0; n < 4; ++n)
#pragma unroll
            for (int r = 0; r < 4; ++r) acc[m][n][r] = 0.f;

    for (int k0 = 0; k0 < K; k0 += 32) {
#pragma unroll
        for (int e = 0; e < 2; ++e) {
            int idx = tid * 2 + e;
            int ar = idx >> 2, ac = (idx & 3) * 8;
            *(uint4*)&As[ar][ac] = *(const uint4*)(A + (size_t)(row0 + ar) * K + k0 + ac);
        }
        {
            int br = tid >> 2, bc = (tid & 3) * 8;
            *(uint4*)&Bs[br][bc] = *(const uint4*)(WT + (size_t)(col0 + br) * K + k0 + bc);
        }
        __syncthreads();
        bf16x8 af[2], bff[4];
#pragma unroll
        for (int m = 0; m < 2; ++m)
            af[m] = *(const bf16x8*)&As[wave * 32 + m * 16 + lr][lk * 8];
#pragma unroll
        for (int n = 0; n < 4; ++n)
            bff[n] = *(const bf16x8*)&Bs[n * 16 + lr][lk * 8];
#pragma unroll
        for (int m = 0; m < 2; ++m)
#pragma unroll
            for (int n = 0; n < 4; ++n)
                acc[m][n] = __builtin_amdgcn_mfma_f32_16x16x32_bf16(af[m], bff[n], acc[m][n], 0, 0, 0);
        __syncthreads();
    }

#pragma unroll
    for (int m = 0; m < 2; ++m)
#pragma unroll
        for (int n = 0; n < 4; ++n) {
            int col = col0 + n * 16 + lr;
#pragma unroll
            for (int r = 0; r < 4; ++r) {
                int row = row0 + wave * 32 + m * 16 + lk * 4 + r;
                float v = acc[m][n][r];
                if (bias) v += bias[col];
                if (z == 0) v = expf(-0.60653065971263342f * sigf(v));
                else if (z == 1) v = sigf(v);
                if (z == 2) gb[(size_t)row * N + col] = f2bf(v);
                else if (z == 0) wdb[(size_t)row * N + col] = v;
                else ab[(size_t)row * N + col] = v;
            }
        }
}

// ---------------------------------------------------------------------------
// prep_k
// ---------------------------------------------------------------------------
__global__ __launch_bounds__(256) void prep_k_kernel(
    const float* kraw, const float* __restrict__ a,
    const float* __restrict__ k_k, const float* __restrict__ k_a,
    float* kout, float* __restrict__ aaout, float* __restrict__ bbout)
{
    const int row = blockIdx.x;
    const int tid = threadIdx.x;
    const int c0 = tid * 4;
    const size_t o = (size_t)row * Cc;

    float4 kr = *(const float4*)(kraw + o + c0);
    float4 kkw = *(const float4*)(k_k + c0);
    float4 av = *(const float4*)(a + o + c0);
    float4 kaw = *(const float4*)(k_a + c0);

    float kk[4] = { kr.x * kkw.x, kr.y * kkw.y, kr.z * kkw.z, kr.w * kkw.w };
    float ssq = kk[0]*kk[0] + kk[1]*kk[1] + kk[2]*kk[2] + kk[3]*kk[3];
    ssq += __shfl_xor(ssq, 1);
    ssq += __shfl_xor(ssq, 2);
    ssq += __shfl_xor(ssq, 4);
    ssq += __shfl_xor(ssq, 8);
    float inv = 1.f / fmaxf(sqrtf(ssq), 1e-12f);

    float krr[4] = { kr.x, kr.y, kr.z, kr.w };
    float av4[4] = { av.x, av.y, av.z, av.w };
    float ka4[4] = { kaw.x, kaw.y, kaw.z, kaw.w };
    float4 aa4, bb4, kf4;
    float* aap = (float*)&aa4; float* bbp = (float*)&bb4; float* kfp = (float*)&kf4;
#pragma unroll
    for (int j = 0; j < 4; ++j) {
        float kkn = kk[j] * inv;
        aap[j] = -kkn;
        bbp[j] = kkn * av4[j];
        kfp[j] = krr[j] * (1.f + (av4[j] - 1.f) * ka4[j]);
    }
    *(float4*)(aaout + o + c0) = aa4;
    *(float4*)(bbout + o + c0) = bb4;
    *(float4*)(kout + o + c0) = kf4;
}

// ---------------------------------------------------------------------------
// WKV chunked, phase 1 (v4: 4-array LDS, v from global in epilogue).
// st arrays: 0=a 1=w 2=b 3=r. LDS 37.5 KB -> 4 blocks/CU.
// ---------------------------------------------------------------------------
__global__ __launch_bounds__(128, 1) void wkv_chunk1(
    const float* __restrict__ rb, const float* __restrict__ wdb,
    const float* __restrict__ kb, const float* __restrict__ vb,
    const float* __restrict__ aab, const float* __restrict__ bbb,
    float* __restrict__ yb,
    unsigned short* __restrict__ TLt,  // [blk][j=64][p=64]
    unsigned short* __restrict__ Rho,  // [blk][t=32][p=64]
    unsigned short* __restrict__ ZLt)  // [blk][j=64][s=32]
{
    __shared__ float st[CL * STRD];
    __shared__ float A_l[CL][CL + 1];
    const int blk = blockIdx.x;
    const int bh = blk >> 5;
    const int c  = blk & (NCH - 1);
    const int b = bh >> 4, h = bh & 15;
    const size_t base = (size_t)b * Tt * Cc + h * HSs + (size_t)c * CL * Cc;
    const int tid = threadIdx.x;

    {
        const float* srcs[4] = { aab, wdb, bbb, rb };
#pragma unroll
        for (int arr = 0; arr < 4; ++arr) {
            const float* g = srcs[arr];
#pragma unroll
            for (int e = 0; e < 4; ++e) {
                int idx = tid + e * 128;
                int s = idx >> 4, jq = (idx & 15) * 4;
                *(float4*)&st[s * STRD + arr * 64 + jq] =
                    *(const float4*)(g + base + (size_t)s * Cc + jq);
            }
        }
    }
    __syncthreads();

    const int wv = tid >> 6, lane = tid & 63;
    if (wv == 0) {
        // ---- B-task: 4 rows x 16 cols per thread ----
        const int rq = lane >> 2, jc = lane & 3;
        const int i0 = rq * 4, j0 = jc * 16;
        float T[4][16];
#pragma unroll
        for (int rr = 0; rr < 4; ++rr)
#pragma unroll
            for (int cc = 0; cc < 16; ++cc)
                T[rr][cc] = (i0 + rr == j0 + cc) ? 1.f : 0.f;
        const size_t rhob = (size_t)blk * (CL * 64);

        for (int t = 0; t < CL; ++t) {
            const float* sp = st + t * STRD;
            float a[16], w[16], bv[16], r[16];
#pragma unroll
            for (int q = 0; q < 4; ++q) {
                *(float4*)&a[q * 4]  = *(const float4*)(sp + 0 * 64 + j0 + q * 4);
                *(float4*)&w[q * 4]  = *(const float4*)(sp + 1 * 64 + j0 + q * 4);
                *(float4*)&bv[q * 4] = *(const float4*)(sp + 2 * 64 + j0 + q * 4);
                *(float4*)&r[q * 4]  = *(const float4*)(sp + 3 * 64 + j0 + q * 4);
            }
            float ta[4];
#pragma unroll
            for (int rr = 0; rr < 4; ++rr) {
                float q0 = T[rr][0] * a[0], q1 = T[rr][4] * a[4];
                float q2 = T[rr][8] * a[8], q3 = T[rr][12] * a[12];
#pragma unroll
                for (int e = 1; e < 4; ++e) {
                    q0 = fmaf(T[rr][e], a[e], q0);
                    q1 = fmaf(T[rr][4 + e], a[4 + e], q1);
                    q2 = fmaf(T[rr][8 + e], a[8 + e], q2);
                    q3 = fmaf(T[rr][12 + e], a[12 + e], q3);
                }
                ta[rr] = (q0 + q1) + (q2 + q3);
            }
#pragma unroll
            for (int rr = 0; rr < 4; ++rr) {
                ta[rr] = dpp_add_xor1(ta[rr]);
                ta[rr] = dpp_add_xor2(ta[rr]);
            }
            float rp[4];
#pragma unroll
            for (int rr = 0; rr < 4; ++rr) {
                float q0 = 0.f, q1 = 0.f, q2 = 0.f, q3 = 0.f;
#pragma unroll
                for (int e = 0; e < 4; ++e) {
                    T[rr][e]      = fmaf(T[rr][e],      w[e],      ta[rr] * bv[e]);
                    T[rr][4 + e]  = fmaf(T[rr][4 + e],  w[4 + e],  ta[rr] * bv[4 + e]);
                    T[rr][8 + e]  = fmaf(T[rr][8 + e],  w[8 + e],  ta[rr] * bv[8 + e]);
                    T[rr][12 + e] = fmaf(T[rr][12 + e], w[12 + e], ta[rr] * bv[12 + e]);
                    q0 = fmaf(T[rr][e], r[e], q0);
                    q1 = fmaf(T[rr][4 + e], r[4 + e], q1);
                    q2 = fmaf(T[rr][8 + e], r[8 + e], q2);
                    q3 = fmaf(T[rr][12 + e], r[12 + e], q3);
                }
                rp[rr] = (q0 + q1) + (q2 + q3);
            }
#pragma unroll
            for (int rr = 0; rr < 4; ++rr) {
                rp[rr] = dpp_add_xor1(rp[rr]);
                rp[rr] = dpp_add_xor2(rp[rr]);
            }
            if (jc == 0) {
                ushort4 o4;
                o4.x = f2bf(rp[0]); o4.y = f2bf(rp[1]);
                o4.z = f2bf(rp[2]); o4.w = f2bf(rp[3]);
                *(ushort4*)(Rho + rhob + t * 64 + i0) = o4;
            }
        }
        const size_t tlb = (size_t)blk * 4096;
#pragma unroll
        for (int cc = 0; cc < 16; ++cc) {
            ushort4 o4;
            o4.x = f2bf(T[0][cc]); o4.y = f2bf(T[1][cc]);
            o4.z = f2bf(T[2][cc]); o4.w = f2bf(T[3][cc]);
            *(ushort4*)(TLt + tlb + (size_t)(j0 + cc) * 64 + i0) = o4;
        }
    } else {
        // ---- C-task ----
        const int s = lane >> 1, cc = lane & 1, j0 = cc * 32;
        float kreg[32];
#pragma unroll
        for (int q = 0; q < 8; ++q)
            *(float4*)&kreg[q * 4] = *(const float4*)(kb + base + (size_t)s * Cc + j0 + q * 4);
        float z[32];
#pragma unroll
        for (int u = 0; u < 32; ++u) z[u] = 0.f;

        for (int t = 0; t < CL; ++t) {
            const float* sp = st + t * STRD;
            float p[8];
#pragma unroll
            for (int q = 0; q < 8; ++q) {
                float4 a4 = *(const float4*)(sp + 0 * 64 + j0 + q * 4);
                p[q] = z[q*4+0]*a4.x + z[q*4+1]*a4.y;
                p[q] = fmaf(z[q*4+2], a4.z, p[q]);
                p[q] = fmaf(z[q*4+3], a4.w, p[q]);
            }
            float za = ((p[0]+p[1])+(p[2]+p[3])) + ((p[4]+p[5])+(p[6]+p[7]));
            za = dpp_add_xor1(za);
#pragma unroll
            for (int q = 0; q < 8; ++q) {
                float4 w4 = *(const float4*)(sp + 1 * 64 + j0 + q * 4);
                float4 b4 = *(const float4*)(sp + 2 * 64 + j0 + q * 4);
                z[q*4+0] = fmaf(z[q*4+0], w4.x, za * b4.x);
                z[q*4+1] = fmaf(z[q*4+1], w4.y, za * b4.y);
                z[q*4+2] = fmaf(z[q*4+2], w4.z, za * b4.z);
                z[q*4+3] = fmaf(z[q*4+3], w4.w, za * b4.w);
            }
            if (s == t) {
#pragma unroll
                for (int u = 0; u < 32; ++u) z[u] = kreg[u];
            }
            float q8[8];
#pragma unroll
            for (int q = 0; q < 8; ++q) {
                float4 r4 = *(const float4*)(sp + 3 * 64 + j0 + q * 4);
                q8[q] = z[q*4+0]*r4.x + z[q*4+1]*r4.y;
                q8[q] = fmaf(z[q*4+2], r4.z, q8[q]);
                q8[q] = fmaf(z[q*4+3], r4.w, q8[q]);
            }
            float al = ((q8[0]+q8[1])+(q8[2]+q8[3])) + ((q8[4]+q8[5])+(q8[6]+q8[7]));
            al = dpp_add_xor1(al);
            if (cc == 0) A_l[t][s] = al;
        }
        const size_t zlb = (size_t)blk * (CL * 64);
#pragma unroll
        for (int u = 0; u < 32; ++u)
            ZLt[zlb + (size_t)(j0 + u) * 32 + s] = f2bf(z[u]);
    }
    __syncthreads();

    // ---- y_intra = A_lower * V (v read from global; L1/L2-resident) ----
    {
        const int t = tid >> 2, jq = (tid & 3) * 16;
        float y[16];
#pragma unroll
        for (int e = 0; e < 16; ++e) y[e] = 0.f;
        for (int s = 0; s <= t; ++s) {
            float al = A_l[t][s];
            const float* vv = vb + base + (size_t)s * Cc + jq;
#pragma unroll
            for (int q = 0; q < 4; ++q) {
                float4 v4 = *(const float4*)(vv + q * 4);
                y[q*4+0] = fmaf(al, v4.x, y[q*4+0]);
                y[q*4+1] = fmaf(al, v4.y, y[q*4+1]);
                y[q*4+2] = fmaf(al, v4.z, y[q*4+2]);
                y[q*4+3] = fmaf(al, v4.w, y[q*4+3]);
            }
        }
#pragma unroll
        for (int q = 0; q < 4; ++q) {
            float4 o4 = { y[q*4+0], y[q*4+1], y[q*4+2], y[q*4+3] };
            *(float4*)(yb + base + (size_t)t * Cc + jq + q * 4) = o4;
        }
    }
}

// ---------------------------------------------------------------------------
// WKV chunked, phase 2 — MFMA (unchanged).
// ---------------------------------------------------------------------------
__global__ __launch_bounds__(256, 1) void wkv_chunk2(
    const float* __restrict__ vb, const unsigned short* __restrict__ TLt,
    const unsigned short* __restrict__ Rho, const unsigned short* __restrict__ ZLt,
    float* __restrict__ yb)
{
    __shared__ unsigned short Sl[64 * 72];
    __shared__ unsigned short Ttl[64 * 72];
    __shared__ unsigned short Ztl[64 * 40];
    __shared__ unsigned short Rl[32 * 72];
    __shared__ unsigned short Vtl[64 * 40];
    const int bh = blockIdx.x;
    const size_t vbase = (size_t)(bh >> 4) * Tt * Cc + (bh & 15) * HSs;
    const int tid = threadIdx.x;
    const int wv = tid >> 6, lane = tid & 63;
    const int lr = lane & 15, lk = lane >> 4;
    const int i0w = wv * 16;

    f32x4 S[4];
#pragma unroll
    for (int n = 0; n < 4; ++n)
#pragma unroll
        for (int r = 0; r < 4; ++r) S[n][r] = 0.f;

    uint4 pT0, pT1, pZ, pR;
    float4 pV0, pV1;
    const int vs = tid >> 3, vi0 = (tid & 7) * 8;

#define C2_LOAD(c_) do { \
    size_t cb_ = (size_t)(bh * NCH + (c_)); \
    const uint4* tp_ = (const uint4*)(TLt + cb_ * 4096); \
    pT0 = tp_[tid * 2]; pT1 = tp_[tid * 2 + 1]; \
    pZ = ((const uint4*)(ZLt + cb_ * 2048))[tid]; \
    pR = ((const uint4*)(Rho + cb_ * 2048))[tid]; \
    const float* vp_ = vb + vbase + (size_t)((c_) * CL + vs) * Cc + vi0; \
    pV0 = *(const float4*)vp_; pV1 = *(const float4*)(vp_ + 4); \
} while (0)

#define C2_STORE() do { \
    *(uint4*)&Ttl[(tid >> 2) * 72 + (tid & 3) * 16] = pT0; \
    *(uint4*)&Ttl[(tid >> 2) * 72 + (tid & 3) * 16 + 8] = pT1; \
    *(uint4*)&Ztl[(tid >> 2) * 40 + (tid & 3) * 8] = pZ; \
    *(uint4*)&Rl[(tid >> 3) * 72 + (tid & 7) * 8] = pR; \
    const float* pv_ = (const float*)&pV0; \
    Vtl[(vi0 + 0) * 40 + vs] = f2bf(pv_[0]); \
    Vtl[(vi0 + 1) * 40 + vs] = f2bf(pv_[1]); \
    Vtl[(vi0 + 2) * 40 + vs] = f2bf(pv_[2]); \
    Vtl[(vi0 + 3) * 40 + vs] = f2bf(pv_[3]); \
    const float* pw_ = (const float*)&pV1; \
    Vtl[(vi0 + 4) * 40 + vs] = f2bf(pw_[0]); \
    Vtl[(vi0 + 5) * 40 + vs] = f2bf(pw_[1]); \
    Vtl[(vi0 + 6) * 40 + vs] = f2bf(pw_[2]); \
    Vtl[(vi0 + 7) * 40 + vs] = f2bf(pw_[3]); \
} while (0)

    C2_LOAD(0);
    for (int c = 0; c < NCH; ++c) {
        __syncthreads();
#pragma unroll
        for (int n = 0; n < 4; ++n) {
#pragma unroll
            for (int r = 0; r < 4; ++r)
                Sl[(i0w + lk * 4 + r) * 72 + n * 16 + lr] = f2bf(S[n][r]);
        }
        C2_STORE();
        if (c + 1 < NCH) C2_LOAD(c + 1);
        __syncthreads();

        bf16x8 sA0 = *(const bf16x8*)&Sl[(i0w + lr) * 72 + lk * 8];
        bf16x8 sA1 = *(const bf16x8*)&Sl[(i0w + lr) * 72 + 32 + lk * 8];

#pragma unroll
        for (int nt = 0; nt < 2; ++nt) {
            int t = nt * 16 + lr;
            float* yp = yb + vbase + (size_t)(c * CL + t) * Cc + i0w + lk * 4;
            f32x4 yc = *(f32x4*)yp;
            bf16x8 b0 = *(const bf16x8*)&Rl[t * 72 + lk * 8];
            bf16x8 b1 = *(const bf16x8*)&Rl[t * 72 + 32 + lk * 8];
            yc = __builtin_amdgcn_mfma_f32_16x16x32_bf16(sA0, b0, yc, 0, 0, 0);
            yc = __builtin_amdgcn_mfma_f32_16x16x32_bf16(sA1, b1, yc, 0, 0, 0);
            *(f32x4*)yp = yc;
        }

        bf16x8 vA = *(const bf16x8*)&Vtl[(i0w + lr) * 40 + lk * 8];
#pragma unroll
        for (int n = 0; n < 4; ++n) {
            int j = n * 16 + lr;
            bf16x8 t0 = *(const bf16x8*)&Ttl[j * 72 + lk * 8];
            bf16x8 t1 = *(const bf16x8*)&Ttl[j * 72 + 32 + lk * 8];
            bf16x8 z0 = *(const bf16x8*)&Ztl[j * 40 + lk * 8];
            f32x4 acc = { 0.f, 0.f, 0.f, 0.f };
            acc = __builtin_amdgcn_mfma_f32_16x16x32_bf16(sA0, t0, acc, 0, 0, 0);
            acc = __builtin_amdgcn_mfma_f32_16x16x32_bf16(sA1, t1, acc, 0, 0, 0);
            acc = __builtin_amdgcn_mfma_f32_16x16x32_bf16(vA, z0, acc, 0, 0, 0);
            S[n] = acc;
        }
    }
#undef C2_LOAD
#undef C2_STORE
}

// ---------------------------------------------------------------------------
// GroupNorm + r*k*r_k bonus + gate
// ---------------------------------------------------------------------------
__global__ __launch_bounds__(256) void gn_rt_kernel(
    const float* __restrict__ yb, const float* __restrict__ rb,
    const float* __restrict__ kb, const float* __restrict__ vb,
    const unsigned short* __restrict__ gb, const float* __restrict__ r_k,
    const float* __restrict__ ln_w, const float* __restrict__ ln_b,
    unsigned short* __restrict__ zb)
{
    const int row = blockIdx.x;
    const int tid = threadIdx.x;
    const int c0 = tid * 4;
    const int hd = tid >> 4;
    const int n0 = c0 & 63;
    const size_t o = (size_t)row * Cc;

    float4 y4 = *(const float4*)(yb + o + c0);
    float4 r4 = *(const float4*)(rb + o + c0);
    float4 k4 = *(const float4*)(kb + o + c0);
    float4 v4 = *(const float4*)(vb + o + c0);
    ushort4 g4u = *(const ushort4*)(gb + o + c0);
    float4 rk4 = *(const float4*)(r_k + hd * 64 + n0);

    float yv[4] = { y4.x, y4.y, y4.z, y4.w };
    float rv[4] = { r4.x, r4.y, r4.z, r4.w };
    float kv[4] = { k4.x, k4.y, k4.z, k4.w };
    float vv[4] = { v4.x, v4.y, v4.z, v4.w };
    float gv[4] = { bf2f(g4u.x), bf2f(g4u.y), bf2f(g4u.z), bf2f(g4u.w) };
    float rkv[4] = { rk4.x, rk4.y, rk4.z, rk4.w };

    float sum = 0.f, ssq = 0.f, dot = 0.f;
#pragma unroll
    for (int j = 0; j < 4; ++j) {
        sum += yv[j];
        ssq += yv[j] * yv[j];
        dot += rv[j] * kv[j] * rkv[j];
    }
#pragma unroll
    for (int m = 1; m <= 8; m <<= 1) {
        sum += __shfl_xor(sum, m);
        ssq += __shfl_xor(ssq, m);
        dot += __shfl_xor(dot, m);
    }
    const float mu = sum * (1.f / 64.f);
    const float var = ssq * (1.f / 64.f) - mu * mu;
    const float inv = rsqrtf(var + 0.00064f);

    ushort4 z4;
    unsigned short* zp = (unsigned short*)&z4;
#pragma unroll
    for (int j = 0; j < 4; ++j) {
        int c = c0 + j;
        float yg = (yv[j] - mu) * inv * ln_w[c] + ln_b[c];
        yg += dot * vv[j];
        zp[j] = f2bf(yg * gv[j]);
    }
    *(ushort4*)(zb + o + c0) = z4;
}

// ---------------------------------------------------------------------------

extern "C" void kernel_launch(void* const* d_in, const int* in_sizes, int n_in,
                              void* d_out, int out_size, void* d_ws, size_t ws_size,
                              hipStream_t stream)
{
    const float* x   = (const float*)d_in[0];
    const float* x_r = (const float*)d_in[1];
    const float* x_w = (const float*)d_in[2];
    const float* x_k = (const float*)d_in[3];
    const float* x_v = (const float*)d_in[4];
    const float* x_a = (const float*)d_in[5];
    const float* x_g = (const float*)d_in[6];
    const float* w0  = (const float*)d_in[7];
    const float* w1  = (const float*)d_in[8];
    const float* w2  = (const float*)d_in[9];
    const float* a0  = (const float*)d_in[10];
    const float* a1  = (const float*)d_in[11];
    const float* a2  = (const float*)d_in[12];
    // v0,v1,v2 (13..15): forward no-op on first-layer call
    const float* g1  = (const float*)d_in[16];
    const float* g2  = (const float*)d_in[17];
    const float* k_k = (const float*)d_in[18];
    const float* k_a = (const float*)d_in[19];
    const float* r_k = (const float*)d_in[20];
    const float* Wr  = (const float*)d_in[21];
    const float* Wk  = (const float*)d_in[22];
    const float* Wv  = (const float*)d_in[23];
    const float* Wo  = (const float*)d_in[24];
    const float* ln_w = (const float*)d_in[25];
    const float* ln_b = (const float*)d_in[26];

    float* ws = (float*)d_ws;
    const size_t S = (size_t)Bsz * Tt * Cc;       // 4,194,304 floats (16 MiB)
    const int M = Bsz * Tt;                        // 4096

    float* rb  = ws + 0 * S;
    float* wdb = ws + 1 * S;
    float* kb  = ws + 2 * S;
    float* vb  = ws + 3 * S;
    float* aab = ws + 4 * S;
    unsigned short* zb = (unsigned short*)(ws + 4 * S);    // after chunk1 (aab dead)
    float* bbb = ws + 5 * S;
    float* yb  = ws + 6 * S;
    unsigned short* hw = (unsigned short*)yb;              // bf16, dead before chunk1
    unsigned short* ha = hw + 262144;                      // 4096*64
    unsigned short* hg = ha + 262144;                      // 4096*128
    // slot7: xr,xk (bf16) -> ab (f32) -> TLt (bf16)
    unsigned short* xr = (unsigned short*)(ws + 7 * S);
    unsigned short* xk = xr + S;
    float* ab  = ws + 7 * S;
    unsigned short* TLt = (unsigned short*)(ws + 7 * S);
    // slot8 first half: xv (bf16 8MiB) -> gb (bf16 8MiB)
    unsigned short* xv = (unsigned short*)(ws + 8 * S);
    unsigned short* gb = xv;
    // slot8 second half: W transposes (bf16, dead after stage2) -> Rho (8MiB)
    unsigned short* WrT = xv + S;
    unsigned short* WkT = WrT + 1048576;
    unsigned short* WvT = WkT + 1048576;
    unsigned short* w1t = WvT + 1048576;
    unsigned short* a1t = w1t + 65536;
    unsigned short* g1t = a1t + 65536;
    unsigned short* w2t = g1t + 131072;
    unsigned short* a2t = w2t + 65536;
    unsigned short* g2t = a2t + 65536;
    unsigned short* Rho = xv + S;
    // slot9: ZLt (first 8 MiB) + WoT (second 8 MiB, written in prep, read at end)
    unsigned short* ZLt = (unsigned short*)(ws + 9 * S);
    unsigned short* WoT = ZLt + S;

    dim3 blk(256);

    // 1. all prep: mixcast + 11 weight transposes (one launch)
    prep_all<<<dim3(4096 + 1024 + 128), blk, 0, stream>>>(
        x, x_r, x_k, x_v, Wr, Wk, Wv, Wo, w1, a1, g1, w2, a2, g2,
        xr, xk, xv, WrT, WkT, WvT, WoT, w1t, a1t, g1t, w2t, a2t, g2t);

    // 2. stage-1 low-rank (fused mix + bf16 MFMA), one launch
    lowrank1_fused<<<dim3(4, 32), blk, 0, stream>>>(x, x_w, x_a, x_g, w1t, a1t, g1t, hw, ha, hg);

    // 3. big projections r/k/v fused (z=3)
    gemm_rkv<<<dim3(8, 32, 3), blk, 0, stream>>>(xr, xk, xv, WrT, WkT, WvT, rb, kb, vb);

    // 4. stage-2 low-rank fused (z=3)
    stage2_fused<<<dim3(16, 32, 3), blk, 0, stream>>>(hw, ha, hg, w2t, a2t, g2t, wdb, ab, gb, w0, a0);

    // 5. k / kk / aa / bb
    prep_k_kernel<<<dim3(M), blk, 0, stream>>>(kb, ab, k_k, k_a, kb, aab, bbb);

    // 6-7. chunked recurrence
    wkv_chunk1<<<dim3(64 * NCH), dim3(128), 0, stream>>>(rb, wdb, kb, vb, aab, bbb, yb, TLt, Rho, ZLt);
    wkv_chunk2<<<dim3(64), blk, 0, stream>>>(vb, TLt, Rho, ZLt, yb);

    // 8. groupnorm + bonus + gate -> z (bf16)
    gn_rt_kernel<<<dim3(M), blk, 0, stream>>>(yb, rb, kb, vb, gb, r_k, ln_w, ln_b, zb);

    // 9. output projection
    gemm_bf16<<<dim3(8, 32), blk, 0, stream>>>(zb, WoT, (float*)d_out, M, Cc, Cc);
}